// Round 3
// baseline (254.411 us; speedup 1.0000x reference)
//
#include <hip/hip_runtime.h>
#include <hip/hip_bf16.h>

// Raindrop forward, MI355X. B=64 T=128 S=64 O=4 E=64 P=16 A=10 OUT=128.
//  - temporal attention collapsed: (Q K^T) W_s = Q (W_s^T K)  -> no TxT matrix
//  - per-(b,t) chain in bf16 MFMA 16x16x32; LDS <40KB -> 4 blocks/CU
//  - w2 recomputed on the fly in prop2 (no w2 LDS buffer / scatter phase)
// ws floats: PE[131072] | bidir[4096] | masksum[4096] | adj2num[262144] | brp[32]
// ws bytes:  WrT bf16 @4751360 | Hh bf16 [B][S][T][64] @4755456

typedef unsigned short u16;
typedef unsigned int u32;
typedef __attribute__((ext_vector_type(8))) short short8;
typedef __attribute__((ext_vector_type(4))) float f32x4;

#define OFF_PE    0
#define OFF_BIDIR 131072
#define OFF_MS    135168
#define OFF_ADJ   139264
#define OFF_BRP   401408
#define BOFF_WRT  4751360u
#define BOFF_HH   4755456u

__device__ __forceinline__ u16 f2bf(float f){
  __hip_bfloat16 h = __float2bfloat16(f);
  union { __hip_bfloat16 h; u16 u; } v; v.h = h; return v.u;
}
__device__ __forceinline__ u32 pk2bf(float lo, float hi){
  __hip_bfloat162 h = __float22bfloat162_rn(float2{lo, hi});
  union { __hip_bfloat162 h; u32 u; } v; v.h = h; return v.u;
}
__device__ __forceinline__ float bf2f(u16 h){
  union { u32 u; float f; } v; v.u = ((u32)h) << 16; return v.f;
}

// ---------------- K0: PE table, bidir, WrT bf16, brp, masksum ----------------
__global__ void k_pre(const float* __restrict__ times, const float* __restrict__ mask,
                      const float* __restrict__ Wb, const float* __restrict__ Wrecv,
                      const float* __restrict__ brecv,
                      float* __restrict__ ws_f, u16* __restrict__ wrt) {
  const int blk = blockIdx.x, tid = threadIdx.x;
  if (blk < 32) {                      // PE: (B*T,16) sin|cos
    float* PE = ws_f + OFF_PE;
    #pragma unroll
    for (int r = 0; r < 16; ++r) {
      int id = blk * 4096 + r * 256 + tid;
      int bt = id >> 4, k = id & 15;
      float tv = times[bt];
      int kk = k & 7;
      float fr = expf(-(float)kk * 1.1512925465f); // ln(1e4)/8
      float ang = tv * fr;
      PE[id] = (k < 8) ? sinf(ang) : cosf(ang);
    }
  } else if (blk == 32) {              // bidir = Wb @ Wb^T
    float* bidir = ws_f + OFF_BIDIR;
    for (int r = 0; r < 16; ++r) {
      int idx = r * 256 + tid;
      int i = idx >> 6, j = idx & 63;
      float acc = 0.f;
      for (int e = 0; e < 64; ++e) acc += Wb[i*64+e] * Wb[j*64+e];
      bidir[idx] = acc;
    }
  } else if (blk == 33) {              // WrT[d][e] = W_recv[e][d], pad; brp
    for (int r = 0; r < 8; ++r) {
      int idx = r * 256 + tid;
      int d = idx >> 6, e = idx & 63;
      wrt[idx] = (d < 26) ? f2bf(Wrecv[e*26 + d]) : (u16)0;
    }
    if (tid < 32) ws_f[OFF_BRP + tid] = (tid < 26) ? brecv[tid] : 0.f;
  } else {                             // masksum[b][i]
    int b = blk - 34;
    if (tid < 64) {
      float s = 0.f;
      for (int t = 0; t < 128; ++t) s += mask[(b*128 + t)*64 + tid];
      (ws_f + OFF_MS)[b*64 + tid] = s;
    }
  }
}

// ---------------- K1: adj2 numerator (sum_t alpha) ----------------
__global__ __launch_bounds__(256)
void k_adj(const float* __restrict__ x, const float* __restrict__ mask,
           const float* __restrict__ Wobs, const float* __restrict__ battn,
           float* __restrict__ ws_f, const u16* __restrict__ wrt) {
  __shared__ __align__(16) u16 hA[64][72];
  __shared__ __align__(16) u16 hmA[64][40];
  __shared__ __align__(16) u16 catB[64][40];

  const int tid = threadIdx.x;
  const int b = blockIdx.y, tc = blockIdx.x;
  const int w = tid >> 6, l = tid & 63, lr = l & 15, lq = l >> 4, kb = lq * 8;
  const float* PE = ws_f + OFF_PE;
  const float* brp = ws_f + OFF_BRP;
  float* adj = ws_f + OFF_ADJ;

  f32x4 asum[4];
  #pragma unroll
  for (int n = 0; n < 4; ++n) asum[n] = (f32x4){0.f,0.f,0.f,0.f};

  for (int tt = 0; tt < 8; ++tt) {
    int t = tc * 8 + tt;
    int base = b * 128 + t;
    __syncthreads();
    { // P0: h build (lane owns s=l, e-range 16w..16w+15) + catB
      const int s = l, e0 = w * 16;
      float4 xv = *(const float4*)&x[base*256 + s*4];
      float mk = mask[base*64 + s];
      float val[16];
      #pragma unroll
      for (int i = 0; i < 16; ++i) val[i] = 0.f;
      #pragma unroll
      for (int o = 0; o < 4; ++o) {
        float xo = (o==0)?xv.x:(o==1)?xv.y:(o==2)?xv.z:xv.w;
        #pragma unroll
        for (int i4 = 0; i4 < 4; ++i4) {
          float4 wv = *(const float4*)&Wobs[(s*4+o)*64 + e0 + i4*4];
          val[i4*4+0] += xo*wv.x; val[i4*4+1] += xo*wv.y;
          val[i4*4+2] += xo*wv.z; val[i4*4+3] += xo*wv.w;
        }
      }
      union { short8 v[2]; u32 u[8]; } pk;
      #pragma unroll
      for (int k = 0; k < 8; ++k)
        pk.u[k] = pk2bf(fmaxf(val[2*k],0.f)*mk, fmaxf(val[2*k+1],0.f)*mk);
      *(short8*)&hA[s][e0]   = pk.v[0];
      *(short8*)&hA[s][e0+8] = pk.v[1];
      int d = tid & 31;
      float pev = 0.f;
      if (d >= 10 && d < 26) pev = PE[base*16 + d - 10];
      #pragma unroll
      for (int r = 0; r < 8; ++r) {
        int j = r*8 + (tid>>5);
        float v = (d < 10) ? battn[j*10 + d] : pev;
        catB[j][d] = f2bf(v);
      }
    }
    __syncthreads();
    { // P1: hm^T = WrT @ h^T  -> hmA[s][d] row-major (b64 packed)
      int m = w & 1, nb = (w >> 1) * 2;
      const u16* wr = wrt + (16*m + lr) * 64;
      short8 a0 = *(const short8*)&wr[kb];
      short8 a1 = *(const short8*)&wr[32 + kb];
      int d0 = 16*m + lq*4;
      float4 bv = *(const float4*)&brp[d0];
      #pragma unroll
      for (int nn = 0; nn < 2; ++nn) {
        int n = nb + nn;
        f32x4 acc = (f32x4){0.f,0.f,0.f,0.f};
        short8 b0 = *(const short8*)&hA[16*n + lr][kb];
        short8 b1 = *(const short8*)&hA[16*n + lr][32 + kb];
        acc = __builtin_amdgcn_mfma_f32_16x16x32_bf16(a0, b0, acc, 0, 0, 0);
        acc = __builtin_amdgcn_mfma_f32_16x16x32_bf16(a1, b1, acc, 0, 0, 0);
        uint2 qq;
        qq.x = pk2bf(acc[0]+bv.x, acc[1]+bv.y);
        qq.y = pk2bf(acc[2]+bv.z, acc[3]+bv.w);
        *(uint2*)&hmA[16*n + lr][d0] = qq;
      }
    }
    __syncthreads();
    { // P2: alpha accumulate
      short8 am = *(const short8*)&hmA[16*w + lr][kb];
      #pragma unroll
      for (int n = 0; n < 4; ++n) {
        f32x4 z = (f32x4){0.f,0.f,0.f,0.f};
        short8 bc = *(const short8*)&catB[16*n + lr][kb];
        z = __builtin_amdgcn_mfma_f32_16x16x32_bf16(am, bc, z, 0, 0, 0);
        #pragma unroll
        for (int reg = 0; reg < 4; ++reg) asum[n][reg] += fmaxf(z[reg], 0.f);
      }
    }
  }
  #pragma unroll
  for (int n = 0; n < 4; ++n) {
    #pragma unroll
    for (int reg = 0; reg < 4; ++reg) {
      int i = 16*w + lq*4 + reg, j = 16*n + lr;
      atomicAdd(&adj[((size_t)b << 12) + (i << 6) + j], asum[n][reg]);
    }
  }
}

// ---------------- K2: full per-(b,t) chain -> Hh bf16 ----------------
__global__ __launch_bounds__(256)
void k_main(const float* __restrict__ x, const float* __restrict__ mask,
            const float* __restrict__ Wobs, const float* __restrict__ battn,
            const float* __restrict__ ws_f, const u16* __restrict__ wrt,
            u16* __restrict__ Hh) {
  __shared__ __align__(16) u16 hA[64][72];    // h [s][e]; later h1T [e][i]
  __shared__ __align__(16) u16 hT[64][72];    // h^T [e][s]
  __shared__ __align__(16) u16 hmA[64][40];   // h_map [s][d]
  __shared__ __align__(16) u16 catB[64][40];
  __shared__ __align__(16) u16 wA[64][72];    // w1 [i][j]

  const int tid = threadIdx.x;
  const int t = blockIdx.x, b = blockIdx.y;
  const int w = tid >> 6, l = tid & 63, lr = l & 15, lq = l >> 4, kb = lq * 8;
  const int base = b * 128 + t;
  const float* PE = ws_f + OFF_PE;
  const float* bidirG = ws_f + OFF_BIDIR;
  const float* adjG = ws_f + OFF_ADJ + (size_t)b * 4096;
  const float* brp = ws_f + OFF_BRP;

  { // P0: h build + catB
    const int s = l, e0 = w * 16;
    float4 xv = *(const float4*)&x[base*256 + s*4];
    float mk = mask[base*64 + s];
    float val[16];
    #pragma unroll
    for (int i = 0; i < 16; ++i) val[i] = 0.f;
    #pragma unroll
    for (int o = 0; o < 4; ++o) {
      float xo = (o==0)?xv.x:(o==1)?xv.y:(o==2)?xv.z:xv.w;
      #pragma unroll
      for (int i4 = 0; i4 < 4; ++i4) {
        float4 wv = *(const float4*)&Wobs[(s*4+o)*64 + e0 + i4*4];
        val[i4*4+0] += xo*wv.x; val[i4*4+1] += xo*wv.y;
        val[i4*4+2] += xo*wv.z; val[i4*4+3] += xo*wv.w;
      }
    }
    union { short8 v[2]; u32 u[8]; u16 h[16]; } pk;
    #pragma unroll
    for (int k = 0; k < 8; ++k)
      pk.u[k] = pk2bf(fmaxf(val[2*k],0.f)*mk, fmaxf(val[2*k+1],0.f)*mk);
    *(short8*)&hA[s][e0]   = pk.v[0];
    *(short8*)&hA[s][e0+8] = pk.v[1];
    #pragma unroll
    for (int i = 0; i < 16; ++i) hT[e0 + i][s] = pk.h[i];
    int d = tid & 31;
    float pev = 0.f;
    if (d >= 10 && d < 26) pev = PE[base*16 + d - 10];
    #pragma unroll
    for (int r = 0; r < 8; ++r) {
      int j = r*8 + (tid>>5);
      float v = (d < 10) ? battn[j*10 + d] : pev;
      catB[j][d] = f2bf(v);
    }
  }
  __syncthreads();

  { // P1: hm^T = WrT @ h^T  -> hmA[s][d] (b64 packed)
    int m = w & 1, nb = (w >> 1) * 2;
    const u16* wr = wrt + (16*m + lr) * 64;
    short8 a0 = *(const short8*)&wr[kb];
    short8 a1 = *(const short8*)&wr[32 + kb];
    int d0 = 16*m + lq*4;
    float4 bv = *(const float4*)&brp[d0];
    #pragma unroll
    for (int nn = 0; nn < 2; ++nn) {
      int n = nb + nn;
      f32x4 acc = (f32x4){0.f,0.f,0.f,0.f};
      short8 b0 = *(const short8*)&hA[16*n + lr][kb];
      short8 b1 = *(const short8*)&hA[16*n + lr][32 + kb];
      acc = __builtin_amdgcn_mfma_f32_16x16x32_bf16(a0, b0, acc, 0, 0, 0);
      acc = __builtin_amdgcn_mfma_f32_16x16x32_bf16(a1, b1, acc, 0, 0, 0);
      uint2 qq;
      qq.x = pk2bf(acc[0]+bv.x, acc[1]+bv.y);
      qq.y = pk2bf(acc[2]+bv.z, acc[3]+bv.w);
      *(uint2*)&hmA[16*n + lr][d0] = qq;
    }
  }
  __syncthreads();

  { // P2: alpha -> w1 (wA)
    short8 am = *(const short8*)&hmA[16*w + lr][kb];
    int i0 = 16*w + lq*4;
    #pragma unroll
    for (int n = 0; n < 4; ++n) {
      f32x4 z = (f32x4){0.f,0.f,0.f,0.f};
      short8 bc = *(const short8*)&catB[16*n + lr][kb];
      z = __builtin_amdgcn_mfma_f32_16x16x32_bf16(am, bc, z, 0, 0, 0);
      int j = 16*n + lr;
      #pragma unroll
      for (int reg = 0; reg < 4; ++reg) {
        int i = i0 + reg;
        float w1 = fmaxf(z[reg], 0.f) * bidirG[(i << 6) + j];
        wA[i][j] = f2bf(w1);
      }
    }
  }
  __syncthreads();

  { // P3: h1 = relu(w1 @ h) -> h1T into hA (b64 packed)
    short8 aw0 = *(const short8*)&wA[16*w + lr][kb];
    short8 aw1 = *(const short8*)&wA[16*w + lr][32 + kb];
    int i0 = 16*w + lq*4;
    #pragma unroll
    for (int n = 0; n < 4; ++n) {
      f32x4 acc = (f32x4){0.f,0.f,0.f,0.f};
      short8 b0 = *(const short8*)&hT[16*n + lr][kb];
      short8 b1 = *(const short8*)&hT[16*n + lr][32 + kb];
      acc = __builtin_amdgcn_mfma_f32_16x16x32_bf16(aw0, b0, acc, 0, 0, 0);
      acc = __builtin_amdgcn_mfma_f32_16x16x32_bf16(aw1, b1, acc, 0, 0, 0);
      int e = 16*n + lr;
      uint2 pp;
      pp.x = pk2bf(fmaxf(acc[0],0.f), fmaxf(acc[1],0.f));
      pp.y = pk2bf(fmaxf(acc[2],0.f), fmaxf(acc[3],0.f));
      *(uint2*)&hA[e][i0] = pp;   // h1T[e][i]
    }
  }
  __syncthreads();

  { // P4: w2 on-the-fly; h2 = relu(w2 @ h1) -> Hh
    int row = 16*w + lr;
    float rms = 1.0f / (ws_f + OFF_MS)[b*64 + row];
    short8 aw0 = *(const short8*)&wA[row][kb];
    short8 aw1 = *(const short8*)&wA[row][32 + kb];
    float4 f0 = *(const float4*)&adjG[row*64 + kb];
    float4 f1 = *(const float4*)&adjG[row*64 + kb + 4];
    float4 f2 = *(const float4*)&adjG[row*64 + 32 + kb];
    float4 f3 = *(const float4*)&adjG[row*64 + 32 + kb + 4];
    union { short8 v; u16 h[8]; u32 u[4]; } ua, ub, oa, ob;
    ua.v = aw0; ub.v = aw1;
    float fa[8] = {f0.x,f0.y,f0.z,f0.w,f1.x,f1.y,f1.z,f1.w};
    float fb[8] = {f2.x,f2.y,f2.z,f2.w,f3.x,f3.y,f3.z,f3.w};
    #pragma unroll
    for (int k = 0; k < 4; ++k) {
      oa.u[k] = pk2bf(bf2f(ua.h[2*k])*fa[2*k]*rms, bf2f(ua.h[2*k+1])*fa[2*k+1]*rms);
      ob.u[k] = pk2bf(bf2f(ub.h[2*k])*fb[2*k]*rms, bf2f(ub.h[2*k+1])*fb[2*k+1]*rms);
    }
    short8 a20 = oa.v, a21 = ob.v;
    int i0 = 16*w + lq*4;
    size_t obase = ((size_t)b * 64) * 8192 + (size_t)t * 64;
    #pragma unroll
    for (int n = 0; n < 4; ++n) {
      f32x4 acc = (f32x4){0.f,0.f,0.f,0.f};
      short8 b0 = *(const short8*)&hA[16*n + lr][kb];      // h1T
      short8 b1 = *(const short8*)&hA[16*n + lr][32 + kb];
      acc = __builtin_amdgcn_mfma_f32_16x16x32_bf16(a20, b0, acc, 0, 0, 0);
      acc = __builtin_amdgcn_mfma_f32_16x16x32_bf16(a21, b1, acc, 0, 0, 0);
      int e = 16*n + lr;
      u32 p0 = pk2bf(fmaxf(acc[0],0.f), fmaxf(acc[1],0.f));
      u32 p1 = pk2bf(fmaxf(acc[2],0.f), fmaxf(acc[3],0.f));
      Hh[obase + (size_t)(i0+0) * 8192 + e] = (u16)p0;
      Hh[obase + (size_t)(i0+1) * 8192 + e] = (u16)(p0 >> 16);
      Hh[obase + (size_t)(i0+2) * 8192 + e] = (u16)p1;
      Hh[obase + (size_t)(i0+3) * 8192 + e] = (u16)(p1 >> 16);
    }
  }
}

// ---------------- K3: collapsed temporal attention ----------------
#define HTP 82
#define PEP 17

__global__ __launch_bounds__(256)
void k_attn(const float* __restrict__ ws_f, const u16* __restrict__ Hh,
            const float* __restrict__ Wq, const float* __restrict__ bq,
            const float* __restrict__ Wk, const float* __restrict__ bk,
            const float* __restrict__ Ws, const float* __restrict__ bs,
            const float* __restrict__ Wemb, const float* __restrict__ bemb,
            float* __restrict__ out) {
  __shared__ u16 Ht[128][HTP];
  __shared__ float peB[128][PEP];
  __shared__ float wsL[128];
  __shared__ float pA[3][80];
  __shared__ float pK[8][10];
  __shared__ float KtilL[10];
  __shared__ float qvL[80];
  __shared__ float pC[2][128];
  __shared__ float bb[128];
  __shared__ float red[4];
  __shared__ float cstL, sWL;

  const int tid = threadIdx.x;
  const int s = blockIdx.x, b = blockIdx.y;
  const float scale = 0.111803398875f; // 1/sqrt(80)

  const u16* src = Hh + ((size_t)b * 64 + s) * 8192;
  #pragma unroll
  for (int r = 0; r < 4; ++r) {
    int id = r * 256 + tid;
    int tt = id >> 3, c = (id & 7) * 8;
    uint4 q = *(const uint4*)&src[tt * 64 + c];
    u32* dst = (u32*)&Ht[tt][c];
    dst[0] = q.x; dst[1] = q.y; dst[2] = q.z; dst[3] = q.w;
  }
  #pragma unroll
  for (int r = 0; r < 8; ++r) {
    int id = r * 256 + tid;
    peB[id >> 4][id & 15] = ws_f[OFF_PE + (size_t)b * 2048 + id];
  }
  if (tid < 128) wsL[tid] = Ws[tid];
  __syncthreads();

  if (tid < 240) {
    int d = tid % 80, c = tid / 80;
    int t0 = c * 43, t1 = (c == 2) ? 128 : t0 + 43;
    float acc = 0.f;
    if (d < 64) {
      for (int t = t0; t < t1; ++t) acc += wsL[t] * bf2f(Ht[t][d]);
    } else {
      int k = d - 64;
      for (int t = t0; t < t1; ++t) acc += wsL[t] * peB[t][k];
    }
    pA[c][d] = acc;
  } else if (tid == 240) {
    float sw = 0.f;
    for (int t = 0; t < 128; ++t) sw += wsL[t];
    sWL = sw;
  }
  __syncthreads();

  if (tid < 80) {
    int a = tid % 10, c = tid / 10;
    float acc = 0.f;
    #pragma unroll
    for (int i = 0; i < 10; ++i) {
      int d = c * 10 + i;
      float hb = pA[0][d] + pA[1][d] + pA[2][d];
      acc += hb * Wk[d * 10 + a];
    }
    pK[c][a] = acc;
  }
  __syncthreads();
  if (tid < 10) {
    float acc = sWL * bk[tid];
    #pragma unroll
    for (int c = 0; c < 8; ++c) acc += pK[c][tid];
    KtilL[tid] = acc;
  }
  __syncthreads();
  if (tid < 80) {
    float acc = 0.f;
    #pragma unroll
    for (int a = 0; a < 10; ++a) acc += Wq[tid * 10 + a] * KtilL[a];
    qvL[tid] = acc;
  } else if (tid == 80) {
    float cq = 0.f;
    #pragma unroll
    for (int a = 0; a < 10; ++a) cq += bq[a] * KtilL[a];
    cstL = scale * cq + bs[0];
  }
  __syncthreads();

  {
    int t = tid & 127, half = tid >> 7;
    float acc = 0.f;
    const u32* row = (const u32*)&Ht[t][0];
    if (half == 0) {
      #pragma unroll
      for (int i = 0; i < 20; ++i) {
        u32 p = row[i];
        acc += bf2f((u16)p) * qvL[2*i] + bf2f((u16)(p >> 16)) * qvL[2*i+1];
      }
    } else {
      #pragma unroll
      for (int i = 20; i < 32; ++i) {
        u32 p = row[i];
        acc += bf2f((u16)p) * qvL[2*i] + bf2f((u16)(p >> 16)) * qvL[2*i+1];
      }
      #pragma unroll
      for (int k = 0; k < 16; ++k) acc += peB[t][k] * qvL[64 + k];
    }
    pC[half][t] = acc;
  }
  __syncthreads();

  float ev = 0.f;
  if (tid < 128) {
    float v = scale * (pC[0][tid] + pC[1][tid]) + cstL;
    bb[tid] = v;
    float mm = v;
    #pragma unroll
    for (int off = 32; off; off >>= 1) mm = fmaxf(mm, __shfl_xor(mm, off));
    if ((tid & 63) == 0) red[tid >> 6] = mm;
  }
  __syncthreads();
  float m = fmaxf(red[0], red[1]);
  if (tid < 128) {
    ev = expf(bb[tid] - m);
    float ss = ev;
    #pragma unroll
    for (int off = 32; off; off >>= 1) ss += __shfl_xor(ss, off);
    if ((tid & 63) == 0) red[2 + (tid >> 6)] = ss;
  }
  __syncthreads();
  if (tid < 128) bb[tid] = ev / (red[2] + red[3]);
  __syncthreads();

  if (tid < 240) {
    int d = tid % 80, c = tid / 80;
    int t0 = c * 43, t1 = (c == 2) ? 128 : t0 + 43;
    float acc = 0.f;
    if (d < 64) {
      for (int t = t0; t < t1; ++t) acc += bb[t] * bf2f(Ht[t][d]);
    } else {
      int k = d - 64;
      for (int t = t0; t < t1; ++t) acc += bb[t] * peB[t][k];
    }
    pA[c][d] = acc;
  }
  __syncthreads();

  {
    int o = tid & 127, half = tid >> 7;
    int d0 = half * 40;
    float acc = 0.f;
    #pragma unroll
    for (int i = 0; i < 40; ++i) {
      int d = d0 + i;
      float hv = pA[0][d] + pA[1][d] + pA[2][d];
      acc += hv * Wemb[d * 128 + o];
    }
    pC[half][o] = acc;
  }
  __syncthreads();
  if (tid < 128) {
    out[(((size_t)b * 64 + s) << 7) + tid] = bemb[tid] + pC[0][tid] + pC[1][tid];
  }
}

extern "C" void kernel_launch(void* const* d_in, const int* in_sizes, int n_in,
                              void* d_out, int out_size, void* d_ws, size_t ws_size,
                              hipStream_t stream) {
  (void)in_sizes; (void)n_in; (void)out_size; (void)ws_size;
  const float* x     = (const float*)d_in[0];
  const float* times = (const float*)d_in[1];
  const float* mask  = (const float*)d_in[2];
  const float* Wobs  = (const float*)d_in[3];
  const float* Wattn = (const float*)d_in[4];
  const float* Wrecv = (const float*)d_in[5];
  const float* brecv = (const float*)d_in[6];
  const float* Wb    = (const float*)d_in[7];
  const float* Wq    = (const float*)d_in[8];
  const float* bq    = (const float*)d_in[9];
  const float* Wk    = (const float*)d_in[10];
  const float* bk    = (const float*)d_in[11];
  const float* Ws    = (const float*)d_in[12];
  const float* bs    = (const float*)d_in[13];
  const float* Wemb  = (const float*)d_in[14];
  const float* bemb  = (const float*)d_in[15];
  float* out = (float*)d_out;
  float* ws_f = (float*)d_ws;
  u16* wrt = (u16*)((char*)d_ws + BOFF_WRT);
  u16* Hh  = (u16*)((char*)d_ws + BOFF_HH);

  hipMemsetAsync((char*)d_ws + (size_t)OFF_ADJ * 4, 0, (size_t)64 * 64 * 64 * 4, stream);
  k_pre<<<98, 256, 0, stream>>>(times, mask, Wb, Wrecv, brecv, ws_f, wrt);
  k_adj<<<dim3(16, 64), 256, 0, stream>>>(x, mask, Wobs, Wattn, ws_f, wrt);
  k_main<<<dim3(128, 64), 256, 0, stream>>>(x, mask, Wobs, Wattn, ws_f, wrt, Hh);
  k_attn<<<dim3(64, 64), 256, 0, stream>>>(ws_f, Hh, Wq, bq, Wk, bk, Ws, bs, Wemb, bemb, out);
}

// Round 4
// 200.947 us; speedup vs baseline: 1.2661x; 1.2661x over previous
//
#include <hip/hip_runtime.h>
#include <hip/hip_bf16.h>

// Raindrop forward, MI355X. B=64 T=128 S=64 O=4 E=64 P=16 A=10 OUT=128.
//  - temporal attention collapsed: (Q K^T) W_s = Q (W_s^T K)  -> no TxT matrix
//  - per-(b,t) chain in bf16 MFMA 16x16x32; LDS 39KB -> 4 blocks/CU
//  - adjS (= sum_t alpha / masksum, bf16) precomputed by k_scale; staged to LDS
//  - all global reads coalesced (lane->e mapping in h-build; r3 lane->sensor regressed)
// ws floats: PE[131072] | bidir[4096] | masksum[4096] | adjnum[262144] | brp[32]
// ws bytes @: WrT 1605760 | catC 1609856 | PEh 1614976 | adjS 1877120 | Hh 2401408

typedef unsigned short u16;
typedef unsigned int u32;
typedef __attribute__((ext_vector_type(8))) short short8;
typedef __attribute__((ext_vector_type(4))) float f32x4;

#define OFF_PE    0
#define OFF_BIDIR 131072
#define OFF_MS    135168
#define OFF_ADJ   139264
#define OFF_BRP   401408
#define BOFF_WRT  1605760u
#define BOFF_CATC 1609856u
#define BOFF_PEH  1614976u
#define BOFF_ADJS 1877120u
#define BOFF_HH   2401408u

__device__ __forceinline__ u16 f2bf(float f){
  __hip_bfloat16 h = __float2bfloat16(f);
  union { __hip_bfloat16 h; u16 u; } v; v.h = h; return v.u;
}
__device__ __forceinline__ u32 pk2bf(float lo, float hi){
  __hip_bfloat162 h = __float22bfloat162_rn(float2{lo, hi});
  union { __hip_bfloat162 h; u32 u; } v; v.h = h; return v.u;
}
__device__ __forceinline__ float bf2f(u16 h){
  union { u32 u; float f; } v; v.u = ((u32)h) << 16; return v.f;
}

// ---------------- K0: PE (f32+bf16), bidir, WrT, brp, catC, masksum ----------------
__global__ void k_pre(const float* __restrict__ times, const float* __restrict__ mask,
                      const float* __restrict__ Wb, const float* __restrict__ Wrecv,
                      const float* __restrict__ brecv, const float* __restrict__ battn,
                      float* __restrict__ ws_f, char* __restrict__ ws_b) {
  const int blk = blockIdx.x, tid = threadIdx.x;
  u16* wrt  = (u16*)(ws_b + BOFF_WRT);
  u16* catC = (u16*)(ws_b + BOFF_CATC);
  u16* peh  = (u16*)(ws_b + BOFF_PEH);
  if (blk < 32) {                      // PE: (B*T,16) sin|cos, f32 + bf16
    float* PE = ws_f + OFF_PE;
    #pragma unroll
    for (int r = 0; r < 16; ++r) {
      int id = blk * 4096 + r * 256 + tid;
      int bt = id >> 4, k = id & 15;
      float tv = times[bt];
      int kk = k & 7;
      float fr = expf(-(float)kk * 1.1512925465f); // ln(1e4)/8
      float ang = tv * fr;
      float v = (k < 8) ? sinf(ang) : cosf(ang);
      PE[id] = v;
      peh[id] = f2bf(v);
    }
  } else if (blk == 32) {              // bidir = Wb @ Wb^T
    float* bidir = ws_f + OFF_BIDIR;
    for (int r = 0; r < 16; ++r) {
      int idx = r * 256 + tid;
      int i = idx >> 6, j = idx & 63;
      float acc = 0.f;
      for (int e = 0; e < 64; ++e) acc += Wb[i*64+e] * Wb[j*64+e];
      bidir[idx] = acc;
    }
  } else if (blk == 33) {              // WrT, brp, catC
    for (int r = 0; r < 8; ++r) {
      int idx = r * 256 + tid;
      int d = idx >> 6, e = idx & 63;
      wrt[idx] = (d < 26) ? f2bf(Wrecv[e*26 + d]) : (u16)0;
    }
    if (tid < 32) ws_f[OFF_BRP + tid] = (tid < 26) ? brecv[tid] : 0.f;
    for (int r = 0; r < 10; ++r) {
      int idx = r * 256 + tid;          // 2560 = 64*40
      int j = idx / 40, d = idx % 40;
      catC[idx] = (d < 10) ? f2bf(battn[j*10 + d]) : (u16)0;
    }
  } else {                             // masksum[b][i]
    int b = blk - 34;
    if (tid < 64) {
      float s = 0.f;
      for (int t = 0; t < 128; ++t) s += mask[(b*128 + t)*64 + tid];
      (ws_f + OFF_MS)[b*64 + tid] = s;
    }
  }
}

// ---------------- K1: adj2 numerator (sum_t alpha) ----------------
__global__ __launch_bounds__(256)
void k_adj(const float* __restrict__ x, const float* __restrict__ mask,
           const float* __restrict__ Wobs, float* __restrict__ ws_f,
           const char* __restrict__ ws_b) {
  __shared__ __align__(16) u16 hA[64][72];
  __shared__ __align__(16) u16 hmA[64][40];
  __shared__ __align__(16) u16 catB[64][40];
  __shared__ float xs[64][4];
  __shared__ float maskv[64];

  const int tid = threadIdx.x;
  const int b = blockIdx.y, tc = blockIdx.x;
  const int w = tid >> 6, l = tid & 63, lr = l & 15, lq = l >> 4, kb = lq * 8;
  const u16* wrt  = (const u16*)(ws_b + BOFF_WRT);
  const u16* catC = (const u16*)(ws_b + BOFF_CATC);
  const u16* peh  = (const u16*)(ws_b + BOFF_PEH);
  const float* brp = ws_f + OFF_BRP;
  float* adj = ws_f + OFF_ADJ;

  #pragma unroll
  for (int k = 0; k < 5; ++k) {        // catB const part (1280 u32)
    int idx = k * 256 + tid;
    ((u32*)catB)[idx] = ((const u32*)catC)[idx];
  }

  f32x4 asum[4];
  #pragma unroll
  for (int n = 0; n < 4; ++n) asum[n] = (f32x4){0.f,0.f,0.f,0.f};

  for (int tt = 0; tt < 8; ++tt) {
    int t = tc * 8 + tt;
    int base = b * 128 + t;
    __syncthreads();
    xs[tid >> 2][tid & 3] = x[base*256 + tid];
    if (tid < 64) maskv[tid] = mask[base*64 + tid];
    { // PE cols 10..25 of catB
      int j = tid & 63, c = tid >> 6;
      const u32* pesrc = (const u32*)(peh + base*16);
      u32* dst = (u32*)&catB[j][10];
      dst[2*c]   = pesrc[2*c];
      dst[2*c+1] = pesrc[2*c+1];
    }
    __syncthreads();
    { // P0: h build, lane -> e (coalesced Wobs)
      int e = tid & 63, s0 = (tid >> 6) * 16;
      #pragma unroll
      for (int si = 0; si < 16; si += 2) {
        int s = s0 + si, s1 = s + 1;
        float a0 = xs[s][0]*Wobs[(s*4+0)*64+e] + xs[s][1]*Wobs[(s*4+1)*64+e]
                 + xs[s][2]*Wobs[(s*4+2)*64+e] + xs[s][3]*Wobs[(s*4+3)*64+e];
        a0 = fmaxf(a0, 0.f) * maskv[s];
        float a1 = xs[s1][0]*Wobs[(s1*4+0)*64+e] + xs[s1][1]*Wobs[(s1*4+1)*64+e]
                 + xs[s1][2]*Wobs[(s1*4+2)*64+e] + xs[s1][3]*Wobs[(s1*4+3)*64+e];
        a1 = fmaxf(a1, 0.f) * maskv[s1];
        u32 p = pk2bf(a0, a1);
        hA[s][e] = (u16)p; hA[s1][e] = (u16)(p >> 16);
      }
    }
    __syncthreads();
    { // P1: hm^T = WrT @ h^T -> hmA[s][d] (b64 packed)
      int m = w & 1, nb = (w >> 1) * 2;
      const u16* wr = wrt + (16*m + lr) * 64;
      short8 a0 = *(const short8*)&wr[kb];
      short8 a1 = *(const short8*)&wr[32 + kb];
      int d0 = 16*m + lq*4;
      float4 bv = *(const float4*)&brp[d0];
      #pragma unroll
      for (int nn = 0; nn < 2; ++nn) {
        int n = nb + nn;
        f32x4 acc = (f32x4){0.f,0.f,0.f,0.f};
        short8 b0 = *(const short8*)&hA[16*n + lr][kb];
        short8 b1 = *(const short8*)&hA[16*n + lr][32 + kb];
        acc = __builtin_amdgcn_mfma_f32_16x16x32_bf16(a0, b0, acc, 0, 0, 0);
        acc = __builtin_amdgcn_mfma_f32_16x16x32_bf16(a1, b1, acc, 0, 0, 0);
        uint2 qq;
        qq.x = pk2bf(acc[0]+bv.x, acc[1]+bv.y);
        qq.y = pk2bf(acc[2]+bv.z, acc[3]+bv.w);
        *(uint2*)&hmA[16*n + lr][d0] = qq;
      }
    }
    __syncthreads();
    { // P2: alpha accumulate
      short8 am = *(const short8*)&hmA[16*w + lr][kb];
      #pragma unroll
      for (int n = 0; n < 4; ++n) {
        f32x4 z = (f32x4){0.f,0.f,0.f,0.f};
        short8 bc = *(const short8*)&catB[16*n + lr][kb];
        z = __builtin_amdgcn_mfma_f32_16x16x32_bf16(am, bc, z, 0, 0, 0);
        #pragma unroll
        for (int reg = 0; reg < 4; ++reg) asum[n][reg] += fmaxf(z[reg], 0.f);
      }
    }
  }
  #pragma unroll
  for (int n = 0; n < 4; ++n) {
    #pragma unroll
    for (int reg = 0; reg < 4; ++reg) {
      int i = 16*w + lq*4 + reg, j = 16*n + lr;
      atomicAdd(&adj[((size_t)b << 12) + (i << 6) + j], asum[n][reg]);
    }
  }
}

// ---------------- K1b: adjS = bf16(adjnum / masksum) ----------------
__global__ __launch_bounds__(256)
void k_scale(const float* __restrict__ ws_f, char* __restrict__ ws_b) {
  const int b = blockIdx.x, tid = threadIdx.x;
  const float* adj = ws_f + OFF_ADJ + (size_t)b * 4096;
  const float* ms = ws_f + OFF_MS + b * 64;
  u16* as_ = (u16*)(ws_b + BOFF_ADJS) + (size_t)b * 4096;
  #pragma unroll
  for (int k = 0; k < 16; ++k) {
    int idx = k * 256 + tid;
    int i = idx >> 6;
    as_[idx] = f2bf(adj[idx] / ms[i]);
  }
}

// ---------------- K2: full per-(b,t) chain -> Hh bf16 ----------------
__global__ __launch_bounds__(256)
void k_main(const float* __restrict__ x, const float* __restrict__ mask,
            const float* __restrict__ Wobs, const float* __restrict__ ws_f,
            const char* __restrict__ ws_b, u16* __restrict__ Hh) {
  __shared__ __align__(16) char smem[39168];
  u16 (*hA)[72]  = (u16 (*)[72])(smem);           // h [s][e]; later h1T [e][i]
  u16 (*hT)[72]  = (u16 (*)[72])(smem + 9216);    // h^T [e][s]
  u16 (*wA)[72]  = (u16 (*)[72])(smem + 18432);   // w1 [i][j]
  u16 (*hmA)[40] = (u16 (*)[40])(smem + 27648);   // h_map [s][d]   (dead after P2)
  u16 (*catB)[40]= (u16 (*)[40])(smem + 32768);   //                (dead after P2)
  u16 (*adjS)[72]= (u16 (*)[72])(smem + 27648);   // overlay, staged in P3
  float (*xs)[4] = (float (*)[4])(smem + 37888);
  float* maskv   = (float*)(smem + 38912);

  const int tid = threadIdx.x;
  const int t = blockIdx.x, b = blockIdx.y;
  const int w = tid >> 6, l = tid & 63, lr = l & 15, lq = l >> 4, kb = lq * 8;
  const int base = b * 128 + t;
  const u16* wrt  = (const u16*)(ws_b + BOFF_WRT);
  const u16* catC = (const u16*)(ws_b + BOFF_CATC);
  const u16* peh  = (const u16*)(ws_b + BOFF_PEH);
  const float* bidirG = ws_f + OFF_BIDIR;
  const float* brp = ws_f + OFF_BRP;

  xs[tid >> 2][tid & 3] = x[base*256 + tid];
  if (tid < 64) maskv[tid] = mask[base*64 + tid];
  #pragma unroll
  for (int k = 0; k < 5; ++k) {
    int idx = k * 256 + tid;
    ((u32*)catB)[idx] = ((const u32*)catC)[idx];
  }
  { // PE cols 10..25
    int j = tid & 63, c = tid >> 6;
    const u32* pesrc = (const u32*)(peh + base*16);
    u32* dst = (u32*)&catB[j][10];
    dst[2*c]   = pesrc[2*c];
    dst[2*c+1] = pesrc[2*c+1];
  }
  __syncthreads();

  { // P0: h build, lane -> e (coalesced); store hA + hT
    int e = tid & 63, s0 = (tid >> 6) * 16;
    #pragma unroll
    for (int si = 0; si < 16; si += 2) {
      int s = s0 + si, s1 = s + 1;
      float a0 = xs[s][0]*Wobs[(s*4+0)*64+e] + xs[s][1]*Wobs[(s*4+1)*64+e]
               + xs[s][2]*Wobs[(s*4+2)*64+e] + xs[s][3]*Wobs[(s*4+3)*64+e];
      a0 = fmaxf(a0, 0.f) * maskv[s];
      float a1 = xs[s1][0]*Wobs[(s1*4+0)*64+e] + xs[s1][1]*Wobs[(s1*4+1)*64+e]
               + xs[s1][2]*Wobs[(s1*4+2)*64+e] + xs[s1][3]*Wobs[(s1*4+3)*64+e];
      a1 = fmaxf(a1, 0.f) * maskv[s1];
      u32 p = pk2bf(a0, a1);
      hA[s][e] = (u16)p; hA[s1][e] = (u16)(p >> 16);
      *(u32*)&hT[e][s] = p;
    }
  }
  __syncthreads();

  { // P1: hm^T = WrT @ h^T -> hmA[s][d] (b64 packed)
    int m = w & 1, nb = (w >> 1) * 2;
    const u16* wr = wrt + (16*m + lr) * 64;
    short8 a0 = *(const short8*)&wr[kb];
    short8 a1 = *(const short8*)&wr[32 + kb];
    int d0 = 16*m + lq*4;
    float4 bv = *(const float4*)&brp[d0];
    #pragma unroll
    for (int nn = 0; nn < 2; ++nn) {
      int n = nb + nn;
      f32x4 acc = (f32x4){0.f,0.f,0.f,0.f};
      short8 b0 = *(const short8*)&hA[16*n + lr][kb];
      short8 b1 = *(const short8*)&hA[16*n + lr][32 + kb];
      acc = __builtin_amdgcn_mfma_f32_16x16x32_bf16(a0, b0, acc, 0, 0, 0);
      acc = __builtin_amdgcn_mfma_f32_16x16x32_bf16(a1, b1, acc, 0, 0, 0);
      uint2 qq;
      qq.x = pk2bf(acc[0]+bv.x, acc[1]+bv.y);
      qq.y = pk2bf(acc[2]+bv.z, acc[3]+bv.w);
      *(uint2*)&hmA[16*n + lr][d0] = qq;
    }
  }
  __syncthreads();

  { // P2: alpha -> w1 (wA); bidir read coalesced
    short8 am = *(const short8*)&hmA[16*w + lr][kb];
    int i0 = 16*w + lq*4;
    #pragma unroll
    for (int n = 0; n < 4; ++n) {
      f32x4 z = (f32x4){0.f,0.f,0.f,0.f};
      short8 bc = *(const short8*)&catB[16*n + lr][kb];
      z = __builtin_amdgcn_mfma_f32_16x16x32_bf16(am, bc, z, 0, 0, 0);
      int j = 16*n + lr;
      #pragma unroll
      for (int reg = 0; reg < 4; ++reg) {
        int i = i0 + reg;
        float w1 = fmaxf(z[reg], 0.f) * bidirG[(i << 6) + j];
        wA[i][j] = f2bf(w1);
      }
    }
  }
  __syncthreads();

  { // P3: h1 = relu(w1 @ h) -> h1T into hA; stage adjS -> LDS (overlay hmA/catB)
    const uint4* ag = (const uint4*)(ws_b + BOFF_ADJS + (size_t)b * 8192);
    int idx0 = 2*tid, idx1 = 2*tid + 1;
    uint4 g0 = ag[idx0], g1 = ag[idx1];          // coalesced, in flight during MFMAs

    short8 aw0 = *(const short8*)&wA[16*w + lr][kb];
    short8 aw1 = *(const short8*)&wA[16*w + lr][32 + kb];
    int i0 = 16*w + lq*4;
    #pragma unroll
    for (int n = 0; n < 4; ++n) {
      f32x4 acc = (f32x4){0.f,0.f,0.f,0.f};
      short8 b0 = *(const short8*)&hT[16*n + lr][kb];
      short8 b1 = *(const short8*)&hT[16*n + lr][32 + kb];
      acc = __builtin_amdgcn_mfma_f32_16x16x32_bf16(aw0, b0, acc, 0, 0, 0);
      acc = __builtin_amdgcn_mfma_f32_16x16x32_bf16(aw1, b1, acc, 0, 0, 0);
      int e = 16*n + lr;
      uint2 pp;
      pp.x = pk2bf(fmaxf(acc[0],0.f), fmaxf(acc[1],0.f));
      pp.y = pk2bf(fmaxf(acc[2],0.f), fmaxf(acc[3],0.f));
      *(uint2*)&hA[e][i0] = pp;   // h1T[e][i]
    }
    *(uint4*)&adjS[idx0 >> 3][(idx0 & 7) * 8] = g0;
    *(uint4*)&adjS[idx1 >> 3][(idx1 & 7) * 8] = g1;
  }
  __syncthreads();

  { // P4: w2 = w1 (.) adjS (both bf16, LDS fragments); h2 = relu(w2 @ h1) -> Hh
    int row = 16*w + lr;
    union { short8 v; u16 h[8]; u32 u[4]; } uw0, uw1, ud0, ud1, oa, ob;
    uw0.v = *(const short8*)&wA[row][kb];
    uw1.v = *(const short8*)&wA[row][32 + kb];
    ud0.v = *(const short8*)&adjS[row][kb];
    ud1.v = *(const short8*)&adjS[row][32 + kb];
    #pragma unroll
    for (int k = 0; k < 4; ++k) {
      oa.u[k] = pk2bf(bf2f(uw0.h[2*k])*bf2f(ud0.h[2*k]),
                      bf2f(uw0.h[2*k+1])*bf2f(ud0.h[2*k+1]));
      ob.u[k] = pk2bf(bf2f(uw1.h[2*k])*bf2f(ud1.h[2*k]),
                      bf2f(uw1.h[2*k+1])*bf2f(ud1.h[2*k+1]));
    }
    short8 a20 = oa.v, a21 = ob.v;
    int i0 = 16*w + lq*4;
    size_t obase = ((size_t)b * 64) * 8192 + (size_t)t * 64;
    #pragma unroll
    for (int n = 0; n < 4; ++n) {
      f32x4 acc = (f32x4){0.f,0.f,0.f,0.f};
      short8 b0 = *(const short8*)&hA[16*n + lr][kb];      // h1T
      short8 b1 = *(const short8*)&hA[16*n + lr][32 + kb];
      acc = __builtin_amdgcn_mfma_f32_16x16x32_bf16(a20, b0, acc, 0, 0, 0);
      acc = __builtin_amdgcn_mfma_f32_16x16x32_bf16(a21, b1, acc, 0, 0, 0);
      int e = 16*n + lr;
      u32 p0 = pk2bf(fmaxf(acc[0],0.f), fmaxf(acc[1],0.f));
      u32 p1 = pk2bf(fmaxf(acc[2],0.f), fmaxf(acc[3],0.f));
      Hh[obase + (size_t)(i0+0) * 8192 + e] = (u16)p0;
      Hh[obase + (size_t)(i0+1) * 8192 + e] = (u16)(p0 >> 16);
      Hh[obase + (size_t)(i0+2) * 8192 + e] = (u16)p1;
      Hh[obase + (size_t)(i0+3) * 8192 + e] = (u16)(p1 >> 16);
    }
  }
}

// ---------------- K3: collapsed temporal attention ----------------
#define HTP 82
#define PEP 17

__global__ __launch_bounds__(256)
void k_attn(const float* __restrict__ ws_f, const u16* __restrict__ Hh,
            const float* __restrict__ Wq, const float* __restrict__ bq,
            const float* __restrict__ Wk, const float* __restrict__ bk,
            const float* __restrict__ Ws, const float* __restrict__ bs,
            const float* __restrict__ Wemb, const float* __restrict__ bemb,
            float* __restrict__ out) {
  __shared__ u16 Ht[128][HTP];
  __shared__ float peB[128][PEP];
  __shared__ float wsL[128];
  __shared__ float pA[3][80];
  __shared__ float pK[8][10];
  __shared__ float KtilL[10];
  __shared__ float qvL[80];
  __shared__ float pC[2][128];
  __shared__ float bb[128];
  __shared__ float red[4];
  __shared__ float cstL, sWL;

  const int tid = threadIdx.x;
  const int s = blockIdx.x, b = blockIdx.y;
  const float scale = 0.111803398875f; // 1/sqrt(80)

  const u16* src = Hh + ((size_t)b * 64 + s) * 8192;
  #pragma unroll
  for (int r = 0; r < 4; ++r) {
    int id = r * 256 + tid;
    int tt = id >> 3, c = (id & 7) * 8;
    uint4 q = *(const uint4*)&src[tt * 64 + c];
    u32* dst = (u32*)&Ht[tt][c];
    dst[0] = q.x; dst[1] = q.y; dst[2] = q.z; dst[3] = q.w;
  }
  #pragma unroll
  for (int r = 0; r < 8; ++r) {
    int id = r * 256 + tid;
    peB[id >> 4][id & 15] = ws_f[OFF_PE + (size_t)b * 2048 + id];
  }
  if (tid < 128) wsL[tid] = Ws[tid];
  __syncthreads();

  if (tid < 240) {
    int d = tid % 80, c = tid / 80;
    int t0 = c * 43, t1 = (c == 2) ? 128 : t0 + 43;
    float acc = 0.f;
    if (d < 64) {
      for (int t = t0; t < t1; ++t) acc += wsL[t] * bf2f(Ht[t][d]);
    } else {
      int k = d - 64;
      for (int t = t0; t < t1; ++t) acc += wsL[t] * peB[t][k];
    }
    pA[c][d] = acc;
  } else if (tid == 240) {
    float sw = 0.f;
    for (int t = 0; t < 128; ++t) sw += wsL[t];
    sWL = sw;
  }
  __syncthreads();

  if (tid < 80) {
    int a = tid % 10, c = tid / 10;
    float acc = 0.f;
    #pragma unroll
    for (int i = 0; i < 10; ++i) {
      int d = c * 10 + i;
      float hb = pA[0][d] + pA[1][d] + pA[2][d];
      acc += hb * Wk[d * 10 + a];
    }
    pK[c][a] = acc;
  }
  __syncthreads();
  if (tid < 10) {
    float acc = sWL * bk[tid];
    #pragma unroll
    for (int c = 0; c < 8; ++c) acc += pK[c][tid];
    KtilL[tid] = acc;
  }
  __syncthreads();
  if (tid < 80) {
    float acc = 0.f;
    #pragma unroll
    for (int a = 0; a < 10; ++a) acc += Wq[tid * 10 + a] * KtilL[a];
    qvL[tid] = acc;
  } else if (tid == 80) {
    float cq = 0.f;
    #pragma unroll
    for (int a = 0; a < 10; ++a) cq += bq[a] * KtilL[a];
    cstL = scale * cq + bs[0];
  }
  __syncthreads();

  {
    int t = tid & 127, half = tid >> 7;
    float acc = 0.f;
    const u32* row = (const u32*)&Ht[t][0];
    if (half == 0) {
      #pragma unroll
      for (int i = 0; i < 20; ++i) {
        u32 p = row[i];
        acc += bf2f((u16)p) * qvL[2*i] + bf2f((u16)(p >> 16)) * qvL[2*i+1];
      }
    } else {
      #pragma unroll
      for (int i = 20; i < 32; ++i) {
        u32 p = row[i];
        acc += bf2f((u16)p) * qvL[2*i] + bf2f((u16)(p >> 16)) * qvL[2*i+1];
      }
      #pragma unroll
      for (int k = 0; k < 16; ++k) acc += peB[t][k] * qvL[64 + k];
    }
    pC[half][t] = acc;
  }
  __syncthreads();

  float ev = 0.f;
  if (tid < 128) {
    float v = scale * (pC[0][tid] + pC[1][tid]) + cstL;
    bb[tid] = v;
    float mm = v;
    #pragma unroll
    for (int off = 32; off; off >>= 1) mm = fmaxf(mm, __shfl_xor(mm, off));
    if ((tid & 63) == 0) red[tid >> 6] = mm;
  }
  __syncthreads();
  float m = fmaxf(red[0], red[1]);
  if (tid < 128) {
    ev = expf(bb[tid] - m);
    float ss = ev;
    #pragma unroll
    for (int off = 32; off; off >>= 1) ss += __shfl_xor(ss, off);
    if ((tid & 63) == 0) red[2 + (tid >> 6)] = ss;
  }
  __syncthreads();
  if (tid < 128) bb[tid] = ev / (red[2] + red[3]);
  __syncthreads();

  if (tid < 240) {
    int d = tid % 80, c = tid / 80;
    int t0 = c * 43, t1 = (c == 2) ? 128 : t0 + 43;
    float acc = 0.f;
    if (d < 64) {
      for (int t = t0; t < t1; ++t) acc += bb[t] * bf2f(Ht[t][d]);
    } else {
      int k = d - 64;
      for (int t = t0; t < t1; ++t) acc += bb[t] * peB[t][k];
    }
    pA[c][d] = acc;
  }
  __syncthreads();

  {
    int o = tid & 127, half = tid >> 7;
    int d0 = half * 40;
    float acc = 0.f;
    #pragma unroll
    for (int i = 0; i < 40; ++i) {
      int d = d0 + i;
      float hv = pA[0][d] + pA[1][d] + pA[2][d];
      acc += hv * Wemb[d * 128 + o];
    }
    pC[half][o] = acc;
  }
  __syncthreads();
  if (tid < 128) {
    out[(((size_t)b * 64 + s) << 7) + tid] = bemb[tid] + pC[0][tid] + pC[1][tid];
  }
}

extern "C" void kernel_launch(void* const* d_in, const int* in_sizes, int n_in,
                              void* d_out, int out_size, void* d_ws, size_t ws_size,
                              hipStream_t stream) {
  (void)in_sizes; (void)n_in; (void)out_size; (void)ws_size;
  const float* x     = (const float*)d_in[0];
  const float* times = (const float*)d_in[1];
  const float* mask  = (const float*)d_in[2];
  const float* Wobs  = (const float*)d_in[3];
  const float* Wattn = (const float*)d_in[4];
  const float* Wrecv = (const float*)d_in[5];
  const float* brecv = (const float*)d_in[6];
  const float* Wb    = (const float*)d_in[7];
  const float* Wq    = (const float*)d_in[8];
  const float* bq    = (const float*)d_in[9];
  const float* Wk    = (const float*)d_in[10];
  const float* bk    = (const float*)d_in[11];
  const float* Ws    = (const float*)d_in[12];
  const float* bs    = (const float*)d_in[13];
  const float* Wemb  = (const float*)d_in[14];
  const float* bemb  = (const float*)d_in[15];
  float* out = (float*)d_out;
  float* ws_f = (float*)d_ws;
  char* ws_b = (char*)d_ws;
  u16* Hh = (u16*)(ws_b + BOFF_HH);

  hipMemsetAsync(ws_b + (size_t)OFF_ADJ * 4, 0, (size_t)64 * 64 * 64 * 4, stream);
  k_pre<<<98, 256, 0, stream>>>(times, mask, Wb, Wrecv, brecv, Wattn, ws_f, ws_b);
  k_adj<<<dim3(16, 64), 256, 0, stream>>>(x, mask, Wobs, ws_f, ws_b);
  k_scale<<<64, 256, 0, stream>>>(ws_f, ws_b);
  k_main<<<dim3(128, 64), 256, 0, stream>>>(x, mask, Wobs, ws_f, ws_b, Hh);
  k_attn<<<dim3(64, 64), 256, 0, stream>>>(ws_f, Hh, Wq, bq, Wk, bk, Ws, bs, Wemb, bemb, out);
}

// Round 5
// 200.224 us; speedup vs baseline: 1.2706x; 1.0036x over previous
//
#include <hip/hip_runtime.h>
#include <hip/hip_bf16.h>

// Raindrop forward, MI355X. B=64 T=128 S=64 O=4 E=64 P=16 A=10 OUT=128.
//  - temporal attention collapsed: (Q K^T) W_s = Q (W_s^T K)  -> no TxT matrix
//  - per-(b,t) chain in bf16 MFMA 16x16x32; LDS 38.3KB -> 4 blocks/CU
//  - h-build remap: thread=(4e,4s) -> float4 Wobs loads (16 vs 64 VMEM/thread)
//  - k_main: 2 t per block; bidir in regs; hT rebuilt from hA in P1 phase
//  - adjS (= sum_t alpha / masksum, bf16) precomputed by k_scale; staged to LDS
// ws floats: PE[131072] | bidir[4096] | masksum[4096] | adjnum[262144] | brp[32]
// ws bytes @: WrT 1605760 | catC 1609856 | PEh 1614976 | adjS 1877120 | Hh 2401408

typedef unsigned short u16;
typedef unsigned int u32;
typedef __attribute__((ext_vector_type(8))) short short8;
typedef __attribute__((ext_vector_type(4))) float f32x4;

#define OFF_PE    0
#define OFF_BIDIR 131072
#define OFF_MS    135168
#define OFF_ADJ   139264
#define OFF_BRP   401408
#define BOFF_WRT  1605760u
#define BOFF_CATC 1609856u
#define BOFF_PEH  1614976u
#define BOFF_ADJS 1877120u
#define BOFF_HH   2401408u

__device__ __forceinline__ u16 f2bf(float f){
  __hip_bfloat16 h = __float2bfloat16(f);
  union { __hip_bfloat16 h; u16 u; } v; v.h = h; return v.u;
}
__device__ __forceinline__ u32 pk2bf(float lo, float hi){
  __hip_bfloat162 h = __float22bfloat162_rn(float2{lo, hi});
  union { __hip_bfloat162 h; u32 u; } v; v.h = h; return v.u;
}
__device__ __forceinline__ float bf2f(u16 h){
  union { u32 u; float f; } v; v.u = ((u32)h) << 16; return v.f;
}

// ---------------- K0: PE (f32+bf16), bidir, WrT, brp, catC, masksum ----------------
__global__ void k_pre(const float* __restrict__ times, const float* __restrict__ mask,
                      const float* __restrict__ Wb, const float* __restrict__ Wrecv,
                      const float* __restrict__ brecv, const float* __restrict__ battn,
                      float* __restrict__ ws_f, char* __restrict__ ws_b) {
  const int blk = blockIdx.x, tid = threadIdx.x;
  u16* wrt  = (u16*)(ws_b + BOFF_WRT);
  u16* catC = (u16*)(ws_b + BOFF_CATC);
  u16* peh  = (u16*)(ws_b + BOFF_PEH);
  if (blk < 256) {                     // PE: (B*T,16) sin|cos, f32 + bf16
    float* PE = ws_f + OFF_PE;
    #pragma unroll
    for (int r = 0; r < 2; ++r) {
      int id = blk * 512 + r * 256 + tid;
      int bt = id >> 4, k = id & 15;
      float tv = times[bt];
      int kk = k & 7;
      float fr = expf(-(float)kk * 1.1512925465f); // ln(1e4)/8
      float ang = tv * fr;
      float v = (k < 8) ? sinf(ang) : cosf(ang);
      PE[id] = v;
      peh[id] = f2bf(v);
    }
  } else if (blk == 256) {             // bidir = Wb @ Wb^T
    float* bidir = ws_f + OFF_BIDIR;
    for (int r = 0; r < 16; ++r) {
      int idx = r * 256 + tid;
      int i = idx >> 6, j = idx & 63;
      float acc = 0.f;
      for (int e = 0; e < 64; ++e) acc += Wb[i*64+e] * Wb[j*64+e];
      bidir[idx] = acc;
    }
  } else if (blk == 257) {             // WrT, brp, catC
    for (int r = 0; r < 8; ++r) {
      int idx = r * 256 + tid;
      int d = idx >> 6, e = idx & 63;
      wrt[idx] = (d < 26) ? f2bf(Wrecv[e*26 + d]) : (u16)0;
    }
    if (tid < 32) ws_f[OFF_BRP + tid] = (tid < 26) ? brecv[tid] : 0.f;
    for (int r = 0; r < 10; ++r) {
      int idx = r * 256 + tid;          // 2560 = 64*40
      int j = idx / 40, d = idx % 40;
      catC[idx] = (d < 10) ? f2bf(battn[j*10 + d]) : (u16)0;
    }
  } else {                             // masksum[b][i]
    int b = blk - 258;
    if (tid < 64) {
      float s = 0.f;
      for (int t = 0; t < 128; ++t) s += mask[(b*128 + t)*64 + tid];
      (ws_f + OFF_MS)[b*64 + tid] = s;
    }
  }
}

// ---------------- K1: adj2 numerator (sum_t alpha) ----------------
__global__ __launch_bounds__(256)
void k_adj(const float* __restrict__ x, const float* __restrict__ mask,
           const float* __restrict__ Wobs, float* __restrict__ ws_f,
           const char* __restrict__ ws_b) {
  __shared__ __align__(16) u16 hA[64][72];
  __shared__ __align__(16) u16 hmA[64][40];
  __shared__ __align__(16) u16 catB[64][40];
  __shared__ float xs[64][4];
  __shared__ float maskv[64];

  const int tid = threadIdx.x;
  const int b = blockIdx.y, tc = blockIdx.x;
  const int w = tid >> 6, l = tid & 63, lr = l & 15, lq = l >> 4, kb = lq * 8;
  const u16* wrt  = (const u16*)(ws_b + BOFF_WRT);
  const u16* catC = (const u16*)(ws_b + BOFF_CATC);
  const u16* peh  = (const u16*)(ws_b + BOFF_PEH);
  const float* brp = ws_f + OFF_BRP;
  float* adj = ws_f + OFF_ADJ;

  #pragma unroll
  for (int k = 0; k < 5; ++k) {        // catB const part (1280 u32)
    int idx = k * 256 + tid;
    ((u32*)catB)[idx] = ((const u32*)catC)[idx];
  }

  f32x4 asum[4];
  #pragma unroll
  for (int n = 0; n < 4; ++n) asum[n] = (f32x4){0.f,0.f,0.f,0.f};

  for (int tt = 0; tt < 8; ++tt) {
    int t = tc * 8 + tt;
    int base = b * 128 + t;
    __syncthreads();
    xs[tid >> 2][tid & 3] = x[base*256 + tid];
    if (tid < 64) maskv[tid] = mask[base*64 + tid];
    { // PE cols 10..25 of catB
      int j = tid & 63, c = tid >> 6;
      const u32* pesrc = (const u32*)(peh + base*16);
      u32* dst = (u32*)&catB[j][10];
      dst[2*c]   = pesrc[2*c];
      dst[2*c+1] = pesrc[2*c+1];
    }
    __syncthreads();
    { // P0: h build, thread=(e4,sg): float4 Wobs loads
      const int e4 = tid & 15, sg = tid >> 4;
      #pragma unroll
      for (int si = 0; si < 4; ++si) {
        int s = sg*4 + si;
        float ax = 0.f, ay = 0.f, az = 0.f, aw = 0.f;
        #pragma unroll
        for (int o = 0; o < 4; ++o) {
          float xo = xs[s][o];
          float4 wv = *(const float4*)&Wobs[(s*4+o)*64 + e4*4];
          ax += xo*wv.x; ay += xo*wv.y; az += xo*wv.z; aw += xo*wv.w;
        }
        float mk = maskv[s];
        uint2 p;
        p.x = pk2bf(fmaxf(ax,0.f)*mk, fmaxf(ay,0.f)*mk);
        p.y = pk2bf(fmaxf(az,0.f)*mk, fmaxf(aw,0.f)*mk);
        *(uint2*)&hA[s][e4*4] = p;
      }
    }
    __syncthreads();
    { // P1: hm^T = WrT @ h^T -> hmA[s][d] (b64 packed)
      int m = w & 1, nb = (w >> 1) * 2;
      const u16* wr = wrt + (16*m + lr) * 64;
      short8 a0 = *(const short8*)&wr[kb];
      short8 a1 = *(const short8*)&wr[32 + kb];
      int d0 = 16*m + lq*4;
      float4 bv = *(const float4*)&brp[d0];
      #pragma unroll
      for (int nn = 0; nn < 2; ++nn) {
        int n = nb + nn;
        f32x4 acc = (f32x4){0.f,0.f,0.f,0.f};
        short8 b0 = *(const short8*)&hA[16*n + lr][kb];
        short8 b1 = *(const short8*)&hA[16*n + lr][32 + kb];
        acc = __builtin_amdgcn_mfma_f32_16x16x32_bf16(a0, b0, acc, 0, 0, 0);
        acc = __builtin_amdgcn_mfma_f32_16x16x32_bf16(a1, b1, acc, 0, 0, 0);
        uint2 qq;
        qq.x = pk2bf(acc[0]+bv.x, acc[1]+bv.y);
        qq.y = pk2bf(acc[2]+bv.z, acc[3]+bv.w);
        *(uint2*)&hmA[16*n + lr][d0] = qq;
      }
    }
    __syncthreads();
    { // P2: alpha accumulate
      short8 am = *(const short8*)&hmA[16*w + lr][kb];
      #pragma unroll
      for (int n = 0; n < 4; ++n) {
        f32x4 z = (f32x4){0.f,0.f,0.f,0.f};
        short8 bc = *(const short8*)&catB[16*n + lr][kb];
        z = __builtin_amdgcn_mfma_f32_16x16x32_bf16(am, bc, z, 0, 0, 0);
        #pragma unroll
        for (int reg = 0; reg < 4; ++reg) asum[n][reg] += fmaxf(z[reg], 0.f);
      }
    }
  }
  #pragma unroll
  for (int n = 0; n < 4; ++n) {
    #pragma unroll
    for (int reg = 0; reg < 4; ++reg) {
      int i = 16*w + lq*4 + reg, j = 16*n + lr;
      atomicAdd(&adj[((size_t)b << 12) + (i << 6) + j], asum[n][reg]);
    }
  }
}

// ---------------- K1b: adjS = bf16(adjnum / masksum) ----------------
__global__ __launch_bounds__(256)
void k_scale(const float* __restrict__ ws_f, char* __restrict__ ws_b) {
  const int b = blockIdx.x, tid = threadIdx.x;
  const float* adj = ws_f + OFF_ADJ + (size_t)b * 4096;
  const float* ms = ws_f + OFF_MS + b * 64;
  u16* as_ = (u16*)(ws_b + BOFF_ADJS) + (size_t)b * 4096;
  #pragma unroll
  for (int k = 0; k < 16; ++k) {
    int idx = k * 256 + tid;
    int i = idx >> 6;
    as_[idx] = f2bf(adj[idx] / ms[i]);
  }
}

// ---------------- K2: full per-(b,t) chain -> Hh bf16 (2 t per block) ----------------
__global__ __launch_bounds__(256)
void k_main(const float* __restrict__ x, const float* __restrict__ mask,
            const float* __restrict__ Wobs, const float* __restrict__ ws_f,
            const char* __restrict__ ws_b, u16* __restrict__ Hh) {
  __shared__ __align__(16) char smem[39168];
  u16 (*hA)[72]  = (u16 (*)[72])(smem);           // h [s][e]; later h1T [e][i]
  u16 (*hT)[72]  = (u16 (*)[72])(smem + 9216);    // h^T [e][s]
  u16 (*wA)[72]  = (u16 (*)[72])(smem + 18432);   // w1 [i][j]
  u16 (*hmA)[40] = (u16 (*)[40])(smem + 27648);   // h_map [s][d]   (dead after P2)
  u16 (*catB)[40]= (u16 (*)[40])(smem + 32768);   //                (dead after P2)
  u16 (*adjS)[72]= (u16 (*)[72])(smem + 27648);   // overlay, staged in P3
  float (*xs)[4] = (float (*)[4])(smem + 37888);
  float* maskv   = (float*)(smem + 38912);

  const int tid = threadIdx.x;
  const int b = blockIdx.y;
  const int w = tid >> 6, l = tid & 63, lr = l & 15, lq = l >> 4, kb = lq * 8;
  const u16* wrt  = (const u16*)(ws_b + BOFF_WRT);
  const u16* catC = (const u16*)(ws_b + BOFF_CATC);
  const u16* peh  = (const u16*)(ws_b + BOFF_PEH);
  const float* bidirG = ws_f + OFF_BIDIR;
  const float* brp = ws_f + OFF_BRP;
  const int i0 = 16*w + lq*4;

  float bid[4][4];                      // bidir, reused across both t
  #pragma unroll
  for (int n = 0; n < 4; ++n)
    #pragma unroll
    for (int reg = 0; reg < 4; ++reg)
      bid[n][reg] = bidirG[((i0+reg) << 6) + 16*n + lr];

  for (int th = 0; th < 2; ++th) {
    const int t = blockIdx.x * 2 + th;
    const int base = b * 128 + t;
    __syncthreads();                    // vs prev P4 reads of overlay/hA/wA
    // stage: xs, mask, catB const (zeros in cols 10.. get PE'd next phase)
    xs[tid >> 2][tid & 3] = x[base*256 + tid];
    if (tid < 64) maskv[tid] = mask[base*64 + tid];
    #pragma unroll
    for (int k = 0; k < 5; ++k) {
      int idx = k * 256 + tid;
      ((u32*)catB)[idx] = ((const u32*)catC)[idx];
    }
    __syncthreads();

    { // P0a: h build, thread=(e4,sg) float4 Wobs; + PE cols of catB
      const int e4 = tid & 15, sg = tid >> 4;
      #pragma unroll
      for (int si = 0; si < 4; ++si) {
        int s = sg*4 + si;
        float ax = 0.f, ay = 0.f, az = 0.f, aw = 0.f;
        #pragma unroll
        for (int o = 0; o < 4; ++o) {
          float xo = xs[s][o];
          float4 wv = *(const float4*)&Wobs[(s*4+o)*64 + e4*4];
          ax += xo*wv.x; ay += xo*wv.y; az += xo*wv.z; aw += xo*wv.w;
        }
        float mk = maskv[s];
        uint2 p;
        p.x = pk2bf(fmaxf(ax,0.f)*mk, fmaxf(ay,0.f)*mk);
        p.y = pk2bf(fmaxf(az,0.f)*mk, fmaxf(aw,0.f)*mk);
        *(uint2*)&hA[s][e4*4] = p;
      }
      int j = tid & 63, c = tid >> 6;
      const u32* pesrc = (const u32*)(peh + base*16);
      u32* dst = (u32*)&catB[j][10];
      dst[2*c]   = pesrc[2*c];
      dst[2*c+1] = pesrc[2*c+1];
    }
    __syncthreads();

    { // P0b: hT from hA (rides P1's phase)
      #pragma unroll
      for (int sp = 0; sp < 8; ++sp) {
        int s = w*16 + sp*2;
        *(u32*)&hT[l][s] = (u32)hA[s][l] | ((u32)hA[s+1][l] << 16);
      }
    }
    { // P1: hm^T = WrT @ h^T -> hmA[s][d] (b64 packed)
      int m = w & 1, nb = (w >> 1) * 2;
      const u16* wr = wrt + (16*m + lr) * 64;
      short8 a0 = *(const short8*)&wr[kb];
      short8 a1 = *(const short8*)&wr[32 + kb];
      int d0 = 16*m + lq*4;
      float4 bv = *(const float4*)&brp[d0];
      #pragma unroll
      for (int nn = 0; nn < 2; ++nn) {
        int n = nb + nn;
        f32x4 acc = (f32x4){0.f,0.f,0.f,0.f};
        short8 b0 = *(const short8*)&hA[16*n + lr][kb];
        short8 b1 = *(const short8*)&hA[16*n + lr][32 + kb];
        acc = __builtin_amdgcn_mfma_f32_16x16x32_bf16(a0, b0, acc, 0, 0, 0);
        acc = __builtin_amdgcn_mfma_f32_16x16x32_bf16(a1, b1, acc, 0, 0, 0);
        uint2 qq;
        qq.x = pk2bf(acc[0]+bv.x, acc[1]+bv.y);
        qq.y = pk2bf(acc[2]+bv.z, acc[3]+bv.w);
        *(uint2*)&hmA[16*n + lr][d0] = qq;
      }
    }
    __syncthreads();

    { // P2: alpha -> w1 (wA); bidir from regs
      short8 am = *(const short8*)&hmA[16*w + lr][kb];
      #pragma unroll
      for (int n = 0; n < 4; ++n) {
        f32x4 z = (f32x4){0.f,0.f,0.f,0.f};
        short8 bc = *(const short8*)&catB[16*n + lr][kb];
        z = __builtin_amdgcn_mfma_f32_16x16x32_bf16(am, bc, z, 0, 0, 0);
        int j = 16*n + lr;
        #pragma unroll
        for (int reg = 0; reg < 4; ++reg) {
          float w1 = fmaxf(z[reg], 0.f) * bid[n][reg];
          wA[i0 + reg][j] = f2bf(w1);
        }
      }
    }
    __syncthreads();

    { // P3: h1 = relu(w1 @ h) -> h1T into hA; stage adjS (overlay hmA/catB)
      const uint4* ag = (const uint4*)(ws_b + BOFF_ADJS + (size_t)b * 8192);
      int idx0 = 2*tid, idx1 = 2*tid + 1;
      uint4 g0 = ag[idx0], g1 = ag[idx1];        // in flight during MFMAs

      short8 aw0 = *(const short8*)&wA[16*w + lr][kb];
      short8 aw1 = *(const short8*)&wA[16*w + lr][32 + kb];
      #pragma unroll
      for (int n = 0; n < 4; ++n) {
        f32x4 acc = (f32x4){0.f,0.f,0.f,0.f};
        short8 b0 = *(const short8*)&hT[16*n + lr][kb];
        short8 b1 = *(const short8*)&hT[16*n + lr][32 + kb];
        acc = __builtin_amdgcn_mfma_f32_16x16x32_bf16(aw0, b0, acc, 0, 0, 0);
        acc = __builtin_amdgcn_mfma_f32_16x16x32_bf16(aw1, b1, acc, 0, 0, 0);
        int e = 16*n + lr;
        uint2 pp;
        pp.x = pk2bf(fmaxf(acc[0],0.f), fmaxf(acc[1],0.f));
        pp.y = pk2bf(fmaxf(acc[2],0.f), fmaxf(acc[3],0.f));
        *(uint2*)&hA[e][i0] = pp;   // h1T[e][i]
      }
      *(uint4*)&adjS[idx0 >> 3][(idx0 & 7) * 8] = g0;
      *(uint4*)&adjS[idx1 >> 3][(idx1 & 7) * 8] = g1;
    }
    __syncthreads();

    { // P4: w2 = w1 (.) adjS; h2 = relu(w2 @ h1) -> Hh
      int row = 16*w + lr;
      union { short8 v; u16 h[8]; u32 u[4]; } uw0, uw1, ud0, ud1, oa, ob;
      uw0.v = *(const short8*)&wA[row][kb];
      uw1.v = *(const short8*)&wA[row][32 + kb];
      ud0.v = *(const short8*)&adjS[row][kb];
      ud1.v = *(const short8*)&adjS[row][32 + kb];
      #pragma unroll
      for (int k = 0; k < 4; ++k) {
        oa.u[k] = pk2bf(bf2f(uw0.h[2*k])*bf2f(ud0.h[2*k]),
                        bf2f(uw0.h[2*k+1])*bf2f(ud0.h[2*k+1]));
        ob.u[k] = pk2bf(bf2f(uw1.h[2*k])*bf2f(ud1.h[2*k]),
                        bf2f(uw1.h[2*k+1])*bf2f(ud1.h[2*k+1]));
      }
      short8 a20 = oa.v, a21 = ob.v;
      size_t obase = ((size_t)b * 64) * 8192 + (size_t)t * 64;
      #pragma unroll
      for (int n = 0; n < 4; ++n) {
        f32x4 acc = (f32x4){0.f,0.f,0.f,0.f};
        short8 b0 = *(const short8*)&hA[16*n + lr][kb];      // h1T
        short8 b1 = *(const short8*)&hA[16*n + lr][32 + kb];
        acc = __builtin_amdgcn_mfma_f32_16x16x32_bf16(a20, b0, acc, 0, 0, 0);
        acc = __builtin_amdgcn_mfma_f32_16x16x32_bf16(a21, b1, acc, 0, 0, 0);
        int e = 16*n + lr;
        u32 p0 = pk2bf(fmaxf(acc[0],0.f), fmaxf(acc[1],0.f));
        u32 p1 = pk2bf(fmaxf(acc[2],0.f), fmaxf(acc[3],0.f));
        Hh[obase + (size_t)(i0+0) * 8192 + e] = (u16)p0;
        Hh[obase + (size_t)(i0+1) * 8192 + e] = (u16)(p0 >> 16);
        Hh[obase + (size_t)(i0+2) * 8192 + e] = (u16)p1;
        Hh[obase + (size_t)(i0+3) * 8192 + e] = (u16)(p1 >> 16);
      }
    }
  }
}

// ---------------- K3: collapsed temporal attention ----------------
#define HTP 82
#define PEP 17

__global__ __launch_bounds__(256)
void k_attn(const float* __restrict__ ws_f, const u16* __restrict__ Hh,
            const float* __restrict__ Wq, const float* __restrict__ bq,
            const float* __restrict__ Wk, const float* __restrict__ bk,
            const float* __restrict__ Ws, const float* __restrict__ bs,
            const float* __restrict__ Wemb, const float* __restrict__ bemb,
            float* __restrict__ out) {
  __shared__ u16 Ht[128][HTP];
  __shared__ float peB[128][PEP];
  __shared__ float wsL[128];
  __shared__ float pA[3][80];
  __shared__ float pK[8][10];
  __shared__ float KtilL[10];
  __shared__ float qvL[80];
  __shared__ float pC[2][128];
  __shared__ float bb[128];
  __shared__ float red[4];
  __shared__ float cstL, sWL;

  const int tid = threadIdx.x;
  const int s = blockIdx.x, b = blockIdx.y;
  const float scale = 0.111803398875f; // 1/sqrt(80)

  const u16* src = Hh + ((size_t)b * 64 + s) * 8192;
  #pragma unroll
  for (int r = 0; r < 4; ++r) {
    int id = r * 256 + tid;
    int tt = id >> 3, c = (id & 7) * 8;
    uint4 q = *(const uint4*)&src[tt * 64 + c];
    u32* dst = (u32*)&Ht[tt][c];
    dst[0] = q.x; dst[1] = q.y; dst[2] = q.z; dst[3] = q.w;
  }
  #pragma unroll
  for (int r = 0; r < 8; ++r) {
    int id = r * 256 + tid;
    peB[id >> 4][id & 15] = ws_f[OFF_PE + (size_t)b * 2048 + id];
  }
  if (tid < 128) wsL[tid] = Ws[tid];
  __syncthreads();

  if (tid < 240) {
    int d = tid % 80, c = tid / 80;
    int t0 = c * 43, t1 = (c == 2) ? 128 : t0 + 43;
    float acc = 0.f;
    if (d < 64) {
      for (int t = t0; t < t1; ++t) acc += wsL[t] * bf2f(Ht[t][d]);
    } else {
      int k = d - 64;
      for (int t = t0; t < t1; ++t) acc += wsL[t] * peB[t][k];
    }
    pA[c][d] = acc;
  } else if (tid == 240) {
    float sw = 0.f;
    for (int t = 0; t < 128; ++t) sw += wsL[t];
    sWL = sw;
  }
  __syncthreads();

  if (tid < 80) {
    int a = tid % 10, c = tid / 10;
    float acc = 0.f;
    #pragma unroll
    for (int i = 0; i < 10; ++i) {
      int d = c * 10 + i;
      float hb = pA[0][d] + pA[1][d] + pA[2][d];
      acc += hb * Wk[d * 10 + a];
    }
    pK[c][a] = acc;
  }
  __syncthreads();
  if (tid < 10) {
    float acc = sWL * bk[tid];
    #pragma unroll
    for (int c = 0; c < 8; ++c) acc += pK[c][tid];
    KtilL[tid] = acc;
  }
  __syncthreads();
  if (tid < 80) {
    float acc = 0.f;
    #pragma unroll
    for (int a = 0; a < 10; ++a) acc += Wq[tid * 10 + a] * KtilL[a];
    qvL[tid] = acc;
  } else if (tid == 80) {
    float cq = 0.f;
    #pragma unroll
    for (int a = 0; a < 10; ++a) cq += bq[a] * KtilL[a];
    cstL = scale * cq + bs[0];
  }
  __syncthreads();

  {
    int t = tid & 127, half = tid >> 7;
    float acc = 0.f;
    const u32* row = (const u32*)&Ht[t][0];
    if (half == 0) {
      #pragma unroll
      for (int i = 0; i < 20; ++i) {
        u32 p = row[i];
        acc += bf2f((u16)p) * qvL[2*i] + bf2f((u16)(p >> 16)) * qvL[2*i+1];
      }
    } else {
      #pragma unroll
      for (int i = 20; i < 32; ++i) {
        u32 p = row[i];
        acc += bf2f((u16)p) * qvL[2*i] + bf2f((u16)(p >> 16)) * qvL[2*i+1];
      }
      #pragma unroll
      for (int k = 0; k < 16; ++k) acc += peB[t][k] * qvL[64 + k];
    }
    pC[half][t] = acc;
  }
  __syncthreads();

  float ev = 0.f;
  if (tid < 128) {
    float v = scale * (pC[0][tid] + pC[1][tid]) + cstL;
    bb[tid] = v;
    float mm = v;
    #pragma unroll
    for (int off = 32; off; off >>= 1) mm = fmaxf(mm, __shfl_xor(mm, off));
    if ((tid & 63) == 0) red[tid >> 6] = mm;
  }
  __syncthreads();
  float m = fmaxf(red[0], red[1]);
  if (tid < 128) {
    ev = expf(bb[tid] - m);
    float ss = ev;
    #pragma unroll
    for (int off = 32; off; off >>= 1) ss += __shfl_xor(ss, off);
    if ((tid & 63) == 0) red[2 + (tid >> 6)] = ss;
  }
  __syncthreads();
  if (tid < 128) bb[tid] = ev / (red[2] + red[3]);
  __syncthreads();

  if (tid < 240) {
    int d = tid % 80, c = tid / 80;
    int t0 = c * 43, t1 = (c == 2) ? 128 : t0 + 43;
    float acc = 0.f;
    if (d < 64) {
      for (int t = t0; t < t1; ++t) acc += bb[t] * bf2f(Ht[t][d]);
    } else {
      int k = d - 64;
      for (int t = t0; t < t1; ++t) acc += bb[t] * peB[t][k];
    }
    pA[c][d] = acc;
  }
  __syncthreads();

  {
    int o = tid & 127, half = tid >> 7;
    int d0 = half * 40;
    float acc = 0.f;
    #pragma unroll
    for (int i = 0; i < 40; ++i) {
      int d = d0 + i;
      float hv = pA[0][d] + pA[1][d] + pA[2][d];
      acc += hv * Wemb[d * 128 + o];
    }
    pC[half][o] = acc;
  }
  __syncthreads();
  if (tid < 128) {
    out[(((size_t)b * 64 + s) << 7) + tid] = bemb[tid] + pC[0][tid] + pC[1][tid];
  }
}

extern "C" void kernel_launch(void* const* d_in, const int* in_sizes, int n_in,
                              void* d_out, int out_size, void* d_ws, size_t ws_size,
                              hipStream_t stream) {
  (void)in_sizes; (void)n_in; (void)out_size; (void)ws_size;
  const float* x     = (const float*)d_in[0];
  const float* times = (const float*)d_in[1];
  const float* mask  = (const float*)d_in[2];
  const float* Wobs  = (const float*)d_in[3];
  const float* Wattn = (const float*)d_in[4];
  const float* Wrecv = (const float*)d_in[5];
  const float* brecv = (const float*)d_in[6];
  const float* Wb    = (const float*)d_in[7];
  const float* Wq    = (const float*)d_in[8];
  const float* bq    = (const float*)d_in[9];
  const float* Wk    = (const float*)d_in[10];
  const float* bk    = (const float*)d_in[11];
  const float* Ws    = (const float*)d_in[12];
  const float* bs    = (const float*)d_in[13];
  const float* Wemb  = (const float*)d_in[14];
  const float* bemb  = (const float*)d_in[15];
  float* out = (float*)d_out;
  float* ws_f = (float*)d_ws;
  char* ws_b = (char*)d_ws;
  u16* Hh = (u16*)(ws_b + BOFF_HH);

  hipMemsetAsync(ws_b + (size_t)OFF_ADJ * 4, 0, (size_t)64 * 64 * 64 * 4, stream);
  k_pre<<<322, 256, 0, stream>>>(times, mask, Wb, Wrecv, brecv, Wattn, ws_f, ws_b);
  k_adj<<<dim3(16, 64), 256, 0, stream>>>(x, mask, Wobs, ws_f, ws_b);
  k_scale<<<64, 256, 0, stream>>>(ws_f, ws_b);
  k_main<<<dim3(64, 64), 256, 0, stream>>>(x, mask, Wobs, ws_f, ws_b, Hh);
  k_attn<<<dim3(64, 64), 256, 0, stream>>>(ws_f, Hh, Wq, bq, Wk, bk, Ws, bs, Wemb, bemb, out);
}

// Round 6
// 197.707 us; speedup vs baseline: 1.2868x; 1.0127x over previous
//
#include <hip/hip_runtime.h>
#include <hip/hip_bf16.h>

// Raindrop forward, MI355X. B=64 T=128 S=64 O=4 E=64 P=16 A=10 OUT=128.
//  - temporal attention collapsed: (Q K^T) W_s = Q (W_s^T K)  -> no TxT matrix
//  - per-(b,t) chain in bf16 MFMA 16x16x32; 1 t/block; 4 barriers/block
//  - direct per-thread x/mask loads (L1 broadcast) -> no staging phase
//  - adjS/WrT prefetched at kernel entry; latency hidden under h-build
// ws floats: PE[131072] | bidir[4096] | masksum[4096] | adjnum[262144] | brp[32]
// ws bytes @: WrT 1605760 | catC 1609856 | PEh 1614976 | adjS 1877120 | Hh 2401408

typedef unsigned short u16;
typedef unsigned int u32;
typedef __attribute__((ext_vector_type(8))) short short8;
typedef __attribute__((ext_vector_type(4))) float f32x4;

#define OFF_PE    0
#define OFF_BIDIR 131072
#define OFF_MS    135168
#define OFF_ADJ   139264
#define OFF_BRP   401408
#define BOFF_WRT  1605760u
#define BOFF_CATC 1609856u
#define BOFF_PEH  1614976u
#define BOFF_ADJS 1877120u
#define BOFF_HH   2401408u

__device__ __forceinline__ u16 f2bf(float f){
  __hip_bfloat16 h = __float2bfloat16(f);
  union { __hip_bfloat16 h; u16 u; } v; v.h = h; return v.u;
}
__device__ __forceinline__ u32 pk2bf(float lo, float hi){
  __hip_bfloat162 h = __float22bfloat162_rn(float2{lo, hi});
  union { __hip_bfloat162 h; u32 u; } v; v.h = h; return v.u;
}
__device__ __forceinline__ float bf2f(u16 h){
  union { u32 u; float f; } v; v.u = ((u32)h) << 16; return v.f;
}

// ---------------- K0: PE (f32+bf16), bidir, WrT, brp, catC, masksum ----------------
__global__ void k_pre(const float* __restrict__ times, const float* __restrict__ mask,
                      const float* __restrict__ Wb, const float* __restrict__ Wrecv,
                      const float* __restrict__ brecv, const float* __restrict__ battn,
                      float* __restrict__ ws_f, char* __restrict__ ws_b) {
  __shared__ float pm[4][64];
  const int blk = blockIdx.x, tid = threadIdx.x;
  u16* wrt  = (u16*)(ws_b + BOFF_WRT);
  u16* catC = (u16*)(ws_b + BOFF_CATC);
  u16* peh  = (u16*)(ws_b + BOFF_PEH);
  if (blk < 256) {                     // PE: (B*T,16) sin|cos, f32 + bf16
    float* PE = ws_f + OFF_PE;
    #pragma unroll
    for (int r = 0; r < 2; ++r) {
      int id = blk * 512 + r * 256 + tid;
      int bt = id >> 4, k = id & 15;
      float tv = times[bt];
      int kk = k & 7;
      float fr = expf(-(float)kk * 1.1512925465f); // ln(1e4)/8
      float ang = tv * fr;
      float v = (k < 8) ? sinf(ang) : cosf(ang);
      PE[id] = v;
      peh[id] = f2bf(v);
    }
  } else if (blk == 256) {             // bidir = Wb @ Wb^T
    float* bidir = ws_f + OFF_BIDIR;
    for (int r = 0; r < 16; ++r) {
      int idx = r * 256 + tid;
      int i = idx >> 6, j = idx & 63;
      float acc = 0.f;
      for (int e = 0; e < 64; ++e) acc += Wb[i*64+e] * Wb[j*64+e];
      bidir[idx] = acc;
    }
  } else if (blk == 257) {             // WrT, brp, catC
    for (int r = 0; r < 8; ++r) {
      int idx = r * 256 + tid;
      int d = idx >> 6, e = idx & 63;
      wrt[idx] = (d < 26) ? f2bf(Wrecv[e*26 + d]) : (u16)0;
    }
    if (tid < 32) ws_f[OFF_BRP + tid] = (tid < 26) ? brecv[tid] : 0.f;
    for (int r = 0; r < 10; ++r) {
      int idx = r * 256 + tid;          // 2560 = 64*40
      int j = idx / 40, d = idx % 40;
      catC[idx] = (d < 10) ? f2bf(battn[j*10 + d]) : (u16)0;
    }
  } else {                             // masksum[b][i], 4-partial reduce
    int b = blk - 258;
    int i = tid & 63, q = tid >> 6;
    float s = 0.f;
    for (int t = q*32; t < q*32 + 32; ++t) s += mask[(b*128 + t)*64 + i];
    pm[q][i] = s;
    __syncthreads();
    if (tid < 64)
      (ws_f + OFF_MS)[b*64 + tid] = pm[0][tid] + pm[1][tid] + pm[2][tid] + pm[3][tid];
  }
}

// ---------------- K1: adj2 numerator (sum_t alpha) ----------------
__global__ __launch_bounds__(256)
void k_adj(const float* __restrict__ x, const float* __restrict__ mask,
           const float* __restrict__ Wobs, float* __restrict__ ws_f,
           const char* __restrict__ ws_b) {
  __shared__ __align__(16) u16 hA[64][72];
  __shared__ __align__(16) u16 hmA[64][40];
  __shared__ __align__(16) u16 catB[64][40];

  const int tid = threadIdx.x;
  const int b = blockIdx.y, tc = blockIdx.x;
  const int w = tid >> 6, l = tid & 63, lr = l & 15, lq = l >> 4, kb = lq * 8;
  const u16* wrt  = (const u16*)(ws_b + BOFF_WRT);
  const u16* catC = (const u16*)(ws_b + BOFF_CATC);
  const u16* peh  = (const u16*)(ws_b + BOFF_PEH);
  const float* brp = ws_f + OFF_BRP;
  float* adj = ws_f + OFF_ADJ;

  #pragma unroll
  for (int k = 0; k < 5; ++k) {        // catB const part (1280 u32)
    int idx = k * 256 + tid;
    ((u32*)catB)[idx] = ((const u32*)catC)[idx];
  }

  // prefetch WrT fragments (loop-invariant)
  const int m = w & 1, nb = (w >> 1) * 2;
  const u16* wr = wrt + (16*m + lr) * 64;
  short8 wa0 = *(const short8*)&wr[kb];
  short8 wa1 = *(const short8*)&wr[32 + kb];
  const int d0 = 16*m + lq*4;
  float4 bv = *(const float4*)&brp[d0];

  f32x4 asum[4];
  #pragma unroll
  for (int n = 0; n < 4; ++n) asum[n] = (f32x4){0.f,0.f,0.f,0.f};

  const int e4 = tid & 15, sg = tid >> 4;

  for (int tt = 0; tt < 8; ++tt) {
    int t = tc * 8 + tt;
    int base = b * 128 + t;
    { // P0: h build, direct x/mask loads (L1 broadcast across e4 lanes)
      float4 mk4 = *(const float4*)&mask[base*64 + sg*4];
      float mks[4] = {mk4.x, mk4.y, mk4.z, mk4.w};
      #pragma unroll
      for (int si = 0; si < 4; ++si) {
        int s = sg*4 + si;
        float4 xv = *(const float4*)&x[base*256 + s*4];
        float xo[4] = {xv.x, xv.y, xv.z, xv.w};
        float ax = 0.f, ay = 0.f, az = 0.f, aw = 0.f;
        #pragma unroll
        for (int o = 0; o < 4; ++o) {
          float4 wv = *(const float4*)&Wobs[(s*4+o)*64 + e4*4];
          ax += xo[o]*wv.x; ay += xo[o]*wv.y; az += xo[o]*wv.z; aw += xo[o]*wv.w;
        }
        float mk = mks[si];
        uint2 p;
        p.x = pk2bf(fmaxf(ax,0.f)*mk, fmaxf(ay,0.f)*mk);
        p.y = pk2bf(fmaxf(az,0.f)*mk, fmaxf(aw,0.f)*mk);
        *(uint2*)&hA[s][e4*4] = p;
      }
    }
    __syncthreads();
    { // P1: PE cols of catB + hm^T = WrT @ h^T -> hmA[s][d]
      int j = tid & 63, c = tid >> 6;
      const u32* pesrc = (const u32*)(peh + base*16);
      u32* dst = (u32*)&catB[j][10];
      dst[2*c]   = pesrc[2*c];
      dst[2*c+1] = pesrc[2*c+1];
      #pragma unroll
      for (int nn = 0; nn < 2; ++nn) {
        int n = nb + nn;
        f32x4 acc = (f32x4){0.f,0.f,0.f,0.f};
        short8 b0 = *(const short8*)&hA[16*n + lr][kb];
        short8 b1 = *(const short8*)&hA[16*n + lr][32 + kb];
        acc = __builtin_amdgcn_mfma_f32_16x16x32_bf16(wa0, b0, acc, 0, 0, 0);
        acc = __builtin_amdgcn_mfma_f32_16x16x32_bf16(wa1, b1, acc, 0, 0, 0);
        uint2 qq;
        qq.x = pk2bf(acc[0]+bv.x, acc[1]+bv.y);
        qq.y = pk2bf(acc[2]+bv.z, acc[3]+bv.w);
        *(uint2*)&hmA[16*n + lr][d0] = qq;
      }
    }
    __syncthreads();
    { // P2: alpha accumulate
      short8 am = *(const short8*)&hmA[16*w + lr][kb];
      #pragma unroll
      for (int n = 0; n < 4; ++n) {
        f32x4 z = (f32x4){0.f,0.f,0.f,0.f};
        short8 bc = *(const short8*)&catB[16*n + lr][kb];
        z = __builtin_amdgcn_mfma_f32_16x16x32_bf16(am, bc, z, 0, 0, 0);
        #pragma unroll
        for (int reg = 0; reg < 4; ++reg) asum[n][reg] += fmaxf(z[reg], 0.f);
      }
    }
    __syncthreads();
  }
  #pragma unroll
  for (int n = 0; n < 4; ++n) {
    #pragma unroll
    for (int reg = 0; reg < 4; ++reg) {
      int i = 16*w + lq*4 + reg, j = 16*n + lr;
      atomicAdd(&adj[((size_t)b << 12) + (i << 6) + j], asum[n][reg]);
    }
  }
}

// ---------------- K1b: adjS = bf16(adjnum / masksum) ----------------
__global__ __launch_bounds__(256)
void k_scale(const float* __restrict__ ws_f, char* __restrict__ ws_b) {
  const int b = blockIdx.x, tid = threadIdx.x;
  const float* adj = ws_f + OFF_ADJ + (size_t)b * 4096;
  const float* ms = ws_f + OFF_MS + b * 64;
  u16* as_ = (u16*)(ws_b + BOFF_ADJS) + (size_t)b * 4096;
  #pragma unroll
  for (int k = 0; k < 16; ++k) {
    int idx = k * 256 + tid;
    int i = idx >> 6;
    as_[idx] = f2bf(adj[idx] / ms[i]);
  }
}

// ---------------- K2: full per-(b,t) chain -> Hh bf16 (1 t/block) ----------------
__global__ __launch_bounds__(256, 4)
void k_main(const float* __restrict__ x, const float* __restrict__ mask,
            const float* __restrict__ Wobs, const float* __restrict__ ws_f,
            const char* __restrict__ ws_b, u16* __restrict__ Hh) {
  __shared__ __align__(16) char smem[37888];
  u16 (*hA)[72]  = (u16 (*)[72])(smem);           // h [s][e]; later h1T [e][i]
  u16 (*hT)[72]  = (u16 (*)[72])(smem + 9216);    // h^T [e][s]
  u16 (*wA)[72]  = (u16 (*)[72])(smem + 18432);   // w1 [i][j]
  u16 (*hmA)[40] = (u16 (*)[40])(smem + 27648);   // h_map [s][d]   (dead after P2)
  u16 (*catB)[40]= (u16 (*)[40])(smem + 32768);   //                (dead after P2)
  u16 (*adjS)[72]= (u16 (*)[72])(smem + 27648);   // overlay, staged in P3

  const int tid = threadIdx.x;
  const int t = blockIdx.x, b = blockIdx.y;
  const int w = tid >> 6, l = tid & 63, lr = l & 15, lq = l >> 4, kb = lq * 8;
  const int base = b * 128 + t;
  const u16* wrt  = (const u16*)(ws_b + BOFF_WRT);
  const u16* catC = (const u16*)(ws_b + BOFF_CATC);
  const u16* peh  = (const u16*)(ws_b + BOFF_PEH);
  const float* bidirG = ws_f + OFF_BIDIR;
  const float* brp = ws_f + OFF_BRP;
  const int i0 = 16*w + lq*4;

  // ---- prefetches: long-latency loads issued before any compute ----
  const uint4* ag = (const uint4*)(ws_b + BOFF_ADJS + (size_t)b * 8192);
  uint4 g0 = ag[2*tid], g1 = ag[2*tid + 1];
  const int m = w & 1, nb = (w >> 1) * 2;
  const u16* wr = wrt + (16*m + lr) * 64;
  short8 wa0 = *(const short8*)&wr[kb];
  short8 wa1 = *(const short8*)&wr[32 + kb];

  { // P0: h build (direct x/mask loads) + catB const copy
    const int e4 = tid & 15, sg = tid >> 4;
    float4 mk4 = *(const float4*)&mask[base*64 + sg*4];
    float mks[4] = {mk4.x, mk4.y, mk4.z, mk4.w};
    #pragma unroll
    for (int si = 0; si < 4; ++si) {
      int s = sg*4 + si;
      float4 xv = *(const float4*)&x[base*256 + s*4];
      float xo[4] = {xv.x, xv.y, xv.z, xv.w};
      float ax = 0.f, ay = 0.f, az = 0.f, aw = 0.f;
      #pragma unroll
      for (int o = 0; o < 4; ++o) {
        float4 wv = *(const float4*)&Wobs[(s*4+o)*64 + e4*4];
        ax += xo[o]*wv.x; ay += xo[o]*wv.y; az += xo[o]*wv.z; aw += xo[o]*wv.w;
      }
      float mk = mks[si];
      uint2 p;
      p.x = pk2bf(fmaxf(ax,0.f)*mk, fmaxf(ay,0.f)*mk);
      p.y = pk2bf(fmaxf(az,0.f)*mk, fmaxf(aw,0.f)*mk);
      *(uint2*)&hA[s][e4*4] = p;
    }
    #pragma unroll
    for (int k = 0; k < 5; ++k) {
      int idx = k * 256 + tid;
      ((u32*)catB)[idx] = ((const u32*)catC)[idx];
    }
  }
  __syncthreads();

  { // P1 phase: hT rebuild + PE cols of catB + hm MFMA
    #pragma unroll
    for (int sp = 0; sp < 8; ++sp) {
      int s = w*16 + sp*2;
      *(u32*)&hT[l][s] = (u32)hA[s][l] | ((u32)hA[s+1][l] << 16);
    }
    { int j = tid & 63, c = tid >> 6;
      const u32* pesrc = (const u32*)(peh + base*16);
      u32* dst = (u32*)&catB[j][10];
      dst[2*c]   = pesrc[2*c];
      dst[2*c+1] = pesrc[2*c+1];
    }
    int d0 = 16*m + lq*4;
    float4 bv = *(const float4*)&brp[d0];
    #pragma unroll
    for (int nn = 0; nn < 2; ++nn) {
      int n = nb + nn;
      f32x4 acc = (f32x4){0.f,0.f,0.f,0.f};
      short8 b0 = *(const short8*)&hA[16*n + lr][kb];
      short8 b1 = *(const short8*)&hA[16*n + lr][32 + kb];
      acc = __builtin_amdgcn_mfma_f32_16x16x32_bf16(wa0, b0, acc, 0, 0, 0);
      acc = __builtin_amdgcn_mfma_f32_16x16x32_bf16(wa1, b1, acc, 0, 0, 0);
      uint2 qq;
      qq.x = pk2bf(acc[0]+bv.x, acc[1]+bv.y);
      qq.y = pk2bf(acc[2]+bv.z, acc[3]+bv.w);
      *(uint2*)&hmA[16*n + lr][d0] = qq;
    }
  }
  __syncthreads();

  { // P2: alpha -> w1 (wA)
    short8 am = *(const short8*)&hmA[16*w + lr][kb];
    #pragma unroll
    for (int n = 0; n < 4; ++n) {
      f32x4 z = (f32x4){0.f,0.f,0.f,0.f};
      short8 bc = *(const short8*)&catB[16*n + lr][kb];
      z = __builtin_amdgcn_mfma_f32_16x16x32_bf16(am, bc, z, 0, 0, 0);
      int j = 16*n + lr;
      #pragma unroll
      for (int reg = 0; reg < 4; ++reg) {
        float w1 = fmaxf(z[reg], 0.f) * bidirG[((i0+reg) << 6) + j];
        wA[i0 + reg][j] = f2bf(w1);
      }
    }
  }
  __syncthreads();

  { // P3: adjS regs -> LDS (overlay); h1 = relu(w1 @ h) -> h1T into hA
    int idx0 = 2*tid, idx1 = 2*tid + 1;
    *(uint4*)&adjS[idx0 >> 3][(idx0 & 7) * 8] = g0;
    *(uint4*)&adjS[idx1 >> 3][(idx1 & 7) * 8] = g1;

    short8 aw0 = *(const short8*)&wA[16*w + lr][kb];
    short8 aw1 = *(const short8*)&wA[16*w + lr][32 + kb];
    #pragma unroll
    for (int n = 0; n < 4; ++n) {
      f32x4 acc = (f32x4){0.f,0.f,0.f,0.f};
      short8 b0 = *(const short8*)&hT[16*n + lr][kb];
      short8 b1 = *(const short8*)&hT[16*n + lr][32 + kb];
      acc = __builtin_amdgcn_mfma_f32_16x16x32_bf16(aw0, b0, acc, 0, 0, 0);
      acc = __builtin_amdgcn_mfma_f32_16x16x32_bf16(aw1, b1, acc, 0, 0, 0);
      int e = 16*n + lr;
      uint2 pp;
      pp.x = pk2bf(fmaxf(acc[0],0.f), fmaxf(acc[1],0.f));
      pp.y = pk2bf(fmaxf(acc[2],0.f), fmaxf(acc[3],0.f));
      *(uint2*)&hA[e][i0] = pp;   // h1T[e][i]
    }
  }
  __syncthreads();

  { // P4: w2 = w1 (.) adjS; h2 = relu(w2 @ h1) -> Hh
    int row = 16*w + lr;
    union { short8 v; u16 h[8]; u32 u[4]; } uw0, uw1, ud0, ud1, oa, ob;
    uw0.v = *(const short8*)&wA[row][kb];
    uw1.v = *(const short8*)&wA[row][32 + kb];
    ud0.v = *(const short8*)&adjS[row][kb];
    ud1.v = *(const short8*)&adjS[row][32 + kb];
    #pragma unroll
    for (int k = 0; k < 4; ++k) {
      oa.u[k] = pk2bf(bf2f(uw0.h[2*k])*bf2f(ud0.h[2*k]),
                      bf2f(uw0.h[2*k+1])*bf2f(ud0.h[2*k+1]));
      ob.u[k] = pk2bf(bf2f(uw1.h[2*k])*bf2f(ud1.h[2*k]),
                      bf2f(uw1.h[2*k+1])*bf2f(ud1.h[2*k+1]));
    }
    short8 a20 = oa.v, a21 = ob.v;
    size_t obase = ((size_t)b * 64) * 8192 + (size_t)t * 64;
    #pragma unroll
    for (int n = 0; n < 4; ++n) {
      f32x4 acc = (f32x4){0.f,0.f,0.f,0.f};
      short8 b0 = *(const short8*)&hA[16*n + lr][kb];      // h1T
      short8 b1 = *(const short8*)&hA[16*n + lr][32 + kb];
      acc = __builtin_amdgcn_mfma_f32_16x16x32_bf16(a20, b0, acc, 0, 0, 0);
      acc = __builtin_amdgcn_mfma_f32_16x16x32_bf16(a21, b1, acc, 0, 0, 0);
      int e = 16*n + lr;
      u32 p0 = pk2bf(fmaxf(acc[0],0.f), fmaxf(acc[1],0.f));
      u32 p1 = pk2bf(fmaxf(acc[2],0.f), fmaxf(acc[3],0.f));
      Hh[obase + (size_t)(i0+0) * 8192 + e] = (u16)p0;
      Hh[obase + (size_t)(i0+1) * 8192 + e] = (u16)(p0 >> 16);
      Hh[obase + (size_t)(i0+2) * 8192 + e] = (u16)p1;
      Hh[obase + (size_t)(i0+3) * 8192 + e] = (u16)(p1 >> 16);
    }
  }
}

// ---------------- K3: collapsed temporal attention ----------------
#define HTP 82
#define PEP 17

__global__ __launch_bounds__(256)
void k_attn(const float* __restrict__ ws_f, const u16* __restrict__ Hh,
            const float* __restrict__ Wq, const float* __restrict__ bq,
            const float* __restrict__ Wk, const float* __restrict__ bk,
            const float* __restrict__ Ws, const float* __restrict__ bs,
            const float* __restrict__ Wemb, const float* __restrict__ bemb,
            float* __restrict__ out) {
  __shared__ u16 Ht[128][HTP];
  __shared__ float peB[128][PEP];
  __shared__ float wsL[128];
  __shared__ float pA[3][80];
  __shared__ float pK[8][10];
  __shared__ float KtilL[10];
  __shared__ float qvL[80];
  __shared__ float pC[2][128];
  __shared__ float bb[128];
  __shared__ float red[4];
  __shared__ float cstL, sWL;

  const int tid = threadIdx.x;
  const int s = blockIdx.x, b = blockIdx.y;
  const float scale = 0.111803398875f; // 1/sqrt(80)

  const u16* src = Hh + ((size_t)b * 64 + s) * 8192;
  #pragma unroll
  for (int r = 0; r < 4; ++r) {
    int id = r * 256 + tid;
    int tt = id >> 3, c = (id & 7) * 8;
    uint4 q = *(const uint4*)&src[tt * 64 + c];
    u32* dst = (u32*)&Ht[tt][c];
    dst[0] = q.x; dst[1] = q.y; dst[2] = q.z; dst[3] = q.w;
  }
  #pragma unroll
  for (int r = 0; r < 8; ++r) {
    int id = r * 256 + tid;
    peB[id >> 4][id & 15] = ws_f[OFF_PE + (size_t)b * 2048 + id];
  }
  if (tid < 128) wsL[tid] = Ws[tid];
  __syncthreads();

  if (tid < 240) {
    int d = tid % 80, c = tid / 80;
    int t0 = c * 43, t1 = (c == 2) ? 128 : t0 + 43;
    float acc = 0.f;
    if (d < 64) {
      for (int t = t0; t < t1; ++t) acc += wsL[t] * bf2f(Ht[t][d]);
    } else {
      int k = d - 64;
      for (int t = t0; t < t1; ++t) acc += wsL[t] * peB[t][k];
    }
    pA[c][d] = acc;
  } else if (tid == 240) {
    float sw = 0.f;
    for (int t = 0; t < 128; ++t) sw += wsL[t];
    sWL = sw;
  }
  __syncthreads();

  if (tid < 80) {
    int a = tid % 10, c = tid / 10;
    float acc = 0.f;
    #pragma unroll
    for (int i = 0; i < 10; ++i) {
      int d = c * 10 + i;
      float hb = pA[0][d] + pA[1][d] + pA[2][d];
      acc += hb * Wk[d * 10 + a];
    }
    pK[c][a] = acc;
  }
  __syncthreads();
  if (tid < 10) {
    float acc = sWL * bk[tid];
    #pragma unroll
    for (int c = 0; c < 8; ++c) acc += pK[c][tid];
    KtilL[tid] = acc;
  }
  __syncthreads();
  if (tid < 80) {
    float acc = 0.f;
    #pragma unroll
    for (int a = 0; a < 10; ++a) acc += Wq[tid * 10 + a] * KtilL[a];
    qvL[tid] = acc;
  } else if (tid == 80) {
    float cq = 0.f;
    #pragma unroll
    for (int a = 0; a < 10; ++a) cq += bq[a] * KtilL[a];
    cstL = scale * cq + bs[0];
  }
  __syncthreads();

  {
    int t = tid & 127, half = tid >> 7;
    float acc = 0.f;
    const u32* row = (const u32*)&Ht[t][0];
    if (half == 0) {
      #pragma unroll
      for (int i = 0; i < 20; ++i) {
        u32 p = row[i];
        acc += bf2f((u16)p) * qvL[2*i] + bf2f((u16)(p >> 16)) * qvL[2*i+1];
      }
    } else {
      #pragma unroll
      for (int i = 20; i < 32; ++i) {
        u32 p = row[i];
        acc += bf2f((u16)p) * qvL[2*i] + bf2f((u16)(p >> 16)) * qvL[2*i+1];
      }
      #pragma unroll
      for (int k = 0; k < 16; ++k) acc += peB[t][k] * qvL[64 + k];
    }
    pC[half][t] = acc;
  }
  __syncthreads();

  float ev = 0.f;
  if (tid < 128) {
    float v = scale * (pC[0][tid] + pC[1][tid]) + cstL;
    bb[tid] = v;
    float mm = v;
    #pragma unroll
    for (int off = 32; off; off >>= 1) mm = fmaxf(mm, __shfl_xor(mm, off));
    if ((tid & 63) == 0) red[tid >> 6] = mm;
  }
  __syncthreads();
  float m = fmaxf(red[0], red[1]);
  if (tid < 128) {
    ev = expf(bb[tid] - m);
    float ss = ev;
    #pragma unroll
    for (int off = 32; off; off >>= 1) ss += __shfl_xor(ss, off);
    if ((tid & 63) == 0) red[2 + (tid >> 6)] = ss;
  }
  __syncthreads();
  if (tid < 128) bb[tid] = ev / (red[2] + red[3]);
  __syncthreads();

  if (tid < 240) {
    int d = tid % 80, c = tid / 80;
    int t0 = c * 43, t1 = (c == 2) ? 128 : t0 + 43;
    float acc = 0.f;
    if (d < 64) {
      for (int t = t0; t < t1; ++t) acc += bb[t] * bf2f(Ht[t][d]);
    } else {
      int k = d - 64;
      for (int t = t0; t < t1; ++t) acc += bb[t] * peB[t][k];
    }
    pA[c][d] = acc;
  }
  __syncthreads();

  {
    int o = tid & 127, half = tid >> 7;
    int d0 = half * 40;
    float acc = 0.f;
    #pragma unroll
    for (int i = 0; i < 40; ++i) {
      int d = d0 + i;
      float hv = pA[0][d] + pA[1][d] + pA[2][d];
      acc += hv * Wemb[d * 128 + o];
    }
    pC[half][o] = acc;
  }
  __syncthreads();
  if (tid < 128) {
    out[(((size_t)b * 64 + s) << 7) + tid] = bemb[tid] + pC[0][tid] + pC[1][tid];
  }
}

extern "C" void kernel_launch(void* const* d_in, const int* in_sizes, int n_in,
                              void* d_out, int out_size, void* d_ws, size_t ws_size,
                              hipStream_t stream) {
  (void)in_sizes; (void)n_in; (void)out_size; (void)ws_size;
  const float* x     = (const float*)d_in[0];
  const float* times = (const float*)d_in[1];
  const float* mask  = (const float*)d_in[2];
  const float* Wobs  = (const float*)d_in[3];
  const float* Wattn = (const float*)d_in[4];
  const float* Wrecv = (const float*)d_in[5];
  const float* brecv = (const float*)d_in[6];
  const float* Wb    = (const float*)d_in[7];
  const float* Wq    = (const float*)d_in[8];
  const float* bq    = (const float*)d_in[9];
  const float* Wk    = (const float*)d_in[10];
  const float* bk    = (const float*)d_in[11];
  const float* Ws    = (const float*)d_in[12];
  const float* bs    = (const float*)d_in[13];
  const float* Wemb  = (const float*)d_in[14];
  const float* bemb  = (const float*)d_in[15];
  float* out = (float*)d_out;
  float* ws_f = (float*)d_ws;
  char* ws_b = (char*)d_ws;
  u16* Hh = (u16*)(ws_b + BOFF_HH);

  hipMemsetAsync(ws_b + (size_t)OFF_ADJ * 4, 0, (size_t)64 * 64 * 64 * 4, stream);
  k_pre<<<322, 256, 0, stream>>>(times, mask, Wb, Wrecv, brecv, Wattn, ws_f, ws_b);
  k_adj<<<dim3(16, 64), 256, 0, stream>>>(x, mask, Wobs, ws_f, ws_b);
  k_scale<<<64, 256, 0, stream>>>(ws_f, ws_b);
  k_main<<<dim3(128, 64), 256, 0, stream>>>(x, mask, Wobs, ws_f, ws_b, Hh);
  k_attn<<<dim3(64, 64), 256, 0, stream>>>(ws_f, Hh, Wq, bq, Wk, bk, Ws, bs, Wemb, bemb, out);
}

// Round 7
// 187.184 us; speedup vs baseline: 1.3591x; 1.0562x over previous
//
#include <hip/hip_runtime.h>
#include <hip/hip_bf16.h>

// Raindrop forward, MI355X. B=64 T=128 S=64 O=4 E=64 P=16 A=10 OUT=128.
//  - temporal attention collapsed: (Q K^T) W_s = Q (W_s^T K)  -> no TxT matrix
//  - per-(b,t) chain in bf16 MFMA 16x16x32; 1 t/block; 4 barriers/block
//  - k_attn: 4-way independent accumulators (break dep chains), 9 barriers,
//            deferred softmax normalization
// ws floats: PE[131072] | bidir[4096] | masksum[4096] | adjnum[262144] | brp[32]
// ws bytes @: WrT 1605760 | catC 1609856 | PEh 1614976 | adjS 1877120 | Hh 2401408

typedef unsigned short u16;
typedef unsigned int u32;
typedef __attribute__((ext_vector_type(8))) short short8;
typedef __attribute__((ext_vector_type(4))) float f32x4;

#define OFF_PE    0
#define OFF_BIDIR 131072
#define OFF_MS    135168
#define OFF_ADJ   139264
#define OFF_BRP   401408
#define BOFF_WRT  1605760u
#define BOFF_CATC 1609856u
#define BOFF_PEH  1614976u
#define BOFF_ADJS 1877120u
#define BOFF_HH   2401408u

__device__ __forceinline__ u16 f2bf(float f){
  __hip_bfloat16 h = __float2bfloat16(f);
  union { __hip_bfloat16 h; u16 u; } v; v.h = h; return v.u;
}
__device__ __forceinline__ u32 pk2bf(float lo, float hi){
  __hip_bfloat162 h = __float22bfloat162_rn(float2{lo, hi});
  union { __hip_bfloat162 h; u32 u; } v; v.h = h; return v.u;
}
__device__ __forceinline__ float bf2f(u16 h){
  union { u32 u; float f; } v; v.u = ((u32)h) << 16; return v.f;
}

// ---------------- K0: PE (f32+bf16), bidir, WrT, brp, catC, masksum ----------------
__global__ void k_pre(const float* __restrict__ times, const float* __restrict__ mask,
                      const float* __restrict__ Wb, const float* __restrict__ Wrecv,
                      const float* __restrict__ brecv, const float* __restrict__ battn,
                      float* __restrict__ ws_f, char* __restrict__ ws_b) {
  __shared__ float pm[4][64];
  const int blk = blockIdx.x, tid = threadIdx.x;
  u16* wrt  = (u16*)(ws_b + BOFF_WRT);
  u16* catC = (u16*)(ws_b + BOFF_CATC);
  u16* peh  = (u16*)(ws_b + BOFF_PEH);
  if (blk < 256) {                     // PE: (B*T,16) sin|cos, f32 + bf16
    float* PE = ws_f + OFF_PE;
    #pragma unroll
    for (int r = 0; r < 2; ++r) {
      int id = blk * 512 + r * 256 + tid;
      int bt = id >> 4, k = id & 15;
      float tv = times[bt];
      int kk = k & 7;
      float fr = expf(-(float)kk * 1.1512925465f); // ln(1e4)/8
      float ang = tv * fr;
      float v = (k < 8) ? sinf(ang) : cosf(ang);
      PE[id] = v;
      peh[id] = f2bf(v);
    }
  } else if (blk == 256) {             // bidir = Wb @ Wb^T
    float* bidir = ws_f + OFF_BIDIR;
    for (int r = 0; r < 16; ++r) {
      int idx = r * 256 + tid;
      int i = idx >> 6, j = idx & 63;
      float acc = 0.f;
      for (int e = 0; e < 64; ++e) acc += Wb[i*64+e] * Wb[j*64+e];
      bidir[idx] = acc;
    }
  } else if (blk == 257) {             // WrT, brp, catC
    for (int r = 0; r < 8; ++r) {
      int idx = r * 256 + tid;
      int d = idx >> 6, e = idx & 63;
      wrt[idx] = (d < 26) ? f2bf(Wrecv[e*26 + d]) : (u16)0;
    }
    if (tid < 32) ws_f[OFF_BRP + tid] = (tid < 26) ? brecv[tid] : 0.f;
    for (int r = 0; r < 10; ++r) {
      int idx = r * 256 + tid;          // 2560 = 64*40
      int j = idx / 40, d = idx % 40;
      catC[idx] = (d < 10) ? f2bf(battn[j*10 + d]) : (u16)0;
    }
  } else {                             // masksum[b][i], 4-partial reduce
    int b = blk - 258;
    int i = tid & 63, q = tid >> 6;
    float s = 0.f;
    for (int t = q*32; t < q*32 + 32; ++t) s += mask[(b*128 + t)*64 + i];
    pm[q][i] = s;
    __syncthreads();
    if (tid < 64)
      (ws_f + OFF_MS)[b*64 + tid] = pm[0][tid] + pm[1][tid] + pm[2][tid] + pm[3][tid];
  }
}

// ---------------- K1: adj2 numerator (sum_t alpha) ----------------
__global__ __launch_bounds__(256)
void k_adj(const float* __restrict__ x, const float* __restrict__ mask,
           const float* __restrict__ Wobs, float* __restrict__ ws_f,
           const char* __restrict__ ws_b) {
  __shared__ __align__(16) u16 hA[64][72];
  __shared__ __align__(16) u16 hmA[64][40];
  __shared__ __align__(16) u16 catB[64][40];

  const int tid = threadIdx.x;
  const int b = blockIdx.y, tc = blockIdx.x;
  const int w = tid >> 6, l = tid & 63, lr = l & 15, lq = l >> 4, kb = lq * 8;
  const u16* wrt  = (const u16*)(ws_b + BOFF_WRT);
  const u16* catC = (const u16*)(ws_b + BOFF_CATC);
  const u16* peh  = (const u16*)(ws_b + BOFF_PEH);
  const float* brp = ws_f + OFF_BRP;
  float* adj = ws_f + OFF_ADJ;

  #pragma unroll
  for (int k = 0; k < 5; ++k) {        // catB const part (1280 u32)
    int idx = k * 256 + tid;
    ((u32*)catB)[idx] = ((const u32*)catC)[idx];
  }

  // prefetch WrT fragments (loop-invariant)
  const int m = w & 1, nb = (w >> 1) * 2;
  const u16* wr = wrt + (16*m + lr) * 64;
  short8 wa0 = *(const short8*)&wr[kb];
  short8 wa1 = *(const short8*)&wr[32 + kb];
  const int d0 = 16*m + lq*4;
  float4 bv = *(const float4*)&brp[d0];

  f32x4 asum[4];
  #pragma unroll
  for (int n = 0; n < 4; ++n) asum[n] = (f32x4){0.f,0.f,0.f,0.f};

  const int e4 = tid & 15, sg = tid >> 4;

  for (int tt = 0; tt < 8; ++tt) {
    int t = tc * 8 + tt;
    int base = b * 128 + t;
    { // P0: h build, direct x/mask loads (L1 broadcast across e4 lanes)
      float4 mk4 = *(const float4*)&mask[base*64 + sg*4];
      float mks[4] = {mk4.x, mk4.y, mk4.z, mk4.w};
      #pragma unroll
      for (int si = 0; si < 4; ++si) {
        int s = sg*4 + si;
        float4 xv = *(const float4*)&x[base*256 + s*4];
        float xo[4] = {xv.x, xv.y, xv.z, xv.w};
        float ax = 0.f, ay = 0.f, az = 0.f, aw = 0.f;
        #pragma unroll
        for (int o = 0; o < 4; ++o) {
          float4 wv = *(const float4*)&Wobs[(s*4+o)*64 + e4*4];
          ax += xo[o]*wv.x; ay += xo[o]*wv.y; az += xo[o]*wv.z; aw += xo[o]*wv.w;
        }
        float mk = mks[si];
        uint2 p;
        p.x = pk2bf(fmaxf(ax,0.f)*mk, fmaxf(ay,0.f)*mk);
        p.y = pk2bf(fmaxf(az,0.f)*mk, fmaxf(aw,0.f)*mk);
        *(uint2*)&hA[s][e4*4] = p;
      }
    }
    __syncthreads();
    { // P1: PE cols of catB + hm^T = WrT @ h^T -> hmA[s][d]
      int j = tid & 63, c = tid >> 6;
      const u32* pesrc = (const u32*)(peh + base*16);
      u32* dst = (u32*)&catB[j][10];
      dst[2*c]   = pesrc[2*c];
      dst[2*c+1] = pesrc[2*c+1];
      #pragma unroll
      for (int nn = 0; nn < 2; ++nn) {
        int n = nb + nn;
        f32x4 acc = (f32x4){0.f,0.f,0.f,0.f};
        short8 b0 = *(const short8*)&hA[16*n + lr][kb];
        short8 b1 = *(const short8*)&hA[16*n + lr][32 + kb];
        acc = __builtin_amdgcn_mfma_f32_16x16x32_bf16(wa0, b0, acc, 0, 0, 0);
        acc = __builtin_amdgcn_mfma_f32_16x16x32_bf16(wa1, b1, acc, 0, 0, 0);
        uint2 qq;
        qq.x = pk2bf(acc[0]+bv.x, acc[1]+bv.y);
        qq.y = pk2bf(acc[2]+bv.z, acc[3]+bv.w);
        *(uint2*)&hmA[16*n + lr][d0] = qq;
      }
    }
    __syncthreads();
    { // P2: alpha accumulate
      short8 am = *(const short8*)&hmA[16*w + lr][kb];
      #pragma unroll
      for (int n = 0; n < 4; ++n) {
        f32x4 z = (f32x4){0.f,0.f,0.f,0.f};
        short8 bc = *(const short8*)&catB[16*n + lr][kb];
        z = __builtin_amdgcn_mfma_f32_16x16x32_bf16(am, bc, z, 0, 0, 0);
        #pragma unroll
        for (int reg = 0; reg < 4; ++reg) asum[n][reg] += fmaxf(z[reg], 0.f);
      }
    }
    __syncthreads();
  }
  #pragma unroll
  for (int n = 0; n < 4; ++n) {
    #pragma unroll
    for (int reg = 0; reg < 4; ++reg) {
      int i = 16*w + lq*4 + reg, j = 16*n + lr;
      atomicAdd(&adj[((size_t)b << 12) + (i << 6) + j], asum[n][reg]);
    }
  }
}

// ---------------- K1b: adjS = bf16(adjnum / masksum) ----------------
__global__ __launch_bounds__(256)
void k_scale(const float* __restrict__ ws_f, char* __restrict__ ws_b) {
  const int b = blockIdx.x, tid = threadIdx.x;
  const float* adj = ws_f + OFF_ADJ + (size_t)b * 4096;
  const float* ms = ws_f + OFF_MS + b * 64;
  u16* as_ = (u16*)(ws_b + BOFF_ADJS) + (size_t)b * 4096;
  #pragma unroll
  for (int k = 0; k < 16; ++k) {
    int idx = k * 256 + tid;
    int i = idx >> 6;
    as_[idx] = f2bf(adj[idx] / ms[i]);
  }
}

// ---------------- K2: full per-(b,t) chain -> Hh bf16 (1 t/block) ----------------
__global__ __launch_bounds__(256, 4)
void k_main(const float* __restrict__ x, const float* __restrict__ mask,
            const float* __restrict__ Wobs, const float* __restrict__ ws_f,
            const char* __restrict__ ws_b, u16* __restrict__ Hh) {
  __shared__ __align__(16) char smem[37888];
  u16 (*hA)[72]  = (u16 (*)[72])(smem);           // h [s][e]; later h1T [e][i]
  u16 (*hT)[72]  = (u16 (*)[72])(smem + 9216);    // h^T [e][s]
  u16 (*wA)[72]  = (u16 (*)[72])(smem + 18432);   // w1 [i][j]
  u16 (*hmA)[40] = (u16 (*)[40])(smem + 27648);   // h_map [s][d]   (dead after P2)
  u16 (*catB)[40]= (u16 (*)[40])(smem + 32768);   //                (dead after P2)
  u16 (*adjS)[72]= (u16 (*)[72])(smem + 27648);   // overlay, staged in P3

  const int tid = threadIdx.x;
  const int t = blockIdx.x, b = blockIdx.y;
  const int w = tid >> 6, l = tid & 63, lr = l & 15, lq = l >> 4, kb = lq * 8;
  const int base = b * 128 + t;
  const u16* wrt  = (const u16*)(ws_b + BOFF_WRT);
  const u16* catC = (const u16*)(ws_b + BOFF_CATC);
  const u16* peh  = (const u16*)(ws_b + BOFF_PEH);
  const float* bidirG = ws_f + OFF_BIDIR;
  const float* brp = ws_f + OFF_BRP;
  const int i0 = 16*w + lq*4;

  // ---- prefetches: long-latency loads issued before any compute ----
  const uint4* ag = (const uint4*)(ws_b + BOFF_ADJS + (size_t)b * 8192);
  uint4 g0 = ag[2*tid], g1 = ag[2*tid + 1];
  const int m = w & 1, nb = (w >> 1) * 2;
  const u16* wr = wrt + (16*m + lr) * 64;
  short8 wa0 = *(const short8*)&wr[kb];
  short8 wa1 = *(const short8*)&wr[32 + kb];

  { // P0: h build (direct x/mask loads) + catB const copy
    const int e4 = tid & 15, sg = tid >> 4;
    float4 mk4 = *(const float4*)&mask[base*64 + sg*4];
    float mks[4] = {mk4.x, mk4.y, mk4.z, mk4.w};
    #pragma unroll
    for (int si = 0; si < 4; ++si) {
      int s = sg*4 + si;
      float4 xv = *(const float4*)&x[base*256 + s*4];
      float xo[4] = {xv.x, xv.y, xv.z, xv.w};
      float ax = 0.f, ay = 0.f, az = 0.f, aw = 0.f;
      #pragma unroll
      for (int o = 0; o < 4; ++o) {
        float4 wv = *(const float4*)&Wobs[(s*4+o)*64 + e4*4];
        ax += xo[o]*wv.x; ay += xo[o]*wv.y; az += xo[o]*wv.z; aw += xo[o]*wv.w;
      }
      float mk = mks[si];
      uint2 p;
      p.x = pk2bf(fmaxf(ax,0.f)*mk, fmaxf(ay,0.f)*mk);
      p.y = pk2bf(fmaxf(az,0.f)*mk, fmaxf(aw,0.f)*mk);
      *(uint2*)&hA[s][e4*4] = p;
    }
    #pragma unroll
    for (int k = 0; k < 5; ++k) {
      int idx = k * 256 + tid;
      ((u32*)catB)[idx] = ((const u32*)catC)[idx];
    }
  }
  __syncthreads();

  { // P1 phase: hT rebuild + PE cols of catB + hm MFMA
    #pragma unroll
    for (int sp = 0; sp < 8; ++sp) {
      int s = w*16 + sp*2;
      *(u32*)&hT[l][s] = (u32)hA[s][l] | ((u32)hA[s+1][l] << 16);
    }
    { int j = tid & 63, c = tid >> 6;
      const u32* pesrc = (const u32*)(peh + base*16);
      u32* dst = (u32*)&catB[j][10];
      dst[2*c]   = pesrc[2*c];
      dst[2*c+1] = pesrc[2*c+1];
    }
    int d0 = 16*m + lq*4;
    float4 bv = *(const float4*)&brp[d0];
    #pragma unroll
    for (int nn = 0; nn < 2; ++nn) {
      int n = nb + nn;
      f32x4 acc = (f32x4){0.f,0.f,0.f,0.f};
      short8 b0 = *(const short8*)&hA[16*n + lr][kb];
      short8 b1 = *(const short8*)&hA[16*n + lr][32 + kb];
      acc = __builtin_amdgcn_mfma_f32_16x16x32_bf16(wa0, b0, acc, 0, 0, 0);
      acc = __builtin_amdgcn_mfma_f32_16x16x32_bf16(wa1, b1, acc, 0, 0, 0);
      uint2 qq;
      qq.x = pk2bf(acc[0]+bv.x, acc[1]+bv.y);
      qq.y = pk2bf(acc[2]+bv.z, acc[3]+bv.w);
      *(uint2*)&hmA[16*n + lr][d0] = qq;
    }
  }
  __syncthreads();

  { // P2: alpha -> w1 (wA)
    short8 am = *(const short8*)&hmA[16*w + lr][kb];
    #pragma unroll
    for (int n = 0; n < 4; ++n) {
      f32x4 z = (f32x4){0.f,0.f,0.f,0.f};
      short8 bc = *(const short8*)&catB[16*n + lr][kb];
      z = __builtin_amdgcn_mfma_f32_16x16x32_bf16(am, bc, z, 0, 0, 0);
      int j = 16*n + lr;
      #pragma unroll
      for (int reg = 0; reg < 4; ++reg) {
        float w1 = fmaxf(z[reg], 0.f) * bidirG[((i0+reg) << 6) + j];
        wA[i0 + reg][j] = f2bf(w1);
      }
    }
  }
  __syncthreads();

  { // P3: adjS regs -> LDS (overlay); h1 = relu(w1 @ h) -> h1T into hA
    int idx0 = 2*tid, idx1 = 2*tid + 1;
    *(uint4*)&adjS[idx0 >> 3][(idx0 & 7) * 8] = g0;
    *(uint4*)&adjS[idx1 >> 3][(idx1 & 7) * 8] = g1;

    short8 aw0 = *(const short8*)&wA[16*w + lr][kb];
    short8 aw1 = *(const short8*)&wA[16*w + lr][32 + kb];
    #pragma unroll
    for (int n = 0; n < 4; ++n) {
      f32x4 acc = (f32x4){0.f,0.f,0.f,0.f};
      short8 b0 = *(const short8*)&hT[16*n + lr][kb];
      short8 b1 = *(const short8*)&hT[16*n + lr][32 + kb];
      acc = __builtin_amdgcn_mfma_f32_16x16x32_bf16(aw0, b0, acc, 0, 0, 0);
      acc = __builtin_amdgcn_mfma_f32_16x16x32_bf16(aw1, b1, acc, 0, 0, 0);
      int e = 16*n + lr;
      uint2 pp;
      pp.x = pk2bf(fmaxf(acc[0],0.f), fmaxf(acc[1],0.f));
      pp.y = pk2bf(fmaxf(acc[2],0.f), fmaxf(acc[3],0.f));
      *(uint2*)&hA[e][i0] = pp;   // h1T[e][i]
    }
  }
  __syncthreads();

  { // P4: w2 = w1 (.) adjS; h2 = relu(w2 @ h1) -> Hh
    int row = 16*w + lr;
    union { short8 v; u16 h[8]; u32 u[4]; } uw0, uw1, ud0, ud1, oa, ob;
    uw0.v = *(const short8*)&wA[row][kb];
    uw1.v = *(const short8*)&wA[row][32 + kb];
    ud0.v = *(const short8*)&adjS[row][kb];
    ud1.v = *(const short8*)&adjS[row][32 + kb];
    #pragma unroll
    for (int k = 0; k < 4; ++k) {
      oa.u[k] = pk2bf(bf2f(uw0.h[2*k])*bf2f(ud0.h[2*k]),
                      bf2f(uw0.h[2*k+1])*bf2f(ud0.h[2*k+1]));
      ob.u[k] = pk2bf(bf2f(uw1.h[2*k])*bf2f(ud1.h[2*k]),
                      bf2f(uw1.h[2*k+1])*bf2f(ud1.h[2*k+1]));
    }
    short8 a20 = oa.v, a21 = ob.v;
    size_t obase = ((size_t)b * 64) * 8192 + (size_t)t * 64;
    #pragma unroll
    for (int n = 0; n < 4; ++n) {
      f32x4 acc = (f32x4){0.f,0.f,0.f,0.f};
      short8 b0 = *(const short8*)&hA[16*n + lr][kb];      // h1T
      short8 b1 = *(const short8*)&hA[16*n + lr][32 + kb];
      acc = __builtin_amdgcn_mfma_f32_16x16x32_bf16(a20, b0, acc, 0, 0, 0);
      acc = __builtin_amdgcn_mfma_f32_16x16x32_bf16(a21, b1, acc, 0, 0, 0);
      int e = 16*n + lr;
      u32 p0 = pk2bf(fmaxf(acc[0],0.f), fmaxf(acc[1],0.f));
      u32 p1 = pk2bf(fmaxf(acc[2],0.f), fmaxf(acc[3],0.f));
      Hh[obase + (size_t)(i0+0) * 8192 + e] = (u16)p0;
      Hh[obase + (size_t)(i0+1) * 8192 + e] = (u16)(p0 >> 16);
      Hh[obase + (size_t)(i0+2) * 8192 + e] = (u16)p1;
      Hh[obase + (size_t)(i0+3) * 8192 + e] = (u16)(p1 >> 16);
    }
  }
}

// ---------------- K3: collapsed temporal attention ----------------
#define HTP 82
#define PEP 17

__global__ __launch_bounds__(256)
void k_attn(const float* __restrict__ ws_f, const u16* __restrict__ Hh,
            const float* __restrict__ Wq, const float* __restrict__ bq,
            const float* __restrict__ Wk, const float* __restrict__ bk,
            const float* __restrict__ Ws, const float* __restrict__ bs,
            const float* __restrict__ Wemb, const float* __restrict__ bemb,
            float* __restrict__ out) {
  __shared__ u16 Ht[128][HTP];
  __shared__ float peB[128][PEP];
  __shared__ float wsL[128];
  __shared__ float pA[3][80];
  __shared__ float pK[8][10];
  __shared__ float qvL[80];
  __shared__ float pC[2][128];
  __shared__ float bb[128];
  __shared__ float red[4];
  __shared__ float cstL, sWL;

  const int tid = threadIdx.x;
  const int s = blockIdx.x, b = blockIdx.y;
  const float scale = 0.111803398875f; // 1/sqrt(80)

  const u16* src = Hh + ((size_t)b * 64 + s) * 8192;
  #pragma unroll
  for (int r = 0; r < 4; ++r) {
    int id = r * 256 + tid;
    int tt = id >> 3, c = (id & 7) * 8;
    uint4 q = *(const uint4*)&src[tt * 64 + c];
    u32* dst = (u32*)&Ht[tt][c];
    dst[0] = q.x; dst[1] = q.y; dst[2] = q.z; dst[3] = q.w;
  }
  #pragma unroll
  for (int r = 0; r < 8; ++r) {
    int id = r * 256 + tid;
    peB[id >> 4][id & 15] = ws_f[OFF_PE + (size_t)b * 2048 + id];
  }
  if (tid < 128) wsL[tid] = Ws[tid];
  __syncthreads();

  // Phase A: hbar partials, 4 independent accumulators
  if (tid < 240) {
    int d = tid % 80, c = tid / 80;
    int t0 = c * 43, t1 = (c == 2) ? 128 : t0 + 43;
    float a0 = 0.f, a1 = 0.f, a2 = 0.f, a3 = 0.f;
    int t = t0;
    if (d < 64) {
      for (; t + 4 <= t1; t += 4) {
        a0 += wsL[t]   * bf2f(Ht[t][d]);
        a1 += wsL[t+1] * bf2f(Ht[t+1][d]);
        a2 += wsL[t+2] * bf2f(Ht[t+2][d]);
        a3 += wsL[t+3] * bf2f(Ht[t+3][d]);
      }
      for (; t < t1; ++t) a0 += wsL[t] * bf2f(Ht[t][d]);
    } else {
      int k = d - 64;
      for (; t + 4 <= t1; t += 4) {
        a0 += wsL[t]   * peB[t][k];
        a1 += wsL[t+1] * peB[t+1][k];
        a2 += wsL[t+2] * peB[t+2][k];
        a3 += wsL[t+3] * peB[t+3][k];
      }
      for (; t < t1; ++t) a0 += wsL[t] * peB[t][k];
    }
    pA[c][d] = (a0 + a1) + (a2 + a3);
  } else if (tid == 240) {
    float a0 = 0.f, a1 = 0.f, a2 = 0.f, a3 = 0.f;
    for (int t = 0; t < 128; t += 4) {
      a0 += wsL[t]; a1 += wsL[t+1]; a2 += wsL[t+2]; a3 += wsL[t+3];
    }
    sWL = (a0 + a1) + (a2 + a3);
  }
  __syncthreads();

  // pK partials: pK[c][a] = sum_{d in chunk} hbar[d]*Wk[d*10+a]
  if (tid < 80) {
    int a = tid % 10, c = tid / 10;
    float a0 = 0.f, a1 = 0.f;
    #pragma unroll
    for (int i = 0; i < 10; i += 2) {
      int d = c * 10 + i;
      float h0 = pA[0][d] + pA[1][d] + pA[2][d];
      float h1 = pA[0][d+1] + pA[1][d+1] + pA[2][d+1];
      a0 += h0 * Wk[d * 10 + a];
      a1 += h1 * Wk[(d+1) * 10 + a];
    }
    pK[c][a] = a0 + a1;
  }
  __syncthreads();

  // qv phase (Ktil rebuilt locally; one barrier saved)
  if (tid <= 80) {
    float kt[10];
    #pragma unroll
    for (int a = 0; a < 10; ++a) {
      float acc = sWL * bk[a];
      #pragma unroll
      for (int c = 0; c < 8; ++c) acc += pK[c][a];
      kt[a] = acc;
    }
    if (tid < 80) {
      float a0 = 0.f, a1 = 0.f;
      #pragma unroll
      for (int a = 0; a < 10; a += 2) {
        a0 += Wq[tid * 10 + a] * kt[a];
        a1 += Wq[tid * 10 + a + 1] * kt[a + 1];
      }
      qvL[tid] = a0 + a1;
    } else {
      float cq = 0.f;
      #pragma unroll
      for (int a = 0; a < 10; ++a) cq += bq[a] * kt[a];
      cstL = scale * cq + bs[0];
    }
  }
  __syncthreads();

  // Phase C: beta partials over d-halves, 4 accumulators
  {
    int t = tid & 127, half = tid >> 7;
    float a0 = 0.f, a1 = 0.f, a2 = 0.f, a3 = 0.f;
    const u32* row = (const u32*)&Ht[t][0];
    if (half == 0) {
      #pragma unroll
      for (int i = 0; i < 20; i += 4) {
        u32 p0 = row[i], p1 = row[i+1], p2 = row[i+2], p3 = row[i+3];
        a0 += bf2f((u16)p0) * qvL[2*i]   + bf2f((u16)(p0 >> 16)) * qvL[2*i+1];
        a1 += bf2f((u16)p1) * qvL[2*i+2] + bf2f((u16)(p1 >> 16)) * qvL[2*i+3];
        a2 += bf2f((u16)p2) * qvL[2*i+4] + bf2f((u16)(p2 >> 16)) * qvL[2*i+5];
        a3 += bf2f((u16)p3) * qvL[2*i+6] + bf2f((u16)(p3 >> 16)) * qvL[2*i+7];
      }
    } else {
      #pragma unroll
      for (int i = 20; i < 32; i += 4) {
        u32 p0 = row[i], p1 = row[i+1], p2 = row[i+2], p3 = row[i+3];
        a0 += bf2f((u16)p0) * qvL[2*i]   + bf2f((u16)(p0 >> 16)) * qvL[2*i+1];
        a1 += bf2f((u16)p1) * qvL[2*i+2] + bf2f((u16)(p1 >> 16)) * qvL[2*i+3];
        a2 += bf2f((u16)p2) * qvL[2*i+4] + bf2f((u16)(p2 >> 16)) * qvL[2*i+5];
        a3 += bf2f((u16)p3) * qvL[2*i+6] + bf2f((u16)(p3 >> 16)) * qvL[2*i+7];
      }
      #pragma unroll
      for (int k = 0; k < 16; k += 4) {
        a0 += peB[t][k]   * qvL[64 + k];
        a1 += peB[t][k+1] * qvL[65 + k];
        a2 += peB[t][k+2] * qvL[66 + k];
        a3 += peB[t][k+3] * qvL[67 + k];
      }
    }
    pC[half][t] = (a0 + a1) + (a2 + a3);
  }
  __syncthreads();

  // softmax (deferred normalization: bb holds unnormalized exp)
  if (tid < 128) {
    float v = scale * (pC[0][tid] + pC[1][tid]) + cstL;
    bb[tid] = v;
    float mm = v;
    #pragma unroll
    for (int off = 32; off; off >>= 1) mm = fmaxf(mm, __shfl_xor(mm, off));
    if ((tid & 63) == 0) red[tid >> 6] = mm;
  }
  __syncthreads();
  float mx = fmaxf(red[0], red[1]);
  if (tid < 128) {
    float ev = expf(bb[tid] - mx);
    bb[tid] = ev;
    float ss = ev;
    #pragma unroll
    for (int off = 32; off; off >>= 1) ss += __shfl_xor(ss, off);
    if ((tid & 63) == 0) red[2 + (tid >> 6)] = ss;
  }
  __syncthreads();

  // Phase E: hout partials on unnormalized weights (reuse pA)
  if (tid < 240) {
    int d = tid % 80, c = tid / 80;
    int t0 = c * 43, t1 = (c == 2) ? 128 : t0 + 43;
    float a0 = 0.f, a1 = 0.f, a2 = 0.f, a3 = 0.f;
    int t = t0;
    if (d < 64) {
      for (; t + 4 <= t1; t += 4) {
        a0 += bb[t]   * bf2f(Ht[t][d]);
        a1 += bb[t+1] * bf2f(Ht[t+1][d]);
        a2 += bb[t+2] * bf2f(Ht[t+2][d]);
        a3 += bb[t+3] * bf2f(Ht[t+3][d]);
      }
      for (; t < t1; ++t) a0 += bb[t] * bf2f(Ht[t][d]);
    } else {
      int k = d - 64;
      for (; t + 4 <= t1; t += 4) {
        a0 += bb[t]   * peB[t][k];
        a1 += bb[t+1] * peB[t+1][k];
        a2 += bb[t+2] * peB[t+2][k];
        a3 += bb[t+3] * peB[t+3][k];
      }
      for (; t < t1; ++t) a0 += bb[t] * peB[t][k];
    }
    pA[c][d] = (a0 + a1) + (a2 + a3);
  }
  __syncthreads();

  // Phase F: out partials over d-halves, 4 accumulators (reuse pC)
  {
    int o = tid & 127, half = tid >> 7;
    int d0 = half * 40;
    float a0 = 0.f, a1 = 0.f, a2 = 0.f, a3 = 0.f;
    #pragma unroll
    for (int i = 0; i < 40; i += 4) {
      int d = d0 + i;
      float h0 = pA[0][d]   + pA[1][d]   + pA[2][d];
      float h1 = pA[0][d+1] + pA[1][d+1] + pA[2][d+1];
      float h2 = pA[0][d+2] + pA[1][d+2] + pA[2][d+2];
      float h3 = pA[0][d+3] + pA[1][d+3] + pA[2][d+3];
      a0 += h0 * Wemb[d * 128 + o];
      a1 += h1 * Wemb[(d+1) * 128 + o];
      a2 += h2 * Wemb[(d+2) * 128 + o];
      a3 += h3 * Wemb[(d+3) * 128 + o];
    }
    pC[half][o] = (a0 + a1) + (a2 + a3);
  }
  __syncthreads();
  if (tid < 128) {
    float rdenom = 1.0f / (red[2] + red[3]);
    out[(((size_t)b * 64 + s) << 7) + tid] =
        bemb[tid] + (pC[0][tid] + pC[1][tid]) * rdenom;
  }
}

extern "C" void kernel_launch(void* const* d_in, const int* in_sizes, int n_in,
                              void* d_out, int out_size, void* d_ws, size_t ws_size,
                              hipStream_t stream) {
  (void)in_sizes; (void)n_in; (void)out_size; (void)ws_size;
  const float* x     = (const float*)d_in[0];
  const float* times = (const float*)d_in[1];
  const float* mask  = (const float*)d_in[2];
  const float* Wobs  = (const float*)d_in[3];
  const float* Wattn = (const float*)d_in[4];
  const float* Wrecv = (const float*)d_in[5];
  const float* brecv = (const float*)d_in[6];
  const float* Wb    = (const float*)d_in[7];
  const float* Wq    = (const float*)d_in[8];
  const float* bq    = (const float*)d_in[9];
  const float* Wk    = (const float*)d_in[10];
  const float* bk    = (const float*)d_in[11];
  const float* Ws    = (const float*)d_in[12];
  const float* bs    = (const float*)d_in[13];
  const float* Wemb  = (const float*)d_in[14];
  const float* bemb  = (const float*)d_in[15];
  float* out = (float*)d_out;
  float* ws_f = (float*)d_ws;
  char* ws_b = (char*)d_ws;
  u16* Hh = (u16*)(ws_b + BOFF_HH);

  hipMemsetAsync(ws_b + (size_t)OFF_ADJ * 4, 0, (size_t)64 * 64 * 64 * 4, stream);
  k_pre<<<322, 256, 0, stream>>>(times, mask, Wb, Wrecv, brecv, Wattn, ws_f, ws_b);
  k_adj<<<dim3(16, 64), 256, 0, stream>>>(x, mask, Wobs, ws_f, ws_b);
  k_scale<<<64, 256, 0, stream>>>(ws_f, ws_b);
  k_main<<<dim3(128, 64), 256, 0, stream>>>(x, mask, Wobs, ws_f, ws_b, Hh);
  k_attn<<<dim3(64, 64), 256, 0, stream>>>(ws_f, Hh, Wq, bq, Wk, bk, Ws, bs, Wemb, bemb, out);
}

// Round 8
// 186.367 us; speedup vs baseline: 1.3651x; 1.0044x over previous
//
#include <hip/hip_runtime.h>
#include <hip/hip_bf16.h>

// Raindrop forward, MI355X. B=64 T=128 S=64 O=4 E=64 P=16 A=10 OUT=128.
//  - temporal attention collapsed: (Q K^T) W_s = Q (W_s^T K)  -> no TxT matrix
//  - per-(b,t) chain in bf16 MFMA 16x16x32; 1 t/block; 4 barriers/block
//  - k_attn: 512 threads, 6-way t-chunks / 4-way d-chunks, deferred softmax norm
// ws floats: PE[131072] | bidir[4096] | masksum[4096] | adjnum[262144] | brp[32]
// ws bytes @: WrT 1605760 | catC 1609856 | PEh 1614976 | adjS 1877120 | Hh 2401408

typedef unsigned short u16;
typedef unsigned int u32;
typedef __attribute__((ext_vector_type(8))) short short8;
typedef __attribute__((ext_vector_type(4))) float f32x4;

#define OFF_PE    0
#define OFF_BIDIR 131072
#define OFF_MS    135168
#define OFF_ADJ   139264
#define OFF_BRP   401408
#define BOFF_WRT  1605760u
#define BOFF_CATC 1609856u
#define BOFF_PEH  1614976u
#define BOFF_ADJS 1877120u
#define BOFF_HH   2401408u

__device__ __forceinline__ u16 f2bf(float f){
  __hip_bfloat16 h = __float2bfloat16(f);
  union { __hip_bfloat16 h; u16 u; } v; v.h = h; return v.u;
}
__device__ __forceinline__ u32 pk2bf(float lo, float hi){
  __hip_bfloat162 h = __float22bfloat162_rn(float2{lo, hi});
  union { __hip_bfloat162 h; u32 u; } v; v.h = h; return v.u;
}
__device__ __forceinline__ float bf2f(u16 h){
  union { u32 u; float f; } v; v.u = ((u32)h) << 16; return v.f;
}

// ---------------- K0: PE (f32+bf16), bidir, WrT, brp, catC, masksum ----------------
__global__ void k_pre(const float* __restrict__ times, const float* __restrict__ mask,
                      const float* __restrict__ Wb, const float* __restrict__ Wrecv,
                      const float* __restrict__ brecv, const float* __restrict__ battn,
                      float* __restrict__ ws_f, char* __restrict__ ws_b) {
  __shared__ float pm[4][64];
  const int blk = blockIdx.x, tid = threadIdx.x;
  u16* wrt  = (u16*)(ws_b + BOFF_WRT);
  u16* catC = (u16*)(ws_b + BOFF_CATC);
  u16* peh  = (u16*)(ws_b + BOFF_PEH);
  if (blk < 256) {                     // PE: (B*T,16) sin|cos, f32 + bf16
    float* PE = ws_f + OFF_PE;
    #pragma unroll
    for (int r = 0; r < 2; ++r) {
      int id = blk * 512 + r * 256 + tid;
      int bt = id >> 4, k = id & 15;
      float tv = times[bt];
      int kk = k & 7;
      float fr = expf(-(float)kk * 1.1512925465f); // ln(1e4)/8
      float ang = tv * fr;
      float v = (k < 8) ? sinf(ang) : cosf(ang);
      PE[id] = v;
      peh[id] = f2bf(v);
    }
  } else if (blk == 256) {             // bidir = Wb @ Wb^T
    float* bidir = ws_f + OFF_BIDIR;
    for (int r = 0; r < 16; ++r) {
      int idx = r * 256 + tid;
      int i = idx >> 6, j = idx & 63;
      float acc = 0.f;
      for (int e = 0; e < 64; ++e) acc += Wb[i*64+e] * Wb[j*64+e];
      bidir[idx] = acc;
    }
  } else if (blk == 257) {             // WrT, brp, catC
    for (int r = 0; r < 8; ++r) {
      int idx = r * 256 + tid;
      int d = idx >> 6, e = idx & 63;
      wrt[idx] = (d < 26) ? f2bf(Wrecv[e*26 + d]) : (u16)0;
    }
    if (tid < 32) ws_f[OFF_BRP + tid] = (tid < 26) ? brecv[tid] : 0.f;
    for (int r = 0; r < 10; ++r) {
      int idx = r * 256 + tid;          // 2560 = 64*40
      int j = idx / 40, d = idx % 40;
      catC[idx] = (d < 10) ? f2bf(battn[j*10 + d]) : (u16)0;
    }
  } else {                             // masksum[b][i], 4-partial reduce
    int b = blk - 258;
    int i = tid & 63, q = tid >> 6;
    float s = 0.f;
    for (int t = q*32; t < q*32 + 32; ++t) s += mask[(b*128 + t)*64 + i];
    pm[q][i] = s;
    __syncthreads();
    if (tid < 64)
      (ws_f + OFF_MS)[b*64 + tid] = pm[0][tid] + pm[1][tid] + pm[2][tid] + pm[3][tid];
  }
}

// ---------------- K1: adj2 numerator (sum_t alpha) ----------------
__global__ __launch_bounds__(256)
void k_adj(const float* __restrict__ x, const float* __restrict__ mask,
           const float* __restrict__ Wobs, float* __restrict__ ws_f,
           const char* __restrict__ ws_b) {
  __shared__ __align__(16) u16 hA[64][72];
  __shared__ __align__(16) u16 hmA[64][40];
  __shared__ __align__(16) u16 catB[64][40];

  const int tid = threadIdx.x;
  const int b = blockIdx.y, tc = blockIdx.x;
  const int w = tid >> 6, l = tid & 63, lr = l & 15, lq = l >> 4, kb = lq * 8;
  const u16* wrt  = (const u16*)(ws_b + BOFF_WRT);
  const u16* catC = (const u16*)(ws_b + BOFF_CATC);
  const u16* peh  = (const u16*)(ws_b + BOFF_PEH);
  const float* brp = ws_f + OFF_BRP;
  float* adj = ws_f + OFF_ADJ;

  #pragma unroll
  for (int k = 0; k < 5; ++k) {        // catB const part (1280 u32)
    int idx = k * 256 + tid;
    ((u32*)catB)[idx] = ((const u32*)catC)[idx];
  }

  // prefetch WrT fragments (loop-invariant)
  const int m = w & 1, nb = (w >> 1) * 2;
  const u16* wr = wrt + (16*m + lr) * 64;
  short8 wa0 = *(const short8*)&wr[kb];
  short8 wa1 = *(const short8*)&wr[32 + kb];
  const int d0 = 16*m + lq*4;
  float4 bv = *(const float4*)&brp[d0];

  f32x4 asum[4];
  #pragma unroll
  for (int n = 0; n < 4; ++n) asum[n] = (f32x4){0.f,0.f,0.f,0.f};

  const int e4 = tid & 15, sg = tid >> 4;

  for (int tt = 0; tt < 8; ++tt) {
    int t = tc * 8 + tt;
    int base = b * 128 + t;
    { // P0: h build, direct x/mask loads (L1 broadcast across e4 lanes)
      float4 mk4 = *(const float4*)&mask[base*64 + sg*4];
      float mks[4] = {mk4.x, mk4.y, mk4.z, mk4.w};
      #pragma unroll
      for (int si = 0; si < 4; ++si) {
        int s = sg*4 + si;
        float4 xv = *(const float4*)&x[base*256 + s*4];
        float xo[4] = {xv.x, xv.y, xv.z, xv.w};
        float ax = 0.f, ay = 0.f, az = 0.f, aw = 0.f;
        #pragma unroll
        for (int o = 0; o < 4; ++o) {
          float4 wv = *(const float4*)&Wobs[(s*4+o)*64 + e4*4];
          ax += xo[o]*wv.x; ay += xo[o]*wv.y; az += xo[o]*wv.z; aw += xo[o]*wv.w;
        }
        float mk = mks[si];
        uint2 p;
        p.x = pk2bf(fmaxf(ax,0.f)*mk, fmaxf(ay,0.f)*mk);
        p.y = pk2bf(fmaxf(az,0.f)*mk, fmaxf(aw,0.f)*mk);
        *(uint2*)&hA[s][e4*4] = p;
      }
    }
    __syncthreads();
    { // P1: PE cols of catB + hm^T = WrT @ h^T -> hmA[s][d]
      int j = tid & 63, c = tid >> 6;
      const u32* pesrc = (const u32*)(peh + base*16);
      u32* dst = (u32*)&catB[j][10];
      dst[2*c]   = pesrc[2*c];
      dst[2*c+1] = pesrc[2*c+1];
      #pragma unroll
      for (int nn = 0; nn < 2; ++nn) {
        int n = nb + nn;
        f32x4 acc = (f32x4){0.f,0.f,0.f,0.f};
        short8 b0 = *(const short8*)&hA[16*n + lr][kb];
        short8 b1 = *(const short8*)&hA[16*n + lr][32 + kb];
        acc = __builtin_amdgcn_mfma_f32_16x16x32_bf16(wa0, b0, acc, 0, 0, 0);
        acc = __builtin_amdgcn_mfma_f32_16x16x32_bf16(wa1, b1, acc, 0, 0, 0);
        uint2 qq;
        qq.x = pk2bf(acc[0]+bv.x, acc[1]+bv.y);
        qq.y = pk2bf(acc[2]+bv.z, acc[3]+bv.w);
        *(uint2*)&hmA[16*n + lr][d0] = qq;
      }
    }
    __syncthreads();
    { // P2: alpha accumulate
      short8 am = *(const short8*)&hmA[16*w + lr][kb];
      #pragma unroll
      for (int n = 0; n < 4; ++n) {
        f32x4 z = (f32x4){0.f,0.f,0.f,0.f};
        short8 bc = *(const short8*)&catB[16*n + lr][kb];
        z = __builtin_amdgcn_mfma_f32_16x16x32_bf16(am, bc, z, 0, 0, 0);
        #pragma unroll
        for (int reg = 0; reg < 4; ++reg) asum[n][reg] += fmaxf(z[reg], 0.f);
      }
    }
    __syncthreads();
  }
  #pragma unroll
  for (int n = 0; n < 4; ++n) {
    #pragma unroll
    for (int reg = 0; reg < 4; ++reg) {
      int i = 16*w + lq*4 + reg, j = 16*n + lr;
      atomicAdd(&adj[((size_t)b << 12) + (i << 6) + j], asum[n][reg]);
    }
  }
}

// ---------------- K1b: adjS = bf16(adjnum / masksum) ----------------
__global__ __launch_bounds__(256)
void k_scale(const float* __restrict__ ws_f, char* __restrict__ ws_b) {
  const int b = blockIdx.x, tid = threadIdx.x;
  const float* adj = ws_f + OFF_ADJ + (size_t)b * 4096;
  const float* ms = ws_f + OFF_MS + b * 64;
  u16* as_ = (u16*)(ws_b + BOFF_ADJS) + (size_t)b * 4096;
  #pragma unroll
  for (int k = 0; k < 16; ++k) {
    int idx = k * 256 + tid;
    int i = idx >> 6;
    as_[idx] = f2bf(adj[idx] / ms[i]);
  }
}

// ---------------- K2: full per-(b,t) chain -> Hh bf16 (1 t/block) ----------------
__global__ __launch_bounds__(256, 4)
void k_main(const float* __restrict__ x, const float* __restrict__ mask,
            const float* __restrict__ Wobs, const float* __restrict__ ws_f,
            const char* __restrict__ ws_b, u16* __restrict__ Hh) {
  __shared__ __align__(16) char smem[37888];
  u16 (*hA)[72]  = (u16 (*)[72])(smem);           // h [s][e]; later h1T [e][i]
  u16 (*hT)[72]  = (u16 (*)[72])(smem + 9216);    // h^T [e][s]
  u16 (*wA)[72]  = (u16 (*)[72])(smem + 18432);   // w1 [i][j]
  u16 (*hmA)[40] = (u16 (*)[40])(smem + 27648);   // h_map [s][d]   (dead after P2)
  u16 (*catB)[40]= (u16 (*)[40])(smem + 32768);   //                (dead after P2)
  u16 (*adjS)[72]= (u16 (*)[72])(smem + 27648);   // overlay, staged in P3

  const int tid = threadIdx.x;
  const int t = blockIdx.x, b = blockIdx.y;
  const int w = tid >> 6, l = tid & 63, lr = l & 15, lq = l >> 4, kb = lq * 8;
  const int base = b * 128 + t;
  const u16* wrt  = (const u16*)(ws_b + BOFF_WRT);
  const u16* catC = (const u16*)(ws_b + BOFF_CATC);
  const u16* peh  = (const u16*)(ws_b + BOFF_PEH);
  const float* bidirG = ws_f + OFF_BIDIR;
  const float* brp = ws_f + OFF_BRP;
  const int i0 = 16*w + lq*4;

  // ---- prefetches: long-latency loads issued before any compute ----
  const uint4* ag = (const uint4*)(ws_b + BOFF_ADJS + (size_t)b * 8192);
  uint4 g0 = ag[2*tid], g1 = ag[2*tid + 1];
  const int m = w & 1, nb = (w >> 1) * 2;
  const u16* wr = wrt + (16*m + lr) * 64;
  short8 wa0 = *(const short8*)&wr[kb];
  short8 wa1 = *(const short8*)&wr[32 + kb];

  { // P0: h build (direct x/mask loads) + catB const copy
    const int e4 = tid & 15, sg = tid >> 4;
    float4 mk4 = *(const float4*)&mask[base*64 + sg*4];
    float mks[4] = {mk4.x, mk4.y, mk4.z, mk4.w};
    #pragma unroll
    for (int si = 0; si < 4; ++si) {
      int s = sg*4 + si;
      float4 xv = *(const float4*)&x[base*256 + s*4];
      float xo[4] = {xv.x, xv.y, xv.z, xv.w};
      float ax = 0.f, ay = 0.f, az = 0.f, aw = 0.f;
      #pragma unroll
      for (int o = 0; o < 4; ++o) {
        float4 wv = *(const float4*)&Wobs[(s*4+o)*64 + e4*4];
        ax += xo[o]*wv.x; ay += xo[o]*wv.y; az += xo[o]*wv.z; aw += xo[o]*wv.w;
      }
      float mk = mks[si];
      uint2 p;
      p.x = pk2bf(fmaxf(ax,0.f)*mk, fmaxf(ay,0.f)*mk);
      p.y = pk2bf(fmaxf(az,0.f)*mk, fmaxf(aw,0.f)*mk);
      *(uint2*)&hA[s][e4*4] = p;
    }
    #pragma unroll
    for (int k = 0; k < 5; ++k) {
      int idx = k * 256 + tid;
      ((u32*)catB)[idx] = ((const u32*)catC)[idx];
    }
  }
  __syncthreads();

  { // P1 phase: hT rebuild + PE cols of catB + hm MFMA
    #pragma unroll
    for (int sp = 0; sp < 8; ++sp) {
      int s = w*16 + sp*2;
      *(u32*)&hT[l][s] = (u32)hA[s][l] | ((u32)hA[s+1][l] << 16);
    }
    { int j = tid & 63, c = tid >> 6;
      const u32* pesrc = (const u32*)(peh + base*16);
      u32* dst = (u32*)&catB[j][10];
      dst[2*c]   = pesrc[2*c];
      dst[2*c+1] = pesrc[2*c+1];
    }
    int d0 = 16*m + lq*4;
    float4 bv = *(const float4*)&brp[d0];
    #pragma unroll
    for (int nn = 0; nn < 2; ++nn) {
      int n = nb + nn;
      f32x4 acc = (f32x4){0.f,0.f,0.f,0.f};
      short8 b0 = *(const short8*)&hA[16*n + lr][kb];
      short8 b1 = *(const short8*)&hA[16*n + lr][32 + kb];
      acc = __builtin_amdgcn_mfma_f32_16x16x32_bf16(wa0, b0, acc, 0, 0, 0);
      acc = __builtin_amdgcn_mfma_f32_16x16x32_bf16(wa1, b1, acc, 0, 0, 0);
      uint2 qq;
      qq.x = pk2bf(acc[0]+bv.x, acc[1]+bv.y);
      qq.y = pk2bf(acc[2]+bv.z, acc[3]+bv.w);
      *(uint2*)&hmA[16*n + lr][d0] = qq;
    }
  }
  __syncthreads();

  { // P2: alpha -> w1 (wA)
    short8 am = *(const short8*)&hmA[16*w + lr][kb];
    #pragma unroll
    for (int n = 0; n < 4; ++n) {
      f32x4 z = (f32x4){0.f,0.f,0.f,0.f};
      short8 bc = *(const short8*)&catB[16*n + lr][kb];
      z = __builtin_amdgcn_mfma_f32_16x16x32_bf16(am, bc, z, 0, 0, 0);
      int j = 16*n + lr;
      #pragma unroll
      for (int reg = 0; reg < 4; ++reg) {
        float w1 = fmaxf(z[reg], 0.f) * bidirG[((i0+reg) << 6) + j];
        wA[i0 + reg][j] = f2bf(w1);
      }
    }
  }
  __syncthreads();

  { // P3: adjS regs -> LDS (overlay); h1 = relu(w1 @ h) -> h1T into hA
    int idx0 = 2*tid, idx1 = 2*tid + 1;
    *(uint4*)&adjS[idx0 >> 3][(idx0 & 7) * 8] = g0;
    *(uint4*)&adjS[idx1 >> 3][(idx1 & 7) * 8] = g1;

    short8 aw0 = *(const short8*)&wA[16*w + lr][kb];
    short8 aw1 = *(const short8*)&wA[16*w + lr][32 + kb];
    #pragma unroll
    for (int n = 0; n < 4; ++n) {
      f32x4 acc = (f32x4){0.f,0.f,0.f,0.f};
      short8 b0 = *(const short8*)&hT[16*n + lr][kb];
      short8 b1 = *(const short8*)&hT[16*n + lr][32 + kb];
      acc = __builtin_amdgcn_mfma_f32_16x16x32_bf16(aw0, b0, acc, 0, 0, 0);
      acc = __builtin_amdgcn_mfma_f32_16x16x32_bf16(aw1, b1, acc, 0, 0, 0);
      int e = 16*n + lr;
      uint2 pp;
      pp.x = pk2bf(fmaxf(acc[0],0.f), fmaxf(acc[1],0.f));
      pp.y = pk2bf(fmaxf(acc[2],0.f), fmaxf(acc[3],0.f));
      *(uint2*)&hA[e][i0] = pp;   // h1T[e][i]
    }
  }
  __syncthreads();

  { // P4: w2 = w1 (.) adjS; h2 = relu(w2 @ h1) -> Hh
    int row = 16*w + lr;
    union { short8 v; u16 h[8]; u32 u[4]; } uw0, uw1, ud0, ud1, oa, ob;
    uw0.v = *(const short8*)&wA[row][kb];
    uw1.v = *(const short8*)&wA[row][32 + kb];
    ud0.v = *(const short8*)&adjS[row][kb];
    ud1.v = *(const short8*)&adjS[row][32 + kb];
    #pragma unroll
    for (int k = 0; k < 4; ++k) {
      oa.u[k] = pk2bf(bf2f(uw0.h[2*k])*bf2f(ud0.h[2*k]),
                      bf2f(uw0.h[2*k+1])*bf2f(ud0.h[2*k+1]));
      ob.u[k] = pk2bf(bf2f(uw1.h[2*k])*bf2f(ud1.h[2*k]),
                      bf2f(uw1.h[2*k+1])*bf2f(ud1.h[2*k+1]));
    }
    short8 a20 = oa.v, a21 = ob.v;
    size_t obase = ((size_t)b * 64) * 8192 + (size_t)t * 64;
    #pragma unroll
    for (int n = 0; n < 4; ++n) {
      f32x4 acc = (f32x4){0.f,0.f,0.f,0.f};
      short8 b0 = *(const short8*)&hA[16*n + lr][kb];      // h1T
      short8 b1 = *(const short8*)&hA[16*n + lr][32 + kb];
      acc = __builtin_amdgcn_mfma_f32_16x16x32_bf16(a20, b0, acc, 0, 0, 0);
      acc = __builtin_amdgcn_mfma_f32_16x16x32_bf16(a21, b1, acc, 0, 0, 0);
      int e = 16*n + lr;
      u32 p0 = pk2bf(fmaxf(acc[0],0.f), fmaxf(acc[1],0.f));
      u32 p1 = pk2bf(fmaxf(acc[2],0.f), fmaxf(acc[3],0.f));
      Hh[obase + (size_t)(i0+0) * 8192 + e] = (u16)p0;
      Hh[obase + (size_t)(i0+1) * 8192 + e] = (u16)(p0 >> 16);
      Hh[obase + (size_t)(i0+2) * 8192 + e] = (u16)p1;
      Hh[obase + (size_t)(i0+3) * 8192 + e] = (u16)(p1 >> 16);
    }
  }
}

// ---------------- K3: collapsed temporal attention (512 threads) ----------------
#define HTP 82
#define PEP 17

__global__ __launch_bounds__(512)
void k_attn(const float* __restrict__ ws_f, const u16* __restrict__ Hh,
            const float* __restrict__ Wq, const float* __restrict__ bq,
            const float* __restrict__ Wk, const float* __restrict__ bk,
            const float* __restrict__ Ws, const float* __restrict__ bs,
            const float* __restrict__ Wemb, const float* __restrict__ bemb,
            float* __restrict__ out) {
  __shared__ u16 Ht[128][HTP];
  __shared__ float peB[128][PEP];
  __shared__ float wsL[128];
  __shared__ float pA[6][80];
  __shared__ float pK[8][10];
  __shared__ float qvL[80];
  __shared__ float pC[4][128];
  __shared__ float bb[128];
  __shared__ float red[4];
  __shared__ float cstL, sWL;

  const int tid = threadIdx.x;
  const int s = blockIdx.x, b = blockIdx.y;
  const float scale = 0.111803398875f; // 1/sqrt(80)

  const u16* src = Hh + ((size_t)b * 64 + s) * 8192;
  #pragma unroll
  for (int r = 0; r < 2; ++r) {
    int id = r * 512 + tid;
    int tt = id >> 3, c = (id & 7) * 8;
    uint4 q = *(const uint4*)&src[tt * 64 + c];
    u32* dst = (u32*)&Ht[tt][c];
    dst[0] = q.x; dst[1] = q.y; dst[2] = q.z; dst[3] = q.w;
  }
  #pragma unroll
  for (int r = 0; r < 4; ++r) {
    int id = r * 512 + tid;
    peB[id >> 4][id & 15] = ws_f[OFF_PE + (size_t)b * 2048 + id];
  }
  if (tid < 128) wsL[tid] = Ws[tid];
  __syncthreads();

  // Phase A: hbar partials over 6 t-chunks of ~22
  if (tid < 480) {
    int d = tid % 80, c = tid / 80;
    int t0 = c * 22, t1 = (t0 + 22 > 128) ? 128 : t0 + 22;
    float a0 = 0.f, a1 = 0.f, a2 = 0.f, a3 = 0.f;
    int t = t0;
    if (d < 64) {
      for (; t + 4 <= t1; t += 4) {
        a0 += wsL[t]   * bf2f(Ht[t][d]);
        a1 += wsL[t+1] * bf2f(Ht[t+1][d]);
        a2 += wsL[t+2] * bf2f(Ht[t+2][d]);
        a3 += wsL[t+3] * bf2f(Ht[t+3][d]);
      }
      for (; t < t1; ++t) a0 += wsL[t] * bf2f(Ht[t][d]);
    } else {
      int k = d - 64;
      for (; t + 4 <= t1; t += 4) {
        a0 += wsL[t]   * peB[t][k];
        a1 += wsL[t+1] * peB[t+1][k];
        a2 += wsL[t+2] * peB[t+2][k];
        a3 += wsL[t+3] * peB[t+3][k];
      }
      for (; t < t1; ++t) a0 += wsL[t] * peB[t][k];
    }
    pA[c][d] = (a0 + a1) + (a2 + a3);
  } else if (tid == 480) {
    float a0 = 0.f, a1 = 0.f, a2 = 0.f, a3 = 0.f;
    for (int t = 0; t < 128; t += 4) {
      a0 += wsL[t]; a1 += wsL[t+1]; a2 += wsL[t+2]; a3 += wsL[t+3];
    }
    sWL = (a0 + a1) + (a2 + a3);
  }
  __syncthreads();

  // pK partials: pK[c][a] = sum_{d in chunk} hbar[d]*Wk[d*10+a]
  if (tid < 80) {
    int a = tid % 10, c = tid / 10;
    float a0 = 0.f, a1 = 0.f;
    #pragma unroll
    for (int i = 0; i < 10; i += 2) {
      int d = c * 10 + i;
      float h0 = pA[0][d] + pA[1][d] + pA[2][d] + pA[3][d] + pA[4][d] + pA[5][d];
      float h1 = pA[0][d+1] + pA[1][d+1] + pA[2][d+1] + pA[3][d+1] + pA[4][d+1] + pA[5][d+1];
      a0 += h0 * Wk[d * 10 + a];
      a1 += h1 * Wk[(d+1) * 10 + a];
    }
    pK[c][a] = a0 + a1;
  }
  __syncthreads();

  // qv phase (Ktil rebuilt locally)
  if (tid <= 80) {
    float kt[10];
    #pragma unroll
    for (int a = 0; a < 10; ++a) {
      float acc = sWL * bk[a];
      #pragma unroll
      for (int c = 0; c < 8; ++c) acc += pK[c][a];
      kt[a] = acc;
    }
    if (tid < 80) {
      float a0 = 0.f, a1 = 0.f;
      #pragma unroll
      for (int a = 0; a < 10; a += 2) {
        a0 += Wq[tid * 10 + a] * kt[a];
        a1 += Wq[tid * 10 + a + 1] * kt[a + 1];
      }
      qvL[tid] = a0 + a1;
    } else {
      float cq = 0.f;
      #pragma unroll
      for (int a = 0; a < 10; ++a) cq += bq[a] * kt[a];
      cstL = scale * cq + bs[0];
    }
  }
  __syncthreads();

  // Phase C: beta partials over 4 d-quarters
  {
    int t = tid & 127, q = tid >> 7;
    float a0 = 0.f, a1 = 0.f, a2 = 0.f, a3 = 0.f;
    const u32* row = (const u32*)&Ht[t][0];
    if (q == 0) {
      #pragma unroll
      for (int i = 0; i < 10; i += 2) {
        u32 p0 = row[i], p1 = row[i+1];
        a0 += bf2f((u16)p0) * qvL[2*i]   + bf2f((u16)(p0 >> 16)) * qvL[2*i+1];
        a1 += bf2f((u16)p1) * qvL[2*i+2] + bf2f((u16)(p1 >> 16)) * qvL[2*i+3];
      }
    } else if (q == 1) {
      #pragma unroll
      for (int i = 10; i < 20; i += 2) {
        u32 p0 = row[i], p1 = row[i+1];
        a0 += bf2f((u16)p0) * qvL[2*i]   + bf2f((u16)(p0 >> 16)) * qvL[2*i+1];
        a1 += bf2f((u16)p1) * qvL[2*i+2] + bf2f((u16)(p1 >> 16)) * qvL[2*i+3];
      }
    } else if (q == 2) {
      #pragma unroll
      for (int i = 20; i < 32; i += 4) {
        u32 p0 = row[i], p1 = row[i+1], p2 = row[i+2], p3 = row[i+3];
        a0 += bf2f((u16)p0) * qvL[2*i]   + bf2f((u16)(p0 >> 16)) * qvL[2*i+1];
        a1 += bf2f((u16)p1) * qvL[2*i+2] + bf2f((u16)(p1 >> 16)) * qvL[2*i+3];
        a2 += bf2f((u16)p2) * qvL[2*i+4] + bf2f((u16)(p2 >> 16)) * qvL[2*i+5];
        a3 += bf2f((u16)p3) * qvL[2*i+6] + bf2f((u16)(p3 >> 16)) * qvL[2*i+7];
      }
    } else {
      #pragma unroll
      for (int k = 0; k < 16; k += 4) {
        a0 += peB[t][k]   * qvL[64 + k];
        a1 += peB[t][k+1] * qvL[65 + k];
        a2 += peB[t][k+2] * qvL[66 + k];
        a3 += peB[t][k+3] * qvL[67 + k];
      }
    }
    pC[q][t] = (a0 + a1) + (a2 + a3);
  }
  __syncthreads();

  // softmax (deferred normalization: bb holds unnormalized exp)
  if (tid < 128) {
    float v = scale * (pC[0][tid] + pC[1][tid] + pC[2][tid] + pC[3][tid]) + cstL;
    bb[tid] = v;
    float mm = v;
    #pragma unroll
    for (int off = 32; off; off >>= 1) mm = fmaxf(mm, __shfl_xor(mm, off));
    if ((tid & 63) == 0) red[tid >> 6] = mm;
  }
  __syncthreads();
  float mx = fmaxf(red[0], red[1]);
  if (tid < 128) {
    float ev = expf(bb[tid] - mx);
    bb[tid] = ev;
    float ss = ev;
    #pragma unroll
    for (int off = 32; off; off >>= 1) ss += __shfl_xor(ss, off);
    if ((tid & 63) == 0) red[2 + (tid >> 6)] = ss;
  }
  __syncthreads();

  // Phase E: hout partials (reuse pA), 6 t-chunks
  if (tid < 480) {
    int d = tid % 80, c = tid / 80;
    int t0 = c * 22, t1 = (t0 + 22 > 128) ? 128 : t0 + 22;
    float a0 = 0.f, a1 = 0.f, a2 = 0.f, a3 = 0.f;
    int t = t0;
    if (d < 64) {
      for (; t + 4 <= t1; t += 4) {
        a0 += bb[t]   * bf2f(Ht[t][d]);
        a1 += bb[t+1] * bf2f(Ht[t+1][d]);
        a2 += bb[t+2] * bf2f(Ht[t+2][d]);
        a3 += bb[t+3] * bf2f(Ht[t+3][d]);
      }
      for (; t < t1; ++t) a0 += bb[t] * bf2f(Ht[t][d]);
    } else {
      int k = d - 64;
      for (; t + 4 <= t1; t += 4) {
        a0 += bb[t]   * peB[t][k];
        a1 += bb[t+1] * peB[t+1][k];
        a2 += bb[t+2] * peB[t+2][k];
        a3 += bb[t+3] * peB[t+3][k];
      }
      for (; t < t1; ++t) a0 += bb[t] * peB[t][k];
    }
    pA[c][d] = (a0 + a1) + (a2 + a3);
  }
  __syncthreads();

  // Phase F: out partials over 4 d-chunks of 20 (reuse pC)
  {
    int o = tid & 127, q = tid >> 7;
    int d0 = q * 20;
    float a0 = 0.f, a1 = 0.f, a2 = 0.f, a3 = 0.f;
    #pragma unroll
    for (int i = 0; i < 20; i += 4) {
      int d = d0 + i;
      float h0 = pA[0][d]   + pA[1][d]   + pA[2][d]   + pA[3][d]   + pA[4][d]   + pA[5][d];
      float h1 = pA[0][d+1] + pA[1][d+1] + pA[2][d+1] + pA[3][d+1] + pA[4][d+1] + pA[5][d+1];
      float h2 = pA[0][d+2] + pA[1][d+2] + pA[2][d+2] + pA[3][d+2] + pA[4][d+2] + pA[5][d+2];
      float h3 = pA[0][d+3] + pA[1][d+3] + pA[2][d+3] + pA[3][d+3] + pA[4][d+3] + pA[5][d+3];
      a0 += h0 * Wemb[d * 128 + o];
      a1 += h1 * Wemb[(d+1) * 128 + o];
      a2 += h2 * Wemb[(d+2) * 128 + o];
      a3 += h3 * Wemb[(d+3) * 128 + o];
    }
    pC[q][o] = (a0 + a1) + (a2 + a3);
  }
  __syncthreads();
  if (tid < 128) {
    float rdenom = 1.0f / (red[2] + red[3]);
    out[(((size_t)b * 64 + s) << 7) + tid] =
        bemb[tid] + (pC[0][tid] + pC[1][tid] + pC[2][tid] + pC[3][tid]) * rdenom;
  }
}

extern "C" void kernel_launch(void* const* d_in, const int* in_sizes, int n_in,
                              void* d_out, int out_size, void* d_ws, size_t ws_size,
                              hipStream_t stream) {
  (void)in_sizes; (void)n_in; (void)out_size; (void)ws_size;
  const float* x     = (const float*)d_in[0];
  const float* times = (const float*)d_in[1];
  const float* mask  = (const float*)d_in[2];
  const float* Wobs  = (const float*)d_in[3];
  const float* Wattn = (const float*)d_in[4];
  const float* Wrecv = (const float*)d_in[5];
  const float* brecv = (const float*)d_in[6];
  const float* Wb    = (const float*)d_in[7];
  const float* Wq    = (const float*)d_in[8];
  const float* bq    = (const float*)d_in[9];
  const float* Wk    = (const float*)d_in[10];
  const float* bk    = (const float*)d_in[11];
  const float* Ws    = (const float*)d_in[12];
  const float* bs    = (const float*)d_in[13];
  const float* Wemb  = (const float*)d_in[14];
  const float* bemb  = (const float*)d_in[15];
  float* out = (float*)d_out;
  float* ws_f = (float*)d_ws;
  char* ws_b = (char*)d_ws;
  u16* Hh = (u16*)(ws_b + BOFF_HH);

  hipMemsetAsync(ws_b + (size_t)OFF_ADJ * 4, 0, (size_t)64 * 64 * 64 * 4, stream);
  k_pre<<<322, 256, 0, stream>>>(times, mask, Wb, Wrecv, brecv, Wattn, ws_f, ws_b);
  k_adj<<<dim3(16, 64), 256, 0, stream>>>(x, mask, Wobs, ws_f, ws_b);
  k_scale<<<64, 256, 0, stream>>>(ws_f, ws_b);
  k_main<<<dim3(128, 64), 256, 0, stream>>>(x, mask, Wobs, ws_f, ws_b, Hh);
  k_attn<<<dim3(64, 64), 512, 0, stream>>>(ws_f, Hh, Wq, bq, Wk, bk, Ws, bs, Wemb, bemb, out);
}

// Round 9
// 150.944 us; speedup vs baseline: 1.6855x; 1.2347x over previous
//
#include <hip/hip_runtime.h>
#include <hip/hip_bf16.h>

// Raindrop forward, MI355X. B=64 T=128 S=64 O=4 E=64 P=16 A=10 OUT=128.
//  - temporal attention collapsed: (Q K^T) W_s = Q (W_s^T K)  -> no TxT matrix
//  - alpha decomposition: alpha[i][j] = relu(hm10[i]*battn[j] + h[i].v_t + s_t)
//    v_t = Wr[:,10:26]@pe_t, s_t = br[10:26].pe_t precomputed in k_pre ->
//    P1 MFMAs halved, catx static, no per-t PE staging in k_adj/k_main
// ws floats: PE[131072] | bidir | masksum | adjnum | brp[16] | sT[8192]
// ws bytes @: WrT 1638464 | catx 1642560 | PEh 1644608 | adjS 1906752 | V 2431040 | Hh 3479616

typedef unsigned short u16;
typedef unsigned int u32;
typedef __attribute__((ext_vector_type(8))) short short8;
typedef __attribute__((ext_vector_type(4))) float f32x4;

#define OFF_PE    0
#define OFF_BIDIR 131072
#define OFF_MS    135168
#define OFF_ADJ   139264
#define OFF_BRP   401408
#define OFF_ST    401424
#define BOFF_WRT  1638464u
#define BOFF_CATX 1642560u
#define BOFF_PEH  1644608u
#define BOFF_ADJS 1906752u
#define BOFF_V    2431040u
#define BOFF_HH   3479616u

__device__ __forceinline__ u16 f2bf(float f){
  __hip_bfloat16 h = __float2bfloat16(f);
  union { __hip_bfloat16 h; u16 u; } v; v.h = h; return v.u;
}
__device__ __forceinline__ u32 pk2bf(float lo, float hi){
  __hip_bfloat162 h = __float22bfloat162_rn(float2{lo, hi});
  union { __hip_bfloat162 h; u32 u; } v; v.h = h; return v.u;
}
__device__ __forceinline__ float bf2f(u16 h){
  union { u32 u; float f; } v; v.u = ((u32)h) << 16; return v.f;
}

// ---------------- K0: PE/peh/v/sT, bidir(x4), WrT/brp/catx, masksum ----------------
__global__ void k_pre(const float* __restrict__ times, const float* __restrict__ mask,
                      const float* __restrict__ Wb, const float* __restrict__ Wrecv,
                      const float* __restrict__ brecv, const float* __restrict__ battn,
                      float* __restrict__ ws_f, char* __restrict__ ws_b) {
  __shared__ float peL[32][17];
  __shared__ float wpe[64][17];
  __shared__ float pm[4][64];
  const int blk = blockIdx.x, tid = threadIdx.x;
  u16* wrt  = (u16*)(ws_b + BOFF_WRT);
  u16* catx = (u16*)(ws_b + BOFF_CATX);
  u16* peh  = (u16*)(ws_b + BOFF_PEH);
  u16* vv   = (u16*)(ws_b + BOFF_V);
  float* ST = ws_f + OFF_ST;
  if (blk < 256) {                     // PE (f32+bf16) + v_t + s_t for 32 bt rows
    float* PE = ws_f + OFF_PE;
    #pragma unroll
    for (int r = 0; r < 2; ++r) {
      int id = blk * 512 + r * 256 + tid;
      int bt = id >> 4, k = id & 15;
      float tv = times[bt];
      int kk = k & 7;
      float fr = expf(-(float)kk * 1.1512925465f); // ln(1e4)/8
      float ang = tv * fr;
      float v = (k < 8) ? sinf(ang) : cosf(ang);
      PE[id] = v;
      peh[id] = f2bf(v);
      peL[r*16 + (tid >> 4)][k] = v;
    }
    #pragma unroll
    for (int q = 0; q < 4; ++q) {
      int idx = q * 256 + tid;
      wpe[idx >> 4][idx & 15] = Wrecv[(idx >> 4)*26 + 10 + (idx & 15)];
    }
    __syncthreads();
    {
      int btl = tid >> 3, e0 = (tid & 7) * 8;
      float acc[8];
      #pragma unroll
      for (int i = 0; i < 8; ++i) acc[i] = 0.f;
      #pragma unroll
      for (int k = 0; k < 16; ++k) {
        float p = peL[btl][k];
        #pragma unroll
        for (int i = 0; i < 8; ++i) acc[i] += wpe[e0 + i][k] * p;
      }
      u32* dst = (u32*)&vv[(blk*32 + btl)*64 + e0];
      #pragma unroll
      for (int p = 0; p < 4; ++p) dst[p] = pk2bf(acc[2*p], acc[2*p+1]);
      if (tid < 32) {
        float s = 0.f;
        #pragma unroll
        for (int k = 0; k < 16; ++k) s += brecv[10 + k] * peL[tid][k];
        ST[blk*32 + tid] = s;
      }
    }
  } else if (blk < 260) {              // bidir = Wb @ Wb^T (4 blocks)
    float* bidir = ws_f + OFF_BIDIR;
    int q = blk - 256;
    for (int rr = 0; rr < 4; ++rr) {
      int idx = (q*4 + rr) * 256 + tid;
      int i = idx >> 6, j = idx & 63;
      float acc = 0.f;
      for (int e = 0; e < 64; ++e) acc += Wb[i*64+e] * Wb[j*64+e];
      bidir[idx] = acc;
    }
  } else if (blk == 260) {             // WrT, brp (pad16), catx
    for (int r = 0; r < 8; ++r) {
      int idx = r * 256 + tid;
      int d = idx >> 6, e = idx & 63;
      wrt[idx] = (d < 26) ? f2bf(Wrecv[e*26 + d]) : (u16)0;
    }
    if (tid < 16) ws_f[OFF_BRP + tid] = (tid < 10) ? brecv[tid] : 0.f;
    #pragma unroll
    for (int i = 0; i < 4; ++i) {
      int idx = i * 256 + tid;
      int j = idx >> 4, d = idx & 15;
      catx[idx] = (d < 10) ? f2bf(battn[j*10 + d]) : ((d == 10) ? f2bf(1.f) : (u16)0);
    }
  } else {                             // masksum[b][i], 4-partial reduce
    int b = blk - 261;
    int i = tid & 63, q = tid >> 6;
    float s = 0.f;
    for (int t = q*32; t < q*32 + 32; ++t) s += mask[(b*128 + t)*64 + i];
    pm[q][i] = s;
    __syncthreads();
    if (tid < 64)
      (ws_f + OFF_MS)[b*64 + tid] = pm[0][tid] + pm[1][tid] + pm[2][tid] + pm[3][tid];
  }
}

// ---------------- K1: adj2 numerator (sum_t alpha) ----------------
__global__ __launch_bounds__(256)
void k_adj(const float* __restrict__ x, const float* __restrict__ mask,
           const float* __restrict__ Wobs, float* __restrict__ ws_f,
           const char* __restrict__ ws_b) {
  __shared__ __align__(16) u16 hA[64][72];
  __shared__ __align__(16) u16 hmA[64][24];

  const int tid = threadIdx.x;
  const int b = blockIdx.y, tc = blockIdx.x;
  const int w = tid >> 6, l = tid & 63, lr = l & 15, lq = l >> 4, kb = lq * 8;
  const u16* wrt  = (const u16*)(ws_b + BOFF_WRT);
  const u16* catx = (const u16*)(ws_b + BOFF_CATX);
  const u16* vv   = (const u16*)(ws_b + BOFF_V);
  const float* brp = ws_f + OFF_BRP;
  const float* ST = ws_f + OFF_ST;
  float* adj = ws_f + OFF_ADJ;

  const short8 z8 = (short8){0,0,0,0,0,0,0,0};
  const bool lowk = (lq < 2);
  // static prefetches
  short8 w0 = z8, w1 = z8;
  if (lr < 10) {
    const u16* wr = wrt + lr * 64;
    w0 = *(const short8*)&wr[kb];
    w1 = *(const short8*)&wr[32 + kb];
  }
  short8 bc[4];
  #pragma unroll
  for (int n = 0; n < 4; ++n)
    bc[n] = lowk ? *(const short8*)&catx[(16*n + lr)*16 + lq*8] : z8;
  float4 bv = *(const float4*)&brp[lq*4];

  f32x4 asum[4];
  #pragma unroll
  for (int n = 0; n < 4; ++n) asum[n] = (f32x4){0.f,0.f,0.f,0.f};

  const int e4 = tid & 15, sg = tid >> 4;

  for (int tt = 0; tt < 8; ++tt) {
    int t = tc * 8 + tt;
    int base = b * 128 + t;
    // P0: h build (lane=(e4,sg)); v_t/s_t loads issued early
    short8 av0 = z8, av1 = z8;
    if (lr == 10) {
      av0 = *(const short8*)&vv[base*64 + kb];
      av1 = *(const short8*)&vv[base*64 + 32 + kb];
    }
    float st = ST[base];
    {
      float4 mk4 = *(const float4*)&mask[base*64 + sg*4];
      float mks[4] = {mk4.x, mk4.y, mk4.z, mk4.w};
      #pragma unroll
      for (int si = 0; si < 4; ++si) {
        int s = sg*4 + si;
        float4 xv = *(const float4*)&x[base*256 + s*4];
        float xo[4] = {xv.x, xv.y, xv.z, xv.w};
        float ax = 0.f, ay = 0.f, az = 0.f, aw = 0.f;
        #pragma unroll
        for (int o = 0; o < 4; ++o) {
          float4 wv = *(const float4*)&Wobs[(s*4+o)*64 + e4*4];
          ax += xo[o]*wv.x; ay += xo[o]*wv.y; az += xo[o]*wv.z; aw += xo[o]*wv.w;
        }
        float mk = mks[si];
        uint2 p;
        p.x = pk2bf(fmaxf(ax,0.f)*mk, fmaxf(ay,0.f)*mk);
        p.y = pk2bf(fmaxf(az,0.f)*mk, fmaxf(aw,0.f)*mk);
        *(uint2*)&hA[s][e4*4] = p;
      }
    }
    __syncthreads();
    { // P1: hmx[s][dx] = h @ [Wr10|v_t|0..] (+br10 pad)
      short8 a0 = (lr < 10) ? w0 : av0;
      short8 a1 = (lr < 10) ? w1 : av1;
      f32x4 acc = (f32x4){0.f,0.f,0.f,0.f};
      short8 b0 = *(const short8*)&hA[16*w + lr][kb];
      short8 b1 = *(const short8*)&hA[16*w + lr][32 + kb];
      acc = __builtin_amdgcn_mfma_f32_16x16x32_bf16(a0, b0, acc, 0, 0, 0);
      acc = __builtin_amdgcn_mfma_f32_16x16x32_bf16(a1, b1, acc, 0, 0, 0);
      uint2 qq;
      qq.x = pk2bf(acc[0]+bv.x, acc[1]+bv.y);
      qq.y = pk2bf(acc[2]+bv.z, acc[3]+bv.w);
      *(uint2*)&hmA[16*w + lr][lq*4] = qq;
    }
    __syncthreads();
    { // P2: alpha = relu(hmx @ catx^T + s_t), accumulate
      short8 am = lowk ? *(const short8*)&hmA[16*w + lr][lq*8] : z8;
      #pragma unroll
      for (int n = 0; n < 4; ++n) {
        f32x4 z = (f32x4){st, st, st, st};
        z = __builtin_amdgcn_mfma_f32_16x16x32_bf16(am, bc[n], z, 0, 0, 0);
        #pragma unroll
        for (int reg = 0; reg < 4; ++reg) asum[n][reg] += fmaxf(z[reg], 0.f);
      }
    }
    __syncthreads();
  }
  #pragma unroll
  for (int n = 0; n < 4; ++n) {
    #pragma unroll
    for (int reg = 0; reg < 4; ++reg) {
      int i = 16*w + lq*4 + reg, j = 16*n + lr;
      atomicAdd(&adj[((size_t)b << 12) + (i << 6) + j], asum[n][reg]);
    }
  }
}

// ---------------- K1b: adjS = bf16(adjnum / masksum) ----------------
__global__ __launch_bounds__(256)
void k_scale(const float* __restrict__ ws_f, char* __restrict__ ws_b) {
  const int b = blockIdx.x, tid = threadIdx.x;
  const float* adj = ws_f + OFF_ADJ + (size_t)b * 4096;
  const float* ms = ws_f + OFF_MS + b * 64;
  u16* as_ = (u16*)(ws_b + BOFF_ADJS) + (size_t)b * 4096;
  #pragma unroll
  for (int k = 0; k < 16; ++k) {
    int idx = k * 256 + tid;
    int i = idx >> 6;
    as_[idx] = f2bf(adj[idx] / ms[i]);
  }
}

// ---------------- K2: full per-(b,t) chain -> Hh bf16 (1 t/block) ----------------
__global__ __launch_bounds__(256, 4)
void k_main(const float* __restrict__ x, const float* __restrict__ mask,
            const float* __restrict__ Wobs, const float* __restrict__ ws_f,
            const char* __restrict__ ws_b, u16* __restrict__ Hh) {
  __shared__ __align__(16) char smem[36864];
  u16 (*hA)[72]  = (u16 (*)[72])(smem);           // h [s][e]; later h1T [e][i]
  u16 (*hT)[72]  = (u16 (*)[72])(smem + 9216);    // h^T [e][s]
  u16 (*wA)[72]  = (u16 (*)[72])(smem + 18432);   // w1 [i][j]
  u16 (*hmA)[24] = (u16 (*)[24])(smem + 27648);   // hmx [s][dx]  (dead after P2)
  u16 (*adjS)[72]= (u16 (*)[72])(smem + 27648);   // overlay, staged in P3

  const int tid = threadIdx.x;
  const int t = blockIdx.x, b = blockIdx.y;
  const int w = tid >> 6, l = tid & 63, lr = l & 15, lq = l >> 4, kb = lq * 8;
  const int base = b * 128 + t;
  const u16* wrt  = (const u16*)(ws_b + BOFF_WRT);
  const u16* catx = (const u16*)(ws_b + BOFF_CATX);
  const u16* vv   = (const u16*)(ws_b + BOFF_V);
  const float* bidirG = ws_f + OFF_BIDIR;
  const float* brp = ws_f + OFF_BRP;
  const int i0 = 16*w + lq*4;
  const short8 z8 = (short8){0,0,0,0,0,0,0,0};
  const bool lowk = (lq < 2);

  // ---- prefetches: long-latency loads issued before any compute ----
  const uint4* ag = (const uint4*)(ws_b + BOFF_ADJS + (size_t)b * 8192);
  uint4 g0 = ag[2*tid], g1 = ag[2*tid + 1];
  short8 w0 = z8, w1 = z8;
  if (lr < 10) {
    const u16* wr = wrt + lr * 64;
    w0 = *(const short8*)&wr[kb];
    w1 = *(const short8*)&wr[32 + kb];
  }
  short8 av0 = z8, av1 = z8;
  if (lr == 10) {
    av0 = *(const short8*)&vv[base*64 + kb];
    av1 = *(const short8*)&vv[base*64 + 32 + kb];
  }
  short8 bc[4];
  #pragma unroll
  for (int n = 0; n < 4; ++n)
    bc[n] = lowk ? *(const short8*)&catx[(16*n + lr)*16 + lq*8] : z8;
  float4 bv = *(const float4*)&brp[lq*4];
  const float st = (ws_f + OFF_ST)[base];

  { // P0: h build (direct x/mask loads)
    const int e4 = tid & 15, sg = tid >> 4;
    float4 mk4 = *(const float4*)&mask[base*64 + sg*4];
    float mks[4] = {mk4.x, mk4.y, mk4.z, mk4.w};
    #pragma unroll
    for (int si = 0; si < 4; ++si) {
      int s = sg*4 + si;
      float4 xv = *(const float4*)&x[base*256 + s*4];
      float xo[4] = {xv.x, xv.y, xv.z, xv.w};
      float ax = 0.f, ay = 0.f, az = 0.f, aw = 0.f;
      #pragma unroll
      for (int o = 0; o < 4; ++o) {
        float4 wv = *(const float4*)&Wobs[(s*4+o)*64 + e4*4];
        ax += xo[o]*wv.x; ay += xo[o]*wv.y; az += xo[o]*wv.z; aw += xo[o]*wv.w;
      }
      float mk = mks[si];
      uint2 p;
      p.x = pk2bf(fmaxf(ax,0.f)*mk, fmaxf(ay,0.f)*mk);
      p.y = pk2bf(fmaxf(az,0.f)*mk, fmaxf(aw,0.f)*mk);
      *(uint2*)&hA[s][e4*4] = p;
    }
  }
  __syncthreads();

  { // P1: hT rebuild + hmx MFMA
    #pragma unroll
    for (int sp = 0; sp < 8; ++sp) {
      int s = w*16 + sp*2;
      *(u32*)&hT[l][s] = (u32)hA[s][l] | ((u32)hA[s+1][l] << 16);
    }
    short8 a0 = (lr < 10) ? w0 : av0;
    short8 a1 = (lr < 10) ? w1 : av1;
    f32x4 acc = (f32x4){0.f,0.f,0.f,0.f};
    short8 b0 = *(const short8*)&hA[16*w + lr][kb];
    short8 b1 = *(const short8*)&hA[16*w + lr][32 + kb];
    acc = __builtin_amdgcn_mfma_f32_16x16x32_bf16(a0, b0, acc, 0, 0, 0);
    acc = __builtin_amdgcn_mfma_f32_16x16x32_bf16(a1, b1, acc, 0, 0, 0);
    uint2 qq;
    qq.x = pk2bf(acc[0]+bv.x, acc[1]+bv.y);
    qq.y = pk2bf(acc[2]+bv.z, acc[3]+bv.w);
    *(uint2*)&hmA[16*w + lr][lq*4] = qq;
  }
  __syncthreads();

  { // P2: alpha -> w1 (wA)
    short8 am = lowk ? *(const short8*)&hmA[16*w + lr][lq*8] : z8;
    #pragma unroll
    for (int n = 0; n < 4; ++n) {
      f32x4 z = (f32x4){st, st, st, st};
      z = __builtin_amdgcn_mfma_f32_16x16x32_bf16(am, bc[n], z, 0, 0, 0);
      int j = 16*n + lr;
      #pragma unroll
      for (int reg = 0; reg < 4; ++reg) {
        float w1v = fmaxf(z[reg], 0.f) * bidirG[((i0+reg) << 6) + j];
        wA[i0 + reg][j] = f2bf(w1v);
      }
    }
  }
  __syncthreads();

  { // P3: adjS regs -> LDS (overlay); h1 = relu(w1 @ h) -> h1T into hA
    int idx0 = 2*tid, idx1 = 2*tid + 1;
    *(uint4*)&adjS[idx0 >> 3][(idx0 & 7) * 8] = g0;
    *(uint4*)&adjS[idx1 >> 3][(idx1 & 7) * 8] = g1;

    short8 aw0 = *(const short8*)&wA[16*w + lr][kb];
    short8 aw1 = *(const short8*)&wA[16*w + lr][32 + kb];
    #pragma unroll
    for (int n = 0; n < 4; ++n) {
      f32x4 acc = (f32x4){0.f,0.f,0.f,0.f};
      short8 b0 = *(const short8*)&hT[16*n + lr][kb];
      short8 b1 = *(const short8*)&hT[16*n + lr][32 + kb];
      acc = __builtin_amdgcn_mfma_f32_16x16x32_bf16(aw0, b0, acc, 0, 0, 0);
      acc = __builtin_amdgcn_mfma_f32_16x16x32_bf16(aw1, b1, acc, 0, 0, 0);
      int e = 16*n + lr;
      uint2 pp;
      pp.x = pk2bf(fmaxf(acc[0],0.f), fmaxf(acc[1],0.f));
      pp.y = pk2bf(fmaxf(acc[2],0.f), fmaxf(acc[3],0.f));
      *(uint2*)&hA[e][i0] = pp;   // h1T[e][i]
    }
  }
  __syncthreads();

  { // P4: w2 = w1 (.) adjS; h2 = relu(w2 @ h1) -> Hh
    int row = 16*w + lr;
    union { short8 v; u16 h[8]; u32 u[4]; } uw0, uw1, ud0, ud1, oa, ob;
    uw0.v = *(const short8*)&wA[row][kb];
    uw1.v = *(const short8*)&wA[row][32 + kb];
    ud0.v = *(const short8*)&adjS[row][kb];
    ud1.v = *(const short8*)&adjS[row][32 + kb];
    #pragma unroll
    for (int k = 0; k < 4; ++k) {
      oa.u[k] = pk2bf(bf2f(uw0.h[2*k])*bf2f(ud0.h[2*k]),
                      bf2f(uw0.h[2*k+1])*bf2f(ud0.h[2*k+1]));
      ob.u[k] = pk2bf(bf2f(uw1.h[2*k])*bf2f(ud1.h[2*k]),
                      bf2f(uw1.h[2*k+1])*bf2f(ud1.h[2*k+1]));
    }
    short8 a20 = oa.v, a21 = ob.v;
    size_t obase = ((size_t)b * 64) * 8192 + (size_t)t * 64;
    #pragma unroll
    for (int n = 0; n < 4; ++n) {
      f32x4 acc = (f32x4){0.f,0.f,0.f,0.f};
      short8 b0 = *(const short8*)&hA[16*n + lr][kb];      // h1T
      short8 b1 = *(const short8*)&hA[16*n + lr][32 + kb];
      acc = __builtin_amdgcn_mfma_f32_16x16x32_bf16(a20, b0, acc, 0, 0, 0);
      acc = __builtin_amdgcn_mfma_f32_16x16x32_bf16(a21, b1, acc, 0, 0, 0);
      int e = 16*n + lr;
      u32 p0 = pk2bf(fmaxf(acc[0],0.f), fmaxf(acc[1],0.f));
      u32 p1 = pk2bf(fmaxf(acc[2],0.f), fmaxf(acc[3],0.f));
      Hh[obase + (size_t)(i0+0) * 8192 + e] = (u16)p0;
      Hh[obase + (size_t)(i0+1) * 8192 + e] = (u16)(p0 >> 16);
      Hh[obase + (size_t)(i0+2) * 8192 + e] = (u16)p1;
      Hh[obase + (size_t)(i0+3) * 8192 + e] = (u16)(p1 >> 16);
    }
  }
}

// ---------------- K3: collapsed temporal attention (512 threads) ----------------
#define HTP 82
#define PEP 17

__global__ __launch_bounds__(512)
void k_attn(const float* __restrict__ ws_f, const u16* __restrict__ Hh,
            const float* __restrict__ Wq, const float* __restrict__ bq,
            const float* __restrict__ Wk, const float* __restrict__ bk,
            const float* __restrict__ Ws, const float* __restrict__ bs,
            const float* __restrict__ Wemb, const float* __restrict__ bemb,
            float* __restrict__ out) {
  __shared__ u16 Ht[128][HTP];
  __shared__ float peB[128][PEP];
  __shared__ float wsL[128];
  __shared__ float pA[6][80];
  __shared__ float pK[8][10];
  __shared__ float qvL[80];
  __shared__ float pC[4][128];
  __shared__ float bb[128];
  __shared__ float red[4];
  __shared__ float cstL, sWL;

  const int tid = threadIdx.x;
  const int s = blockIdx.x, b = blockIdx.y;
  const float scale = 0.111803398875f; // 1/sqrt(80)

  const u16* src = Hh + ((size_t)b * 64 + s) * 8192;
  #pragma unroll
  for (int r = 0; r < 2; ++r) {
    int id = r * 512 + tid;
    int tt = id >> 3, c = (id & 7) * 8;
    uint4 q = *(const uint4*)&src[tt * 64 + c];
    u32* dst = (u32*)&Ht[tt][c];
    dst[0] = q.x; dst[1] = q.y; dst[2] = q.z; dst[3] = q.w;
  }
  #pragma unroll
  for (int r = 0; r < 4; ++r) {
    int id = r * 512 + tid;
    peB[id >> 4][id & 15] = ws_f[OFF_PE + (size_t)b * 2048 + id];
  }
  if (tid < 128) wsL[tid] = Ws[tid];
  __syncthreads();

  // Phase A: hbar partials over 6 t-chunks of ~22
  if (tid < 480) {
    int d = tid % 80, c = tid / 80;
    int t0 = c * 22, t1 = (t0 + 22 > 128) ? 128 : t0 + 22;
    float a0 = 0.f, a1 = 0.f, a2 = 0.f, a3 = 0.f;
    int t = t0;
    if (d < 64) {
      for (; t + 4 <= t1; t += 4) {
        a0 += wsL[t]   * bf2f(Ht[t][d]);
        a1 += wsL[t+1] * bf2f(Ht[t+1][d]);
        a2 += wsL[t+2] * bf2f(Ht[t+2][d]);
        a3 += wsL[t+3] * bf2f(Ht[t+3][d]);
      }
      for (; t < t1; ++t) a0 += wsL[t] * bf2f(Ht[t][d]);
    } else {
      int k = d - 64;
      for (; t + 4 <= t1; t += 4) {
        a0 += wsL[t]   * peB[t][k];
        a1 += wsL[t+1] * peB[t+1][k];
        a2 += wsL[t+2] * peB[t+2][k];
        a3 += wsL[t+3] * peB[t+3][k];
      }
      for (; t < t1; ++t) a0 += wsL[t] * peB[t][k];
    }
    pA[c][d] = (a0 + a1) + (a2 + a3);
  } else if (tid == 480) {
    float a0 = 0.f, a1 = 0.f, a2 = 0.f, a3 = 0.f;
    for (int t = 0; t < 128; t += 4) {
      a0 += wsL[t]; a1 += wsL[t+1]; a2 += wsL[t+2]; a3 += wsL[t+3];
    }
    sWL = (a0 + a1) + (a2 + a3);
  }
  __syncthreads();

  if (tid < 80) {
    int a = tid % 10, c = tid / 10;
    float a0 = 0.f, a1 = 0.f;
    #pragma unroll
    for (int i = 0; i < 10; i += 2) {
      int d = c * 10 + i;
      float h0 = pA[0][d] + pA[1][d] + pA[2][d] + pA[3][d] + pA[4][d] + pA[5][d];
      float h1 = pA[0][d+1] + pA[1][d+1] + pA[2][d+1] + pA[3][d+1] + pA[4][d+1] + pA[5][d+1];
      a0 += h0 * Wk[d * 10 + a];
      a1 += h1 * Wk[(d+1) * 10 + a];
    }
    pK[c][a] = a0 + a1;
  }
  __syncthreads();

  if (tid <= 80) {
    float kt[10];
    #pragma unroll
    for (int a = 0; a < 10; ++a) {
      float acc = sWL * bk[a];
      #pragma unroll
      for (int c = 0; c < 8; ++c) acc += pK[c][a];
      kt[a] = acc;
    }
    if (tid < 80) {
      float a0 = 0.f, a1 = 0.f;
      #pragma unroll
      for (int a = 0; a < 10; a += 2) {
        a0 += Wq[tid * 10 + a] * kt[a];
        a1 += Wq[tid * 10 + a + 1] * kt[a + 1];
      }
      qvL[tid] = a0 + a1;
    } else {
      float cq = 0.f;
      #pragma unroll
      for (int a = 0; a < 10; ++a) cq += bq[a] * kt[a];
      cstL = scale * cq + bs[0];
    }
  }
  __syncthreads();

  // Phase C: beta partials over 4 d-quarters
  {
    int t = tid & 127, q = tid >> 7;
    float a0 = 0.f, a1 = 0.f, a2 = 0.f, a3 = 0.f;
    const u32* row = (const u32*)&Ht[t][0];
    if (q == 0) {
      #pragma unroll
      for (int i = 0; i < 10; i += 2) {
        u32 p0 = row[i], p1 = row[i+1];
        a0 += bf2f((u16)p0) * qvL[2*i]   + bf2f((u16)(p0 >> 16)) * qvL[2*i+1];
        a1 += bf2f((u16)p1) * qvL[2*i+2] + bf2f((u16)(p1 >> 16)) * qvL[2*i+3];
      }
    } else if (q == 1) {
      #pragma unroll
      for (int i = 10; i < 20; i += 2) {
        u32 p0 = row[i], p1 = row[i+1];
        a0 += bf2f((u16)p0) * qvL[2*i]   + bf2f((u16)(p0 >> 16)) * qvL[2*i+1];
        a1 += bf2f((u16)p1) * qvL[2*i+2] + bf2f((u16)(p1 >> 16)) * qvL[2*i+3];
      }
    } else if (q == 2) {
      #pragma unroll
      for (int i = 20; i < 32; i += 4) {
        u32 p0 = row[i], p1 = row[i+1], p2 = row[i+2], p3 = row[i+3];
        a0 += bf2f((u16)p0) * qvL[2*i]   + bf2f((u16)(p0 >> 16)) * qvL[2*i+1];
        a1 += bf2f((u16)p1) * qvL[2*i+2] + bf2f((u16)(p1 >> 16)) * qvL[2*i+3];
        a2 += bf2f((u16)p2) * qvL[2*i+4] + bf2f((u16)(p2 >> 16)) * qvL[2*i+5];
        a3 += bf2f((u16)p3) * qvL[2*i+6] + bf2f((u16)(p3 >> 16)) * qvL[2*i+7];
      }
    } else {
      #pragma unroll
      for (int k = 0; k < 16; k += 4) {
        a0 += peB[t][k]   * qvL[64 + k];
        a1 += peB[t][k+1] * qvL[65 + k];
        a2 += peB[t][k+2] * qvL[66 + k];
        a3 += peB[t][k+3] * qvL[67 + k];
      }
    }
    pC[q][t] = (a0 + a1) + (a2 + a3);
  }
  __syncthreads();

  if (tid < 128) {
    float v = scale * (pC[0][tid] + pC[1][tid] + pC[2][tid] + pC[3][tid]) + cstL;
    bb[tid] = v;
    float mm = v;
    #pragma unroll
    for (int off = 32; off; off >>= 1) mm = fmaxf(mm, __shfl_xor(mm, off));
    if ((tid & 63) == 0) red[tid >> 6] = mm;
  }
  __syncthreads();
  float mx = fmaxf(red[0], red[1]);
  if (tid < 128) {
    float ev = expf(bb[tid] - mx);
    bb[tid] = ev;
    float ss = ev;
    #pragma unroll
    for (int off = 32; off; off >>= 1) ss += __shfl_xor(ss, off);
    if ((tid & 63) == 0) red[2 + (tid >> 6)] = ss;
  }
  __syncthreads();

  // Phase E: hout partials (reuse pA), 6 t-chunks
  if (tid < 480) {
    int d = tid % 80, c = tid / 80;
    int t0 = c * 22, t1 = (t0 + 22 > 128) ? 128 : t0 + 22;
    float a0 = 0.f, a1 = 0.f, a2 = 0.f, a3 = 0.f;
    int t = t0;
    if (d < 64) {
      for (; t + 4 <= t1; t += 4) {
        a0 += bb[t]   * bf2f(Ht[t][d]);
        a1 += bb[t+1] * bf2f(Ht[t+1][d]);
        a2 += bb[t+2] * bf2f(Ht[t+2][d]);
        a3 += bb[t+3] * bf2f(Ht[t+3][d]);
      }
      for (; t < t1; ++t) a0 += bb[t] * bf2f(Ht[t][d]);
    } else {
      int k = d - 64;
      for (; t + 4 <= t1; t += 4) {
        a0 += bb[t]   * peB[t][k];
        a1 += bb[t+1] * peB[t+1][k];
        a2 += bb[t+2] * peB[t+2][k];
        a3 += bb[t+3] * peB[t+3][k];
      }
      for (; t < t1; ++t) a0 += bb[t] * peB[t][k];
    }
    pA[c][d] = (a0 + a1) + (a2 + a3);
  }
  __syncthreads();

  // Phase F: out partials over 4 d-chunks of 20 (reuse pC)
  {
    int o = tid & 127, q = tid >> 7;
    int d0 = q * 20;
    float a0 = 0.f, a1 = 0.f, a2 = 0.f, a3 = 0.f;
    #pragma unroll
    for (int i = 0; i < 20; i += 4) {
      int d = d0 + i;
      float h0 = pA[0][d]   + pA[1][d]   + pA[2][d]   + pA[3][d]   + pA[4][d]   + pA[5][d];
      float h1 = pA[0][d+1] + pA[1][d+1] + pA[2][d+1] + pA[3][d+1] + pA[4][d+1] + pA[5][d+1];
      float h2 = pA[0][d+2] + pA[1][d+2] + pA[2][d+2] + pA[3][d+2] + pA[4][d+2] + pA[5][d+2];
      float h3 = pA[0][d+3] + pA[1][d+3] + pA[2][d+3] + pA[3][d+3] + pA[4][d+3] + pA[5][d+3];
      a0 += h0 * Wemb[d * 128 + o];
      a1 += h1 * Wemb[(d+1) * 128 + o];
      a2 += h2 * Wemb[(d+2) * 128 + o];
      a3 += h3 * Wemb[(d+3) * 128 + o];
    }
    pC[q][o] = (a0 + a1) + (a2 + a3);
  }
  __syncthreads();
  if (tid < 128) {
    float rdenom = 1.0f / (red[2] + red[3]);
    out[(((size_t)b * 64 + s) << 7) + tid] =
        bemb[tid] + (pC[0][tid] + pC[1][tid] + pC[2][tid] + pC[3][tid]) * rdenom;
  }
}

extern "C" void kernel_launch(void* const* d_in, const int* in_sizes, int n_in,
                              void* d_out, int out_size, void* d_ws, size_t ws_size,
                              hipStream_t stream) {
  (void)in_sizes; (void)n_in; (void)out_size; (void)ws_size;
  const float* x     = (const float*)d_in[0];
  const float* times = (const float*)d_in[1];
  const float* mask  = (const float*)d_in[2];
  const float* Wobs  = (const float*)d_in[3];
  const float* Wattn = (const float*)d_in[4];
  const float* Wrecv = (const float*)d_in[5];
  const float* brecv = (const float*)d_in[6];
  const float* Wb    = (const float*)d_in[7];
  const float* Wq    = (const float*)d_in[8];
  const float* bq    = (const float*)d_in[9];
  const float* Wk    = (const float*)d_in[10];
  const float* bk    = (const float*)d_in[11];
  const float* Ws    = (const float*)d_in[12];
  const float* bs    = (const float*)d_in[13];
  const float* Wemb  = (const float*)d_in[14];
  const float* bemb  = (const float*)d_in[15];
  float* out = (float*)d_out;
  float* ws_f = (float*)d_ws;
  char* ws_b = (char*)d_ws;
  u16* Hh = (u16*)(ws_b + BOFF_HH);

  hipMemsetAsync(ws_b + (size_t)OFF_ADJ * 4, 0, (size_t)64 * 64 * 64 * 4, stream);
  k_pre<<<325, 256, 0, stream>>>(times, mask, Wb, Wrecv, brecv, Wattn, ws_f, ws_b);
  k_adj<<<dim3(16, 64), 256, 0, stream>>>(x, mask, Wobs, ws_f, ws_b);
  k_scale<<<64, 256, 0, stream>>>(ws_f, ws_b);
  k_main<<<dim3(128, 64), 256, 0, stream>>>(x, mask, Wobs, ws_f, ws_b, Hh);
  k_attn<<<dim3(64, 64), 512, 0, stream>>>(ws_f, Hh, Wq, bq, Wk, bk, Ws, bs, Wemb, bemb, out);
}